// Round 8
// baseline (1072.267 us; speedup 1.0000x reference)
//
#include <hip/hip_runtime.h>
#include <hip/hip_bf16.h>
#include <math.h>

#define TT 4096
#define DIM 512
#define FFN 2048
#define NVOCAB 32000
#define NT 250

typedef __attribute__((ext_vector_type(8))) short short8_t;
typedef __attribute__((ext_vector_type(4))) float f32x4;

__device__ __forceinline__ float gelu_f(float x) {
    float x3 = x * x * x;
    float u = 0.7978845608028654f * (x + 0.044715f * x3);
    return 0.5f * x * (1.0f + tanhf(u));
}

__device__ __forceinline__ unsigned short f2bf_rn(float f) {
    unsigned u = __float_as_uint(f);
    u += 0x7FFFu + ((u >> 16) & 1u);
    return (unsigned short)(u >> 16);
}

// -------------------- embedding gather + flag init --------------------
__global__ __launch_bounds__(128) void gather_kernel(const int* __restrict__ x,
                                                     const float* __restrict__ emb,
                                                     float* __restrict__ h,
                                                     int* __restrict__ flags) {
    int t = blockIdx.x;
    int idx = x[t];
    const float4 v = *(const float4*)&emb[(size_t)idx * DIM + threadIdx.x * 4];
    *(float4*)&h[(size_t)t * DIM + threadIdx.x * 4] = v;
    if (threadIdx.x == 0) flags[t] = 1;
}

// -------------------- fp32 -> bf16 hi/lo split (flat) --------------------
__global__ __launch_bounds__(256) void cvt_hilo(const float* __restrict__ src,
                                                short* __restrict__ hi,
                                                short* __restrict__ lo, int n4) {
    int i = blockIdx.x * 256 + threadIdx.x;
    if (i >= n4) return;
    float4 v = *(const float4*)&src[(size_t)i * 4];
    float f[4] = {v.x, v.y, v.z, v.w};
    short4 hv, lv;
    short* hp = &hv.x;
    short* lp = &lv.x;
#pragma unroll
    for (int j = 0; j < 4; ++j) {
        unsigned short hb = f2bf_rn(f[j]);
        float hf = __uint_as_float((unsigned)hb << 16);
        unsigned short lb = f2bf_rn(f[j] - hf);
        hp[j] = (short)hb;
        lp[j] = (short)lb;
    }
    *(short4*)&hi[(size_t)i * 4] = hv;
    *(short4*)&lo[(size_t)i * 4] = lv;
}

// -------------------- fp32 W (K,N) -> bf16 hi/lo transposed (N,K) --------------------
__global__ __launch_bounds__(256) void cvt_w_t(const float* __restrict__ W,
                                               short* __restrict__ hiT,
                                               short* __restrict__ loT,
                                               int K, int N) {
    __shared__ short hs[32][36];
    __shared__ short ls[32][36];
    const int n0 = blockIdx.x * 32, k0 = blockIdx.y * 32;
    const int r = threadIdx.x >> 3, c4 = (threadIdx.x & 7) << 2;
    float4 v = *(const float4*)&W[(size_t)(k0 + r) * N + n0 + c4];
    float f[4] = {v.x, v.y, v.z, v.w};
#pragma unroll
    for (int j = 0; j < 4; ++j) {
        unsigned short hb = f2bf_rn(f[j]);
        float hf = __uint_as_float((unsigned)hb << 16);
        unsigned short lb = f2bf_rn(f[j] - hf);
        hs[r][c4 + j] = (short)hb;
        ls[r][c4 + j] = (short)lb;
    }
    __syncthreads();
    const int nr = threadIdx.x >> 3, kc4 = (threadIdx.x & 7) << 2;
    short4 hv, lv;
    short* hp = &hv.x;
    short* lp = &lv.x;
#pragma unroll
    for (int j = 0; j < 4; ++j) {
        hp[j] = hs[kc4 + j][nr];
        lp[j] = ls[kc4 + j][nr];
    }
    *(short4*)&hiT[(size_t)(n0 + nr) * K + k0 + kc4] = hv;
    *(short4*)&loT[(size_t)(n0 + nr) * K + k0 + kc4] = lv;
}

// -------------------- LayerNorm (fp32 out; optional index gather) --------------------
template<bool IDX>
__global__ __launch_bounds__(256) void ln_kernel(const float* __restrict__ x,
                                                 const float* __restrict__ gam,
                                                 const float* __restrict__ bet,
                                                 float* __restrict__ out,
                                                 const int* __restrict__ idx,
                                                 const int* __restrict__ cnt) {
    int wv = threadIdx.x >> 6, lane = threadIdx.x & 63;
    int p = (blockIdx.x << 2) | wv;
    if (IDX && p >= *cnt) return;
    int t = IDX ? idx[p] : p;
    const float* row = x + (size_t)t * DIM;
    int base = lane * 8;
    float4 v0 = *(const float4*)&row[base];
    float4 v1 = *(const float4*)&row[base + 4];
    float s = v0.x + v0.y + v0.z + v0.w + v1.x + v1.y + v1.z + v1.w;
#pragma unroll
    for (int o = 32; o; o >>= 1) s += __shfl_xor(s, o, 64);
    float mean = s * (1.0f / (float)DIM);
    float d0 = v0.x - mean, d1 = v0.y - mean, d2 = v0.z - mean, d3 = v0.w - mean;
    float d4 = v1.x - mean, d5 = v1.y - mean, d6 = v1.z - mean, d7 = v1.w - mean;
    float q = d0*d0 + d1*d1 + d2*d2 + d3*d3 + d4*d4 + d5*d5 + d6*d6 + d7*d7;
#pragma unroll
    for (int o = 32; o; o >>= 1) q += __shfl_xor(q, o, 64);
    float var = q * (1.0f / (float)DIM);
    float rs = 1.0f / sqrtf(var + 1e-5f);
    float4 g0 = *(const float4*)&gam[base];
    float4 g1 = *(const float4*)&gam[base + 4];
    float4 b0 = *(const float4*)&bet[base];
    float4 b1 = *(const float4*)&bet[base + 4];
    float4 o0, o1;
    o0.x = d0 * rs * g0.x + b0.x;  o0.y = d1 * rs * g0.y + b0.y;
    o0.z = d2 * rs * g0.z + b0.z;  o0.w = d3 * rs * g0.w + b0.w;
    o1.x = d4 * rs * g1.x + b1.x;  o1.y = d5 * rs * g1.y + b1.y;
    o1.z = d6 * rs * g1.z + b1.z;  o1.w = d7 * rs * g1.w + b1.w;
    float* orow = out + (size_t)p * DIM;
    *(float4*)&orow[base] = o0;
    *(float4*)&orow[base + 4] = o1;
}

// -------------------- LayerNorm -> bf16 hi/lo (dense, block 0) --------------------
__global__ __launch_bounds__(256) void ln_hilo(const float* __restrict__ x,
                                               const float* __restrict__ gam,
                                               const float* __restrict__ bet,
                                               short* __restrict__ ohi,
                                               short* __restrict__ olo) {
    int wv = threadIdx.x >> 6, lane = threadIdx.x & 63;
    int t = (blockIdx.x << 2) | wv;
    const float* row = x + (size_t)t * DIM;
    int base = lane * 8;
    float4 v0 = *(const float4*)&row[base];
    float4 v1 = *(const float4*)&row[base + 4];
    float s = v0.x + v0.y + v0.z + v0.w + v1.x + v1.y + v1.z + v1.w;
#pragma unroll
    for (int o = 32; o; o >>= 1) s += __shfl_xor(s, o, 64);
    float mean = s * (1.0f / (float)DIM);
    float d[8] = {v0.x - mean, v0.y - mean, v0.z - mean, v0.w - mean,
                  v1.x - mean, v1.y - mean, v1.z - mean, v1.w - mean};
    float q = 0.0f;
#pragma unroll
    for (int j = 0; j < 8; ++j) q += d[j] * d[j];
#pragma unroll
    for (int o = 32; o; o >>= 1) q += __shfl_xor(q, o, 64);
    float var = q * (1.0f / (float)DIM);
    float rs = 1.0f / sqrtf(var + 1e-5f);
    float g[8], bb[8];
    *(float4*)&g[0] = *(const float4*)&gam[base];
    *(float4*)&g[4] = *(const float4*)&gam[base + 4];
    *(float4*)&bb[0] = *(const float4*)&bet[base];
    *(float4*)&bb[4] = *(const float4*)&bet[base + 4];
    short8_t hv, lv;
#pragma unroll
    for (int j = 0; j < 8; ++j) {
        float val = d[j] * rs * g[j] + bb[j];
        unsigned short hb = f2bf_rn(val);
        float hf = __uint_as_float((unsigned)hb << 16);
        hv[j] = (short)hb;
        lv[j] = (short)f2bf_rn(val - hf);
    }
    *(short8_t*)&ohi[(size_t)t * DIM + base] = hv;
    *(short8_t*)&olo[(size_t)t * DIM + base] = lv;
}

// -------------------- split-bf16 MFMA GEMM (128x128): C(M,N) = A(M,K) @ B(N,K)^T -----
// EPI: 0 = store hi/lo bf16; 1 = gelu + store hi/lo; 2 = residual add into Cf;
//      3 = plain fp32 store; 4 = residual add into Cf AND store hi/lo of the sum.
template<int EPI>
__global__ __launch_bounds__(256) void gemm_l_mfma(const short* __restrict__ Ah,
                                                   const short* __restrict__ Al,
                                                   const short* __restrict__ Bh,
                                                   const short* __restrict__ Bl,
                                                   float* __restrict__ Cf,
                                                   short* __restrict__ oHi,
                                                   short* __restrict__ oLo,
                                                   int N, int K) {
    __shared__ __align__(16) short sm[16384];
    short* sAh = sm;
    short* sAl = sm + 4096;
    short* sBh = sm + 8192;
    short* sBl = sm + 12288;
    const int tid = threadIdx.x;
    const int wv = tid >> 6, lane = tid & 63;
    const int m0 = blockIdx.x * 128;
    const int n0 = blockIdx.y * 128;
    const int wm = (wv & 1) * 64, wn = (wv >> 1) * 64;
    const int r16 = lane >> 2;
    const int gsw = ((lane & 3) ^ (r16 & 3)) << 3;
    const int fr = lane & 15;
    const int q = lane >> 4;

    f32x4 acc[4][4];
#pragma unroll
    for (int i = 0; i < 4; ++i)
#pragma unroll
        for (int j = 0; j < 4; ++j)
            acc[i][j] = (f32x4){0.0f, 0.0f, 0.0f, 0.0f};

    const int NKT = K >> 5;
    for (int kt = 0; kt < NKT; ++kt) {
        const int k0 = kt << 5;
        __syncthreads();
#pragma unroll
        for (int j = 0; j < 2; ++j) {
            const int rr = (wv << 5) + (j << 4);
            const int gr = rr + r16;
            const short* ga_h = Ah + (size_t)(m0 + gr) * K + k0 + gsw;
            const short* ga_l = Al + (size_t)(m0 + gr) * K + k0 + gsw;
            const short* gb_h = Bh + (size_t)(n0 + gr) * K + k0 + gsw;
            const short* gb_l = Bl + (size_t)(n0 + gr) * K + k0 + gsw;
            __builtin_amdgcn_global_load_lds((const __attribute__((address_space(1))) void*)ga_h,
                                             (__attribute__((address_space(3))) void*)(sAh + rr * 32), 16, 0, 0);
            __builtin_amdgcn_global_load_lds((const __attribute__((address_space(1))) void*)ga_l,
                                             (__attribute__((address_space(3))) void*)(sAl + rr * 32), 16, 0, 0);
            __builtin_amdgcn_global_load_lds((const __attribute__((address_space(1))) void*)gb_h,
                                             (__attribute__((address_space(3))) void*)(sBh + rr * 32), 16, 0, 0);
            __builtin_amdgcn_global_load_lds((const __attribute__((address_space(1))) void*)gb_l,
                                             (__attribute__((address_space(3))) void*)(sBl + rr * 32), 16, 0, 0);
        }
        __syncthreads();
        short8_t ah[4], al[4], bh[4], bl[4];
#pragma unroll
        for (int i = 0; i < 4; ++i) {
            const int ra = wm + i * 16 + fr;
            const int rb = wn + i * 16 + fr;
            const int swa = (q ^ (fr & 3)) << 3;
            ah[i] = *(const short8_t*)&sAh[ra * 32 + swa];
            al[i] = *(const short8_t*)&sAl[ra * 32 + swa];
            bh[i] = *(const short8_t*)&sBh[rb * 32 + swa];
            bl[i] = *(const short8_t*)&sBl[rb * 32 + swa];
        }
#pragma unroll
        for (int i = 0; i < 4; ++i)
#pragma unroll
            for (int j = 0; j < 4; ++j) {
                acc[i][j] = __builtin_amdgcn_mfma_f32_16x16x32_bf16(ah[i], bh[j], acc[i][j], 0, 0, 0);
                acc[i][j] = __builtin_amdgcn_mfma_f32_16x16x32_bf16(ah[i], bl[j], acc[i][j], 0, 0, 0);
                acc[i][j] = __builtin_amdgcn_mfma_f32_16x16x32_bf16(al[i], bh[j], acc[i][j], 0, 0, 0);
            }
    }
    const int row_base = (lane >> 4) << 2;
#pragma unroll
    for (int i = 0; i < 4; ++i)
#pragma unroll
        for (int j = 0; j < 4; ++j) {
            const int row = m0 + wm + i * 16 + row_base;
            const int col = n0 + wn + j * 16 + fr;
#pragma unroll
            for (int r = 0; r < 4; ++r) {
                float val = acc[i][j][r];
                if (EPI == 3) {
                    Cf[(size_t)(row + r) * N + col] = val;
                } else if (EPI == 2) {
                    Cf[(size_t)(row + r) * N + col] += val;
                } else if (EPI == 4) {
                    float* cp = &Cf[(size_t)(row + r) * N + col];
                    float nv = *cp + val;
                    *cp = nv;
                    unsigned short hb = f2bf_rn(nv);
                    float hf = __uint_as_float((unsigned)hb << 16);
                    oHi[(size_t)(row + r) * N + col] = (short)hb;
                    oLo[(size_t)(row + r) * N + col] = (short)f2bf_rn(nv - hf);
                } else {
                    if (EPI == 1) val = gelu_f(val);
                    unsigned short hb = f2bf_rn(val);
                    float hf = __uint_as_float((unsigned)hb << 16);
                    oHi[(size_t)(row + r) * N + col] = (short)hb;
                    oLo[(size_t)(row + r) * N + col] = (short)f2bf_rn(val - hf);
                }
            }
        }
}

// -------------------- head GEMM + fused confidence partials --------------------
// Conf partials computed BEFORE the C-store so the barrier only drains LDS reads;
// C stores issue last and the wave retires with them in flight (no vmcnt(0) drain).
__global__ __launch_bounds__(256) void gemm_head_fused(const short* __restrict__ Ah,
                                                       const short* __restrict__ Al,
                                                       const short* __restrict__ Bh,
                                                       const short* __restrict__ Bl,
                                                       float* __restrict__ C,
                                                       float2* __restrict__ pp) {
    __shared__ __align__(16) short sm[16384];
    short* sAh = sm;
    short* sAl = sm + 4096;
    short* sBh = sm + 8192;
    short* sBl = sm + 12288;
    const int tid = threadIdx.x;
    const int wv = tid >> 6, lane = tid & 63;
    const int m0 = blockIdx.x * 128;
    const int n0 = blockIdx.y * 128;
    const int nt = blockIdx.y;
    const int wm = (wv & 1) * 64, wn = (wv >> 1) * 64;
    const int r16 = lane >> 2;
    const int gsw = ((lane & 3) ^ (r16 & 3)) << 3;
    const int fr = lane & 15;
    const int q = lane >> 4;

    f32x4 acc[4][4];
#pragma unroll
    for (int i = 0; i < 4; ++i)
#pragma unroll
        for (int j = 0; j < 4; ++j)
            acc[i][j] = (f32x4){0.0f, 0.0f, 0.0f, 0.0f};

    const int NKT = DIM >> 5;
    for (int kt = 0; kt < NKT; ++kt) {
        const int k0 = kt << 5;
        __syncthreads();
#pragma unroll
        for (int j = 0; j < 2; ++j) {
            const int rr = (wv << 5) + (j << 4);
            const int gr = rr + r16;
            const short* ga_h = Ah + (size_t)(m0 + gr) * DIM + k0 + gsw;
            const short* ga_l = Al + (size_t)(m0 + gr) * DIM + k0 + gsw;
            const short* gb_h = Bh + (size_t)(n0 + gr) * DIM + k0 + gsw;
            const short* gb_l = Bl + (size_t)(n0 + gr) * DIM + k0 + gsw;
            __builtin_amdgcn_global_load_lds((const __attribute__((address_space(1))) void*)ga_h,
                                             (__attribute__((address_space(3))) void*)(sAh + rr * 32), 16, 0, 0);
            __builtin_amdgcn_global_load_lds((const __attribute__((address_space(1))) void*)ga_l,
                                             (__attribute__((address_space(3))) void*)(sAl + rr * 32), 16, 0, 0);
            __builtin_amdgcn_global_load_lds((const __attribute__((address_space(1))) void*)gb_h,
                                             (__attribute__((address_space(3))) void*)(sBh + rr * 32), 16, 0, 0);
            __builtin_amdgcn_global_load_lds((const __attribute__((address_space(1))) void*)gb_l,
                                             (__attribute__((address_space(3))) void*)(sBl + rr * 32), 16, 0, 0);
        }
        __syncthreads();
        short8_t ah[4], al[4], bh[4], bl[4];
#pragma unroll
        for (int i = 0; i < 4; ++i) {
            const int ra = wm + i * 16 + fr;
            const int rb = wn + i * 16 + fr;
            const int swa = (q ^ (fr & 3)) << 3;
            ah[i] = *(const short8_t*)&sAh[ra * 32 + swa];
            al[i] = *(const short8_t*)&sAl[ra * 32 + swa];
            bh[i] = *(const short8_t*)&sBh[rb * 32 + swa];
            bl[i] = *(const short8_t*)&sBl[rb * 32 + swa];
        }
#pragma unroll
        for (int i = 0; i < 4; ++i)
#pragma unroll
            for (int j = 0; j < 4; ++j) {
                acc[i][j] = __builtin_amdgcn_mfma_f32_16x16x32_bf16(ah[i], bh[j], acc[i][j], 0, 0, 0);
                acc[i][j] = __builtin_amdgcn_mfma_f32_16x16x32_bf16(ah[i], bl[j], acc[i][j], 0, 0, 0);
                acc[i][j] = __builtin_amdgcn_mfma_f32_16x16x32_bf16(al[i], bh[j], acc[i][j], 0, 0, 0);
            }
    }
    const int hi = lane >> 4;
    const int row_base = hi << 2;

    // ---- conf partials FIRST (barrier drains only LDS reads; no stores yet) ----
    __syncthreads();
    float2* confS = (float2*)sm;  // [128][2] halves
#pragma unroll
    for (int i = 0; i < 4; ++i)
#pragma unroll
        for (int r = 0; r < 4; ++r) {
            float v0 = acc[i][0][r], v1 = acc[i][1][r];
            float v2 = acc[i][2][r], v3 = acc[i][3][r];
            float mg = fmaxf(fmaxf(v0, v1), fmaxf(v2, v3));
#pragma unroll
            for (int o = 1; o < 16; o <<= 1) mg = fmaxf(mg, __shfl_xor(mg, o, 64));
            float sg = __expf(v0 - mg) + __expf(v1 - mg) + __expf(v2 - mg) + __expf(v3 - mg);
#pragma unroll
            for (int o = 1; o < 16; o <<= 1) sg += __shfl_xor(sg, o, 64);
            if (fr == 0)
                confS[(wm + i * 16 + hi * 4 + r) * 2 + (wn >> 6)] = make_float2(mg, sg);
        }
    __syncthreads();
    if (tid < 128) {
        float2 a = confS[tid * 2 + 0];
        float2 b = confS[tid * 2 + 1];
        float mm = fmaxf(a.x, b.x);
        float ss = a.y * __expf(a.x - mm) + b.y * __expf(b.x - mm);
        pp[(size_t)(m0 + tid) * NT + nt] = make_float2(mm, ss);
    }

    // ---- C stores last: fire and retire ----
#pragma unroll
    for (int i = 0; i < 4; ++i)
#pragma unroll
        for (int j = 0; j < 4; ++j) {
            const int row = m0 + wm + i * 16 + row_base;
            const int col = n0 + wn + j * 16 + fr;
#pragma unroll
            for (int r = 0; r < 4; ++r)
                C[(size_t)(row + r) * NVOCAB + col] = acc[i][j][r];
        }
}

// -------------------- conf reduce over head partials (one wave per token) ---------
__global__ __launch_bounds__(256) void conf_reduce(const float2* __restrict__ pp,
                                                   int* __restrict__ flags, float thr) {
    int wv = threadIdx.x >> 6, lane = threadIdx.x & 63;
    int t = blockIdx.x * 4 + wv;
    float m = -INFINITY, s = 0.0f;
    for (int k = lane; k < NT; k += 64) {
        float2 v = pp[(size_t)t * NT + k];
        float mm = fmaxf(m, v.x);
        s = s * __expf(m - mm) + v.y * __expf(v.x - mm);
        m = mm;
    }
#pragma unroll
    for (int o = 1; o < 64; o <<= 1) {
        float mo = __shfl_xor(m, o, 64);
        float so = __shfl_xor(s, o, 64);
        float mm = fmaxf(m, mo);
        s = s * __expf(m - mm) + so * __expf(mo - mm);
        m = mm;
    }
    if (lane == 0) {
        float conf = 1.0f / s;
        if (conf > thr) flags[t] = 0;
    }
}

// -------------------- fp32 tiled GEMM (blocks 1-2 compact path) --------------------
template<bool ADD, bool GELU, bool GUARD, bool SCAT>
__global__ __launch_bounds__(256) void gemm_nn(const float* __restrict__ A,
                                               const float* __restrict__ B,
                                               float* __restrict__ C,
                                               int M, int N, int K,
                                               const int* __restrict__ idx,
                                               const int* __restrict__ cnt) {
    const int m0 = blockIdx.y * 64, n0 = blockIdx.x * 64;
    int c = GUARD ? *cnt : M;
    if (GUARD && m0 >= c) return;
    __shared__ float As[16][68];
    __shared__ float Bs[16][68];
    const int tid = threadIdx.x;
    const int am = tid >> 2, ak = (tid & 3) << 2;
    const int bk = tid >> 4, bn = (tid & 15) << 2;
    const int tn = tid & 15, tm = tid >> 4;
    int ar = m0 + am;
    if (GUARD) ar = ar < c ? ar : c - 1;
    float acc[4][4] = {};
    for (int k0 = 0; k0 < K; k0 += 16) {
        float4 a4 = *(const float4*)&A[(size_t)ar * K + k0 + ak];
        float4 b4 = *(const float4*)&B[(size_t)(k0 + bk) * N + n0 + bn];
        __syncthreads();
        As[ak + 0][am] = a4.x;
        As[ak + 1][am] = a4.y;
        As[ak + 2][am] = a4.z;
        As[ak + 3][am] = a4.w;
        *(float4*)&Bs[bk][bn] = b4;
        __syncthreads();
#pragma unroll
        for (int kk = 0; kk < 16; ++kk) {
            float4 av = *(const float4*)&As[kk][tm << 2];
            float4 bv = *(const float4*)&Bs[kk][tn << 2];
            float a[4] = {av.x, av.y, av.z, av.w};
            float b[4] = {bv.x, bv.y, bv.z, bv.w};
#pragma unroll
            for (int i = 0; i < 4; ++i)
#pragma unroll
                for (int j = 0; j < 4; ++j)
                    acc[i][j] = fmaf(a[i], b[j], acc[i][j]);
        }
    }
#pragma unroll
    for (int i = 0; i < 4; ++i) {
        int p = m0 + (tm << 2) + i;
        if (GUARD && p >= c) continue;
        int r = SCAT ? idx[p] : p;
        float* cp = &C[(size_t)r * N + n0 + (tn << 2)];
        float rr[4] = {acc[i][0], acc[i][1], acc[i][2], acc[i][3]};
        if (GELU) {
#pragma unroll
            for (int j = 0; j < 4; ++j) rr[j] = gelu_f(rr[j]);
        }
        if (ADD) {
            float4 cc = *(const float4*)cp;
            rr[0] += cc.x; rr[1] += cc.y; rr[2] += cc.z; rr[3] += cc.w;
        }
        float4 rv = {rr[0], rr[1], rr[2], rr[3]};
        *(float4*)cp = rv;
    }
}

// -------------------- fp32 head GEMM (fallback / compacted blocks 1-2) --------------------
template<bool IDX>
__global__ __launch_bounds__(256) void gemm_nt_head(const float* __restrict__ A,
                                                    const float* __restrict__ Bt,
                                                    float* __restrict__ C,
                                                    const int* __restrict__ idx,
                                                    const int* __restrict__ cnt,
                                                    int N, int K) {
    const int m0 = blockIdx.y * 64, n0 = blockIdx.x * 64;
    int c = IDX ? *cnt : TT;
    if (IDX && m0 >= c) return;
    __shared__ float As[16][68];
    __shared__ float Bs[16][68];
    const int tid = threadIdx.x;
    const int am = tid >> 2, ak = (tid & 3) << 2;
    const int tn = tid & 15, tm = tid >> 4;
    int ar = m0 + am;
    if (IDX) ar = idx[ar < c ? ar : c - 1];
    float acc[4][4] = {};
    for (int k0 = 0; k0 < K; k0 += 16) {
        float4 a4 = *(const float4*)&A[(size_t)ar * K + k0 + ak];
        float4 b4 = *(const float4*)&Bt[(size_t)(n0 + am) * K + k0 + ak];
        __syncthreads();
        As[ak + 0][am] = a4.x;
        As[ak + 1][am] = a4.y;
        As[ak + 2][am] = a4.z;
        As[ak + 3][am] = a4.w;
        Bs[ak + 0][am] = b4.x;
        Bs[ak + 1][am] = b4.y;
        Bs[ak + 2][am] = b4.z;
        Bs[ak + 3][am] = b4.w;
        __syncthreads();
#pragma unroll
        for (int kk = 0; kk < 16; ++kk) {
            float4 av = *(const float4*)&As[kk][tm << 2];
            float4 bv = *(const float4*)&Bs[kk][tn << 2];
            float a[4] = {av.x, av.y, av.z, av.w};
            float b[4] = {bv.x, bv.y, bv.z, bv.w};
#pragma unroll
            for (int i = 0; i < 4; ++i)
#pragma unroll
                for (int j = 0; j < 4; ++j)
                    acc[i][j] = fmaf(a[i], b[j], acc[i][j]);
        }
    }
#pragma unroll
    for (int i = 0; i < 4; ++i) {
        int p = m0 + (tm << 2) + i;
        if (IDX && p >= c) continue;
        int r = IDX ? idx[p] : p;
        float4 rv = {acc[i][0], acc[i][1], acc[i][2], acc[i][3]};
        *(float4*)&C[(size_t)r * N + n0 + (tn << 2)] = rv;
    }
}

// -------------------- confidence + exit (full-row re-read; tiers 2-3 and block 1) ----
template<bool IDX>
__global__ __launch_bounds__(256) void conf_exit(const float* __restrict__ out,
                                                 int* __restrict__ flags,
                                                 const int* __restrict__ idx,
                                                 const int* __restrict__ cnt,
                                                 float thr) {
    int t;
    if (IDX) {
        if (blockIdx.x >= *cnt) return;
        t = idx[blockIdx.x];
    } else {
        t = blockIdx.x;
        if (flags[t] == 0) return;
    }
    const float* row = out + (size_t)t * NVOCAB;
    float m = -INFINITY, s = 0.0f;
    for (int i = threadIdx.x; i < NVOCAB; i += 256) {
        float x = row[i];
        if (x > m) {
            s = s * expf(m - x) + 1.0f;
        } else {
            s += expf(x - m);
        }
        m = fmaxf(m, x);
    }
    __shared__ float ms[256], ss[256];
    ms[threadIdx.x] = m;
    ss[threadIdx.x] = s;
    __syncthreads();
    for (int st = 128; st; st >>= 1) {
        if (threadIdx.x < st) {
            float m1 = ms[threadIdx.x], s1 = ss[threadIdx.x];
            float m2 = ms[threadIdx.x + st], s2 = ss[threadIdx.x + st];
            float mm = fmaxf(m1, m2);
            ss[threadIdx.x] = s1 * expf(m1 - mm) + s2 * expf(m2 - mm);
            ms[threadIdx.x] = mm;
        }
        __syncthreads();
    }
    if (threadIdx.x == 0) {
        float conf = 1.0f / ss[0];
        if (conf > thr) flags[t] = 0;
    }
}

// -------------------- ordered compaction of active tokens (single block) --------------------
__global__ __launch_bounds__(256) void compact_kernel(const int* __restrict__ flags,
                                                      int* __restrict__ idx,
                                                      int* __restrict__ cnt) {
    __shared__ int wsum[4];
    __shared__ int base;
    if (threadIdx.x == 0) base = 0;
    int lane = threadIdx.x & 63, wv = threadIdx.x >> 6;
    for (int chunk = 0; chunk < TT; chunk += 256) {
        __syncthreads();
        int t = chunk + threadIdx.x;
        int f = flags[t];
        unsigned long long b = __ballot(f != 0);
        if (lane == 0) wsum[wv] = __popcll(b);
        __syncthreads();
        int off = base;
        for (int w = 0; w < wv; ++w) off += wsum[w];
        off += __popcll(b & ((1ull << lane) - 1));
        if (f) idx[off] = t;
        __syncthreads();
        if (threadIdx.x == 0) base += wsum[0] + wsum[1] + wsum[2] + wsum[3];
    }
    __syncthreads();
    if (threadIdx.x == 0) *cnt = base;
}

extern "C" void kernel_launch(void* const* d_in, const int* in_sizes, int n_in,
                              void* d_out, int out_size, void* d_ws, size_t ws_size,
                              hipStream_t stream) {
    const int* x = (const int*)d_in[0];
    const float* emb = (const float*)d_in[1];
    const float* head = (const float*)d_in[2];
    const float* Wv = (const float*)d_in[3];
    const float* Wo = (const float*)d_in[4];
    const float* W1 = (const float*)d_in[5];
    const float* W2 = (const float*)d_in[6];
    const float* ln1s = (const float*)d_in[7];
    const float* ln1b = (const float*)d_in[8];
    const float* ln2s = (const float*)d_in[9];
    const float* ln2b = (const float*)d_in[10];
    float* out = (float*)d_out;
    float* ws = (float*)d_ws;

    float* h  = ws;                      // TT*DIM fp32
    float* hn = ws + 2097152;            // TT*DIM
    float* tA = ws + 4194304;            // TT*DIM (scratch: WvFlat hi/lo during setup)
    float* tF = ws + 6291456;            // TT*FFN
    short* hnHi = (short*)hn;
    short* hnLo = hnHi + TT * DIM;
    short* tAHi = (short*)tA;
    short* tALo = tAHi + TT * DIM;
    short* tFHi = (short*)tF;
    short* tFLo = tFHi + TT * FFN;
    int* flags = (int*)(ws + 14680064);  // TT
    int* idxl  = flags + TT;             // TT
    int* cntp  = flags + 2 * TT;         // 1
    short* hHi    = (short*)(ws + 14700000);
    short* hLo    = (short*)(ws + 15748576);
    short* headHi = (short*)(ws + 16797152);
    short* headLo = (short*)(ws + 24989152);
    short* wT     = (short*)(ws + 33181152);  // 2 layers x 5242880 shorts
    float2* pp = (float2*)(ws + 38424032);    // TT*NT float2
    const size_t LSTRIDE = 5242880;
    const size_t NEED_T2 = (size_t)33181152 * 4;
    const size_t NEED_T1 = (size_t)40472032 * 4;
    const int tier = ws_size >= NEED_T1 ? 1 : (ws_size >= NEED_T2 ? 2 : 3);

    gather_kernel<<<TT, 128, 0, stream>>>(x, emb, h, flags);

    const float THR[3] = {3.5e-05f, 4.0e-05f, 1.0f};
    const dim3 gDD(DIM / 64, TT / 64), gDF(FFN / 64, TT / 64), gHead(NVOCAB / 64, TT / 64);

    // ---------- block 0: dense ----------
    if (tier == 1) {
        // weight prep: WoT, W1T, W2T transpose-splits; W_voT = WoT @ WvFlat (MFMA)
        for (int l = 0; l < 2; ++l) {
            short* wb = wT + (size_t)l * LSTRIDE;
            cvt_hilo<<<(DIM * DIM / 4 + 255) / 256, 256, 0, stream>>>(Wv + (size_t)l * DIM * DIM, tAHi, tALo, DIM * DIM / 4);
            cvt_w_t<<<dim3(DIM / 32, DIM / 32), 256, 0, stream>>>(Wo + (size_t)l * DIM * DIM, wb + 524288, wb + 786432, DIM, DIM);
            // W_voT[n][k] = sum_j WoT[n][j] * Wv[k][j]
            gemm_l_mfma<0><<<dim3(DIM / 128, DIM / 128), 256, 0, stream>>>(
                wb + 524288, wb + 786432, tAHi, tALo, nullptr, wb, wb + 262144, DIM, DIM);
            cvt_w_t<<<dim3(FFN / 32, DIM / 32), 256, 0, stream>>>(W1 + (size_t)l * DIM * FFN, wb + 1048576, wb + 2097152, DIM, FFN);
            cvt_w_t<<<dim3(DIM / 32, FFN / 32), 256, 0, stream>>>(W2 + (size_t)l * FFN * DIM, wb + 3145728, wb + 4194304, FFN, DIM);
        }
        for (int l = 0; l < 2; ++l) {
            short* wb = wT + (size_t)l * LSTRIDE;
            ln_hilo<<<TT / 4, 256, 0, stream>>>(h, ln1s + l * DIM, ln1b + l * DIM, hnHi, hnLo);
            gemm_l_mfma<2><<<dim3(TT / 128, DIM / 128), 256, 0, stream>>>(hnHi, hnLo, wb, wb + 262144, h, nullptr, nullptr, DIM, DIM);
            ln_hilo<<<TT / 4, 256, 0, stream>>>(h, ln2s + l * DIM, ln2b + l * DIM, hnHi, hnLo);
            gemm_l_mfma<1><<<dim3(TT / 128, FFN / 128), 256, 0, stream>>>(hnHi, hnLo, wb + 1048576, wb + 2097152, nullptr, tFHi, tFLo, FFN, DIM);
            if (l == 1) {
                gemm_l_mfma<4><<<dim3(TT / 128, DIM / 128), 256, 0, stream>>>(tFHi, tFLo, wb + 3145728, wb + 4194304, h, hHi, hLo, DIM, FFN);
            } else {
                gemm_l_mfma<2><<<dim3(TT / 128, DIM / 128), 256, 0, stream>>>(tFHi, tFLo, wb + 3145728, wb + 4194304, h, nullptr, nullptr, DIM, FFN);
            }
        }
        cvt_hilo<<<(NVOCAB * DIM / 4 + 255) / 256, 256, 0, stream>>>(head, headHi, headLo, NVOCAB * DIM / 4);
        gemm_head_fused<<<dim3(TT / 128, NVOCAB / 128), 256, 0, stream>>>(hHi, hLo, headHi, headLo, out, pp);
        conf_reduce<<<TT / 4, 256, 0, stream>>>(pp, flags, THR[0]);
    } else {
        for (int l = 0; l < 2; ++l) {
            ln_kernel<false><<<TT / 4, 256, 0, stream>>>(h, ln1s + l * DIM, ln1b + l * DIM, hn, nullptr, nullptr);
            gemm_nn<false, false, false, false><<<gDD, 256, 0, stream>>>(hn, Wv + (size_t)l * DIM * DIM, tA, TT, DIM, DIM, nullptr, nullptr);
            gemm_nn<true, false, false, false><<<gDD, 256, 0, stream>>>(tA, Wo + (size_t)l * DIM * DIM, h, TT, DIM, DIM, nullptr, nullptr);
            ln_kernel<false><<<TT / 4, 256, 0, stream>>>(h, ln2s + l * DIM, ln2b + l * DIM, hn, nullptr, nullptr);
            gemm_nn<false, true, false, false><<<gDF, 256, 0, stream>>>(hn, W1 + (size_t)l * DIM * FFN, tF, TT, FFN, DIM, nullptr, nullptr);
            gemm_nn<true, false, false, false><<<gDD, 256, 0, stream>>>(tF, W2 + (size_t)l * FFN * DIM, h, TT, DIM, FFN, nullptr, nullptr);
        }
        if (tier == 2) {
            cvt_hilo<<<(TT * DIM / 4 + 255) / 256, 256, 0, stream>>>(h, hHi, hLo, TT * DIM / 4);
            cvt_hilo<<<(NVOCAB * DIM / 4 + 255) / 256, 256, 0, stream>>>(head, headHi, headLo, NVOCAB * DIM / 4);
            gemm_l_mfma<3><<<dim3(TT / 128, NVOCAB / 128), 256, 0, stream>>>(hHi, hLo, headHi, headLo, out, nullptr, nullptr, NVOCAB, DIM);
        } else {
            gemm_nt_head<false><<<gHead, 256, 0, stream>>>(h, head, out, nullptr, nullptr, NVOCAB, DIM);
        }
        conf_exit<false><<<TT, 256, 0, stream>>>(out, flags, nullptr, nullptr, THR[0]);
    }
    compact_kernel<<<1, 256, 0, stream>>>(flags, idxl, cntp);

    // ---------- blocks 1,2: compacted active rows (fp32 path; ~empty on this input) ----------
    for (int b = 1; b < 3; ++b) {
        for (int li = 0; li < 2; ++li) {
            int l = b * 2 + li;
            ln_kernel<true><<<TT / 4, 256, 0, stream>>>(h, ln1s + l * DIM, ln1b + l * DIM, hn, idxl, cntp);
            gemm_nn<false, false, true, false><<<gDD, 256, 0, stream>>>(hn, Wv + (size_t)l * DIM * DIM, tA, TT, DIM, DIM, idxl, cntp);
            gemm_nn<true, false, true, true><<<gDD, 256, 0, stream>>>(tA, Wo + (size_t)l * DIM * DIM, h, TT, DIM, DIM, idxl, cntp);
            ln_kernel<true><<<TT / 4, 256, 0, stream>>>(h, ln2s + l * DIM, ln2b + l * DIM, hn, idxl, cntp);
            gemm_nn<false, true, true, false><<<gDF, 256, 0, stream>>>(hn, W1 + (size_t)l * DIM * FFN, tF, TT, FFN, DIM, idxl, cntp);
            gemm_nn<true, false, true, true><<<gDD, 256, 0, stream>>>(tF, W2 + (size_t)l * FFN * DIM, h, TT, DIM, FFN, idxl, cntp);
        }
        gemm_nt_head<true><<<gHead, 256, 0, stream>>>(h, head, out, idxl, cntp, NVOCAB, DIM);
        if (b == 1) {
            conf_exit<true><<<TT, 256, 0, stream>>>(out, flags, idxl, cntp, THR[1]);
            compact_kernel<<<1, 256, 0, stream>>>(flags, idxl, cntp);
        }
    }
}

// Round 9
// 1042.301 us; speedup vs baseline: 1.0287x; 1.0287x over previous
//
#include <hip/hip_runtime.h>
#include <hip/hip_bf16.h>
#include <math.h>

#define TT 4096
#define DIM 512
#define FFN 2048
#define NVOCAB 32000

typedef __attribute__((ext_vector_type(8))) short short8_t;
typedef __attribute__((ext_vector_type(4))) float f32x4;

__device__ __forceinline__ float gelu_f(float x) {
    float x3 = x * x * x;
    float u = 0.7978845608028654f * (x + 0.044715f * x3);
    return 0.5f * x * (1.0f + tanhf(u));
}

__device__ __forceinline__ unsigned short f2bf_rn(float f) {
    unsigned u = __float_as_uint(f);
    u += 0x7FFFu + ((u >> 16) & 1u);
    return (unsigned short)(u >> 16);
}

// -------------------- embedding gather + flag init --------------------
__global__ __launch_bounds__(128) void gather_kernel(const int* __restrict__ x,
                                                     const float* __restrict__ emb,
                                                     float* __restrict__ h,
                                                     int* __restrict__ flags) {
    int t = blockIdx.x;
    int idx = x[t];
    const float4 v = *(const float4*)&emb[(size_t)idx * DIM + threadIdx.x * 4];
    *(float4*)&h[(size_t)t * DIM + threadIdx.x * 4] = v;
    if (threadIdx.x == 0) flags[t] = 1;
}

// -------------------- fp32 -> bf16 hi/lo split (flat) --------------------
__global__ __launch_bounds__(256) void cvt_hilo(const float* __restrict__ src,
                                                short* __restrict__ hi,
                                                short* __restrict__ lo, int n4) {
    int i = blockIdx.x * 256 + threadIdx.x;
    if (i >= n4) return;
    float4 v = *(const float4*)&src[(size_t)i * 4];
    float f[4] = {v.x, v.y, v.z, v.w};
    short4 hv, lv;
    short* hp = &hv.x;
    short* lp = &lv.x;
#pragma unroll
    for (int j = 0; j < 4; ++j) {
        unsigned short hb = f2bf_rn(f[j]);
        float hf = __uint_as_float((unsigned)hb << 16);
        unsigned short lb = f2bf_rn(f[j] - hf);
        hp[j] = (short)hb;
        lp[j] = (short)lb;
    }
    *(short4*)&hi[(size_t)i * 4] = hv;
    *(short4*)&lo[(size_t)i * 4] = lv;
}

// -------------------- fp32 W (K,N) -> bf16 hi/lo transposed (N,K) --------------------
__global__ __launch_bounds__(256) void cvt_w_t(const float* __restrict__ W,
                                               short* __restrict__ hiT,
                                               short* __restrict__ loT,
                                               int K, int N) {
    __shared__ short hs[32][36];
    __shared__ short ls[32][36];
    const int n0 = blockIdx.x * 32, k0 = blockIdx.y * 32;
    const int r = threadIdx.x >> 3, c4 = (threadIdx.x & 7) << 2;
    float4 v = *(const float4*)&W[(size_t)(k0 + r) * N + n0 + c4];
    float f[4] = {v.x, v.y, v.z, v.w};
#pragma unroll
    for (int j = 0; j < 4; ++j) {
        unsigned short hb = f2bf_rn(f[j]);
        float hf = __uint_as_float((unsigned)hb << 16);
        unsigned short lb = f2bf_rn(f[j] - hf);
        hs[r][c4 + j] = (short)hb;
        ls[r][c4 + j] = (short)lb;
    }
    __syncthreads();
    const int nr = threadIdx.x >> 3, kc4 = (threadIdx.x & 7) << 2;
    short4 hv, lv;
    short* hp = &hv.x;
    short* lp = &lv.x;
#pragma unroll
    for (int j = 0; j < 4; ++j) {
        hp[j] = hs[kc4 + j][nr];
        lp[j] = ls[kc4 + j][nr];
    }
    *(short4*)&hiT[(size_t)(n0 + nr) * K + k0 + kc4] = hv;
    *(short4*)&loT[(size_t)(n0 + nr) * K + k0 + kc4] = lv;
}

// -------------------- LayerNorm (fp32 out; optional index gather) --------------------
template<bool IDX>
__global__ __launch_bounds__(256) void ln_kernel(const float* __restrict__ x,
                                                 const float* __restrict__ gam,
                                                 const float* __restrict__ bet,
                                                 float* __restrict__ out,
                                                 const int* __restrict__ idx,
                                                 const int* __restrict__ cnt) {
    int wv = threadIdx.x >> 6, lane = threadIdx.x & 63;
    int p = (blockIdx.x << 2) | wv;
    if (IDX && p >= *cnt) return;
    int t = IDX ? idx[p] : p;
    const float* row = x + (size_t)t * DIM;
    int base = lane * 8;
    float4 v0 = *(const float4*)&row[base];
    float4 v1 = *(const float4*)&row[base + 4];
    float s = v0.x + v0.y + v0.z + v0.w + v1.x + v1.y + v1.z + v1.w;
#pragma unroll
    for (int o = 32; o; o >>= 1) s += __shfl_xor(s, o, 64);
    float mean = s * (1.0f / (float)DIM);
    float d0 = v0.x - mean, d1 = v0.y - mean, d2 = v0.z - mean, d3 = v0.w - mean;
    float d4 = v1.x - mean, d5 = v1.y - mean, d6 = v1.z - mean, d7 = v1.w - mean;
    float q = d0*d0 + d1*d1 + d2*d2 + d3*d3 + d4*d4 + d5*d5 + d6*d6 + d7*d7;
#pragma unroll
    for (int o = 32; o; o >>= 1) q += __shfl_xor(q, o, 64);
    float var = q * (1.0f / (float)DIM);
    float rs = 1.0f / sqrtf(var + 1e-5f);
    float4 g0 = *(const float4*)&gam[base];
    float4 g1 = *(const float4*)&gam[base + 4];
    float4 b0 = *(const float4*)&bet[base];
    float4 b1 = *(const float4*)&bet[base + 4];
    float4 o0, o1;
    o0.x = d0 * rs * g0.x + b0.x;  o0.y = d1 * rs * g0.y + b0.y;
    o0.z = d2 * rs * g0.z + b0.z;  o0.w = d3 * rs * g0.w + b0.w;
    o1.x = d4 * rs * g1.x + b1.x;  o1.y = d5 * rs * g1.y + b1.y;
    o1.z = d6 * rs * g1.z + b1.z;  o1.w = d7 * rs * g1.w + b1.w;
    float* orow = out + (size_t)p * DIM;
    *(float4*)&orow[base] = o0;
    *(float4*)&orow[base + 4] = o1;
}

// -------------------- LayerNorm -> bf16 hi/lo (dense, block 0) --------------------
__global__ __launch_bounds__(256) void ln_hilo(const float* __restrict__ x,
                                               const float* __restrict__ gam,
                                               const float* __restrict__ bet,
                                               short* __restrict__ ohi,
                                               short* __restrict__ olo) {
    int wv = threadIdx.x >> 6, lane = threadIdx.x & 63;
    int t = (blockIdx.x << 2) | wv;
    const float* row = x + (size_t)t * DIM;
    int base = lane * 8;
    float4 v0 = *(const float4*)&row[base];
    float4 v1 = *(const float4*)&row[base + 4];
    float s = v0.x + v0.y + v0.z + v0.w + v1.x + v1.y + v1.z + v1.w;
#pragma unroll
    for (int o = 32; o; o >>= 1) s += __shfl_xor(s, o, 64);
    float mean = s * (1.0f / (float)DIM);
    float d[8] = {v0.x - mean, v0.y - mean, v0.z - mean, v0.w - mean,
                  v1.x - mean, v1.y - mean, v1.z - mean, v1.w - mean};
    float q = 0.0f;
#pragma unroll
    for (int j = 0; j < 8; ++j) q += d[j] * d[j];
#pragma unroll
    for (int o = 32; o; o >>= 1) q += __shfl_xor(q, o, 64);
    float var = q * (1.0f / (float)DIM);
    float rs = 1.0f / sqrtf(var + 1e-5f);
    float g[8], bb[8];
    *(float4*)&g[0] = *(const float4*)&gam[base];
    *(float4*)&g[4] = *(const float4*)&gam[base + 4];
    *(float4*)&bb[0] = *(const float4*)&bet[base];
    *(float4*)&bb[4] = *(const float4*)&bet[base + 4];
    short8_t hv, lv;
#pragma unroll
    for (int j = 0; j < 8; ++j) {
        float val = d[j] * rs * g[j] + bb[j];
        unsigned short hb = f2bf_rn(val);
        float hf = __uint_as_float((unsigned)hb << 16);
        hv[j] = (short)hb;
        lv[j] = (short)f2bf_rn(val - hf);
    }
    *(short8_t*)&ohi[(size_t)t * DIM + base] = hv;
    *(short8_t*)&olo[(size_t)t * DIM + base] = lv;
}

// -------------------- split-bf16 MFMA GEMM (128x128): C(M,N) = A(M,K) @ B(N,K)^T -----
// EPI: 0 = store hi/lo bf16; 1 = gelu + store hi/lo; 2 = residual add into Cf;
//      3 = plain fp32 store; 4 = residual add into Cf AND store hi/lo of the sum.
template<int EPI>
__global__ __launch_bounds__(256) void gemm_l_mfma(const short* __restrict__ Ah,
                                                   const short* __restrict__ Al,
                                                   const short* __restrict__ Bh,
                                                   const short* __restrict__ Bl,
                                                   float* __restrict__ Cf,
                                                   short* __restrict__ oHi,
                                                   short* __restrict__ oLo,
                                                   int N, int K) {
    __shared__ __align__(16) short sm[16384];
    short* sAh = sm;
    short* sAl = sm + 4096;
    short* sBh = sm + 8192;
    short* sBl = sm + 12288;
    const int tid = threadIdx.x;
    const int wv = tid >> 6, lane = tid & 63;
    const int m0 = blockIdx.x * 128;
    const int n0 = blockIdx.y * 128;
    const int wm = (wv & 1) * 64, wn = (wv >> 1) * 64;
    const int r16 = lane >> 2;
    const int gsw = ((lane & 3) ^ (r16 & 3)) << 3;
    const int fr = lane & 15;
    const int q = lane >> 4;

    f32x4 acc[4][4];
#pragma unroll
    for (int i = 0; i < 4; ++i)
#pragma unroll
        for (int j = 0; j < 4; ++j)
            acc[i][j] = (f32x4){0.0f, 0.0f, 0.0f, 0.0f};

    const int NKT = K >> 5;
    for (int kt = 0; kt < NKT; ++kt) {
        const int k0 = kt << 5;
        __syncthreads();
#pragma unroll
        for (int j = 0; j < 2; ++j) {
            const int rr = (wv << 5) + (j << 4);
            const int gr = rr + r16;
            const short* ga_h = Ah + (size_t)(m0 + gr) * K + k0 + gsw;
            const short* ga_l = Al + (size_t)(m0 + gr) * K + k0 + gsw;
            const short* gb_h = Bh + (size_t)(n0 + gr) * K + k0 + gsw;
            const short* gb_l = Bl + (size_t)(n0 + gr) * K + k0 + gsw;
            __builtin_amdgcn_global_load_lds((const __attribute__((address_space(1))) void*)ga_h,
                                             (__attribute__((address_space(3))) void*)(sAh + rr * 32), 16, 0, 0);
            __builtin_amdgcn_global_load_lds((const __attribute__((address_space(1))) void*)ga_l,
                                             (__attribute__((address_space(3))) void*)(sAl + rr * 32), 16, 0, 0);
            __builtin_amdgcn_global_load_lds((const __attribute__((address_space(1))) void*)gb_h,
                                             (__attribute__((address_space(3))) void*)(sBh + rr * 32), 16, 0, 0);
            __builtin_amdgcn_global_load_lds((const __attribute__((address_space(1))) void*)gb_l,
                                             (__attribute__((address_space(3))) void*)(sBl + rr * 32), 16, 0, 0);
        }
        __syncthreads();
        short8_t ah[4], al[4], bh[4], bl[4];
#pragma unroll
        for (int i = 0; i < 4; ++i) {
            const int ra = wm + i * 16 + fr;
            const int rb = wn + i * 16 + fr;
            const int swa = (q ^ (fr & 3)) << 3;
            ah[i] = *(const short8_t*)&sAh[ra * 32 + swa];
            al[i] = *(const short8_t*)&sAl[ra * 32 + swa];
            bh[i] = *(const short8_t*)&sBh[rb * 32 + swa];
            bl[i] = *(const short8_t*)&sBl[rb * 32 + swa];
        }
#pragma unroll
        for (int i = 0; i < 4; ++i)
#pragma unroll
            for (int j = 0; j < 4; ++j) {
                acc[i][j] = __builtin_amdgcn_mfma_f32_16x16x32_bf16(ah[i], bh[j], acc[i][j], 0, 0, 0);
                acc[i][j] = __builtin_amdgcn_mfma_f32_16x16x32_bf16(ah[i], bl[j], acc[i][j], 0, 0, 0);
                acc[i][j] = __builtin_amdgcn_mfma_f32_16x16x32_bf16(al[i], bh[j], acc[i][j], 0, 0, 0);
            }
    }
    const int row_base = (lane >> 4) << 2;
#pragma unroll
    for (int i = 0; i < 4; ++i)
#pragma unroll
        for (int j = 0; j < 4; ++j) {
            const int row = m0 + wm + i * 16 + row_base;
            const int col = n0 + wn + j * 16 + fr;
#pragma unroll
            for (int r = 0; r < 4; ++r) {
                float val = acc[i][j][r];
                if (EPI == 3) {
                    Cf[(size_t)(row + r) * N + col] = val;
                } else if (EPI == 2) {
                    Cf[(size_t)(row + r) * N + col] += val;
                } else if (EPI == 4) {
                    float* cp = &Cf[(size_t)(row + r) * N + col];
                    float nv = *cp + val;
                    *cp = nv;
                    unsigned short hb = f2bf_rn(nv);
                    float hf = __uint_as_float((unsigned)hb << 16);
                    oHi[(size_t)(row + r) * N + col] = (short)hb;
                    oLo[(size_t)(row + r) * N + col] = (short)f2bf_rn(nv - hf);
                } else {
                    if (EPI == 1) val = gelu_f(val);
                    unsigned short hb = f2bf_rn(val);
                    float hf = __uint_as_float((unsigned)hb << 16);
                    oHi[(size_t)(row + r) * N + col] = (short)hb;
                    oLo[(size_t)(row + r) * N + col] = (short)f2bf_rn(val - hf);
                }
            }
        }
}

// -------------------- fp32 tiled GEMM (blocks 1-2 compact path) --------------------
template<bool ADD, bool GELU, bool GUARD, bool SCAT>
__global__ __launch_bounds__(256) void gemm_nn(const float* __restrict__ A,
                                               const float* __restrict__ B,
                                               float* __restrict__ C,
                                               int M, int N, int K,
                                               const int* __restrict__ idx,
                                               const int* __restrict__ cnt) {
    const int m0 = blockIdx.y * 64, n0 = blockIdx.x * 64;
    int c = GUARD ? *cnt : M;
    if (GUARD && m0 >= c) return;
    __shared__ float As[16][68];
    __shared__ float Bs[16][68];
    const int tid = threadIdx.x;
    const int am = tid >> 2, ak = (tid & 3) << 2;
    const int bk = tid >> 4, bn = (tid & 15) << 2;
    const int tn = tid & 15, tm = tid >> 4;
    int ar = m0 + am;
    if (GUARD) ar = ar < c ? ar : c - 1;
    float acc[4][4] = {};
    for (int k0 = 0; k0 < K; k0 += 16) {
        float4 a4 = *(const float4*)&A[(size_t)ar * K + k0 + ak];
        float4 b4 = *(const float4*)&B[(size_t)(k0 + bk) * N + n0 + bn];
        __syncthreads();
        As[ak + 0][am] = a4.x;
        As[ak + 1][am] = a4.y;
        As[ak + 2][am] = a4.z;
        As[ak + 3][am] = a4.w;
        *(float4*)&Bs[bk][bn] = b4;
        __syncthreads();
#pragma unroll
        for (int kk = 0; kk < 16; ++kk) {
            float4 av = *(const float4*)&As[kk][tm << 2];
            float4 bv = *(const float4*)&Bs[kk][tn << 2];
            float a[4] = {av.x, av.y, av.z, av.w};
            float b[4] = {bv.x, bv.y, bv.z, bv.w};
#pragma unroll
            for (int i = 0; i < 4; ++i)
#pragma unroll
                for (int j = 0; j < 4; ++j)
                    acc[i][j] = fmaf(a[i], b[j], acc[i][j]);
        }
    }
#pragma unroll
    for (int i = 0; i < 4; ++i) {
        int p = m0 + (tm << 2) + i;
        if (GUARD && p >= c) continue;
        int r = SCAT ? idx[p] : p;
        float* cp = &C[(size_t)r * N + n0 + (tn << 2)];
        float rr[4] = {acc[i][0], acc[i][1], acc[i][2], acc[i][3]};
        if (GELU) {
#pragma unroll
            for (int j = 0; j < 4; ++j) rr[j] = gelu_f(rr[j]);
        }
        if (ADD) {
            float4 cc = *(const float4*)cp;
            rr[0] += cc.x; rr[1] += cc.y; rr[2] += cc.z; rr[3] += cc.w;
        }
        float4 rv = {rr[0], rr[1], rr[2], rr[3]};
        *(float4*)cp = rv;
    }
}

// -------------------- fp32 head GEMM (fallback / compacted blocks 1-2) --------------------
template<bool IDX>
__global__ __launch_bounds__(256) void gemm_nt_head(const float* __restrict__ A,
                                                    const float* __restrict__ Bt,
                                                    float* __restrict__ C,
                                                    const int* __restrict__ idx,
                                                    const int* __restrict__ cnt,
                                                    int N, int K) {
    const int m0 = blockIdx.y * 64, n0 = blockIdx.x * 64;
    int c = IDX ? *cnt : TT;
    if (IDX && m0 >= c) return;
    __shared__ float As[16][68];
    __shared__ float Bs[16][68];
    const int tid = threadIdx.x;
    const int am = tid >> 2, ak = (tid & 3) << 2;
    const int tn = tid & 15, tm = tid >> 4;
    int ar = m0 + am;
    if (IDX) ar = idx[ar < c ? ar : c - 1];
    float acc[4][4] = {};
    for (int k0 = 0; k0 < K; k0 += 16) {
        float4 a4 = *(const float4*)&A[(size_t)ar * K + k0 + ak];
        float4 b4 = *(const float4*)&Bt[(size_t)(n0 + am) * K + k0 + ak];
        __syncthreads();
        As[ak + 0][am] = a4.x;
        As[ak + 1][am] = a4.y;
        As[ak + 2][am] = a4.z;
        As[ak + 3][am] = a4.w;
        Bs[ak + 0][am] = b4.x;
        Bs[ak + 1][am] = b4.y;
        Bs[ak + 2][am] = b4.z;
        Bs[ak + 3][am] = b4.w;
        __syncthreads();
#pragma unroll
        for (int kk = 0; kk < 16; ++kk) {
            float4 av = *(const float4*)&As[kk][tm << 2];
            float4 bv = *(const float4*)&Bs[kk][tn << 2];
            float a[4] = {av.x, av.y, av.z, av.w};
            float b[4] = {bv.x, bv.y, bv.z, bv.w};
#pragma unroll
            for (int i = 0; i < 4; ++i)
#pragma unroll
                for (int j = 0; j < 4; ++j)
                    acc[i][j] = fmaf(a[i], b[j], acc[i][j]);
        }
    }
#pragma unroll
    for (int i = 0; i < 4; ++i) {
        int p = m0 + (tm << 2) + i;
        if (IDX && p >= c) continue;
        int r = IDX ? idx[p] : p;
        float4 rv = {acc[i][0], acc[i][1], acc[i][2], acc[i][3]};
        *(float4*)&C[(size_t)r * N + n0 + (tn << 2)] = rv;
    }
}

// -------------------- confidence + exit (vectorized full-row read) --------------------
template<bool IDX>
__global__ __launch_bounds__(256) void conf_exit(const float* __restrict__ out,
                                                 int* __restrict__ flags,
                                                 const int* __restrict__ idx,
                                                 const int* __restrict__ cnt,
                                                 float thr) {
    int t;
    if (IDX) {
        if (blockIdx.x >= *cnt) return;
        t = idx[blockIdx.x];
    } else {
        t = blockIdx.x;
        if (flags[t] == 0) return;
    }
    const float4* row = (const float4*)(out + (size_t)t * NVOCAB);  // 8000 float4
    float m = -INFINITY, s = 0.0f;
    for (int i = threadIdx.x; i < NVOCAB / 4; i += 256) {
        float4 v = row[i];
        float m4 = fmaxf(fmaxf(v.x, v.y), fmaxf(v.z, v.w));
        float s4 = __expf(v.x - m4) + __expf(v.y - m4) + __expf(v.z - m4) + __expf(v.w - m4);
        if (m4 > m) {
            s = s * __expf(m - m4) + s4;
            m = m4;
        } else {
            s += s4 * __expf(m4 - m);
        }
    }
    __shared__ float ms[256], ss[256];
    ms[threadIdx.x] = m;
    ss[threadIdx.x] = s;
    __syncthreads();
    for (int st = 128; st; st >>= 1) {
        if (threadIdx.x < st) {
            float m1 = ms[threadIdx.x], s1 = ss[threadIdx.x];
            float m2 = ms[threadIdx.x + st], s2 = ss[threadIdx.x + st];
            float mm = fmaxf(m1, m2);
            ss[threadIdx.x] = s1 * __expf(m1 - mm) + s2 * __expf(m2 - mm);
            ms[threadIdx.x] = mm;
        }
        __syncthreads();
    }
    if (threadIdx.x == 0) {
        float conf = 1.0f / ss[0];
        if (conf > thr) flags[t] = 0;
    }
}

// -------------------- ordered compaction of active tokens (single block) --------------------
__global__ __launch_bounds__(256) void compact_kernel(const int* __restrict__ flags,
                                                      int* __restrict__ idx,
                                                      int* __restrict__ cnt) {
    __shared__ int wsum[4];
    __shared__ int base;
    if (threadIdx.x == 0) base = 0;
    int lane = threadIdx.x & 63, wv = threadIdx.x >> 6;
    for (int chunk = 0; chunk < TT; chunk += 256) {
        __syncthreads();
        int t = chunk + threadIdx.x;
        int f = flags[t];
        unsigned long long b = __ballot(f != 0);
        if (lane == 0) wsum[wv] = __popcll(b);
        __syncthreads();
        int off = base;
        for (int w = 0; w < wv; ++w) off += wsum[w];
        off += __popcll(b & ((1ull << lane) - 1));
        if (f) idx[off] = t;
        __syncthreads();
        if (threadIdx.x == 0) base += wsum[0] + wsum[1] + wsum[2] + wsum[3];
    }
    __syncthreads();
    if (threadIdx.x == 0) *cnt = base;
}

extern "C" void kernel_launch(void* const* d_in, const int* in_sizes, int n_in,
                              void* d_out, int out_size, void* d_ws, size_t ws_size,
                              hipStream_t stream) {
    const int* x = (const int*)d_in[0];
    const float* emb = (const float*)d_in[1];
    const float* head = (const float*)d_in[2];
    const float* Wv = (const float*)d_in[3];
    const float* Wo = (const float*)d_in[4];
    const float* W1 = (const float*)d_in[5];
    const float* W2 = (const float*)d_in[6];
    const float* ln1s = (const float*)d_in[7];
    const float* ln1b = (const float*)d_in[8];
    const float* ln2s = (const float*)d_in[9];
    const float* ln2b = (const float*)d_in[10];
    float* out = (float*)d_out;
    float* ws = (float*)d_ws;

    float* h  = ws;                      // TT*DIM fp32
    float* hn = ws + 2097152;            // TT*DIM
    float* tA = ws + 4194304;            // TT*DIM (scratch: WvFlat hi/lo during setup)
    float* tF = ws + 6291456;            // TT*FFN
    short* hnHi = (short*)hn;
    short* hnLo = hnHi + TT * DIM;
    short* tAHi = (short*)tA;
    short* tALo = tAHi + TT * DIM;
    short* tFHi = (short*)tF;
    short* tFLo = tFHi + TT * FFN;
    int* flags = (int*)(ws + 14680064);  // TT
    int* idxl  = flags + TT;             // TT
    int* cntp  = flags + 2 * TT;         // 1
    short* hHi    = (short*)(ws + 14700000);
    short* hLo    = (short*)(ws + 15748576);
    short* headHi = (short*)(ws + 16797152);
    short* headLo = (short*)(ws + 24989152);
    short* wT     = (short*)(ws + 33181152);  // 2 layers x 5242880 shorts
    const size_t LSTRIDE = 5242880;
    const size_t NEED_T2 = (size_t)33181152 * 4;
    const size_t NEED_T1 = (size_t)38424032 * 4;
    const int tier = ws_size >= NEED_T1 ? 1 : (ws_size >= NEED_T2 ? 2 : 3);

    gather_kernel<<<TT, 128, 0, stream>>>(x, emb, h, flags);

    const float THR[3] = {3.5e-05f, 4.0e-05f, 1.0f};
    const dim3 gDD(DIM / 64, TT / 64), gDF(FFN / 64, TT / 64), gHead(NVOCAB / 64, TT / 64);

    // ---------- block 0: dense ----------
    if (tier == 1) {
        // weight prep: WoT, W1T, W2T transpose-splits; W_voT = WoT @ WvFlat (MFMA)
        for (int l = 0; l < 2; ++l) {
            short* wb = wT + (size_t)l * LSTRIDE;
            cvt_hilo<<<(DIM * DIM / 4 + 255) / 256, 256, 0, stream>>>(Wv + (size_t)l * DIM * DIM, tAHi, tALo, DIM * DIM / 4);
            cvt_w_t<<<dim3(DIM / 32, DIM / 32), 256, 0, stream>>>(Wo + (size_t)l * DIM * DIM, wb + 524288, wb + 786432, DIM, DIM);
            // W_voT[n][k] = sum_j WoT[n][j] * Wv[k][j]
            gemm_l_mfma<0><<<dim3(DIM / 128, DIM / 128), 256, 0, stream>>>(
                wb + 524288, wb + 786432, tAHi, tALo, nullptr, wb, wb + 262144, DIM, DIM);
            cvt_w_t<<<dim3(FFN / 32, DIM / 32), 256, 0, stream>>>(W1 + (size_t)l * DIM * FFN, wb + 1048576, wb + 2097152, DIM, FFN);
            cvt_w_t<<<dim3(DIM / 32, FFN / 32), 256, 0, stream>>>(W2 + (size_t)l * FFN * DIM, wb + 3145728, wb + 4194304, FFN, DIM);
        }
        for (int l = 0; l < 2; ++l) {
            short* wb = wT + (size_t)l * LSTRIDE;
            ln_hilo<<<TT / 4, 256, 0, stream>>>(h, ln1s + l * DIM, ln1b + l * DIM, hnHi, hnLo);
            gemm_l_mfma<2><<<dim3(TT / 128, DIM / 128), 256, 0, stream>>>(hnHi, hnLo, wb, wb + 262144, h, nullptr, nullptr, DIM, DIM);
            ln_hilo<<<TT / 4, 256, 0, stream>>>(h, ln2s + l * DIM, ln2b + l * DIM, hnHi, hnLo);
            gemm_l_mfma<1><<<dim3(TT / 128, FFN / 128), 256, 0, stream>>>(hnHi, hnLo, wb + 1048576, wb + 2097152, nullptr, tFHi, tFLo, FFN, DIM);
            if (l == 1) {
                gemm_l_mfma<4><<<dim3(TT / 128, DIM / 128), 256, 0, stream>>>(tFHi, tFLo, wb + 3145728, wb + 4194304, h, hHi, hLo, DIM, FFN);
            } else {
                gemm_l_mfma<2><<<dim3(TT / 128, DIM / 128), 256, 0, stream>>>(tFHi, tFLo, wb + 3145728, wb + 4194304, h, nullptr, nullptr, DIM, FFN);
            }
        }
        cvt_hilo<<<(NVOCAB * DIM / 4 + 255) / 256, 256, 0, stream>>>(head, headHi, headLo, NVOCAB * DIM / 4);
        gemm_l_mfma<3><<<dim3(TT / 128, NVOCAB / 128), 256, 0, stream>>>(hHi, hLo, headHi, headLo, out, nullptr, nullptr, NVOCAB, DIM);
        conf_exit<false><<<TT, 256, 0, stream>>>(out, flags, nullptr, nullptr, THR[0]);
    } else {
        for (int l = 0; l < 2; ++l) {
            ln_kernel<false><<<TT / 4, 256, 0, stream>>>(h, ln1s + l * DIM, ln1b + l * DIM, hn, nullptr, nullptr);
            gemm_nn<false, false, false, false><<<gDD, 256, 0, stream>>>(hn, Wv + (size_t)l * DIM * DIM, tA, TT, DIM, DIM, nullptr, nullptr);
            gemm_nn<true, false, false, false><<<gDD, 256, 0, stream>>>(tA, Wo + (size_t)l * DIM * DIM, h, TT, DIM, DIM, nullptr, nullptr);
            ln_kernel<false><<<TT / 4, 256, 0, stream>>>(h, ln2s + l * DIM, ln2b + l * DIM, hn, nullptr, nullptr);
            gemm_nn<false, true, false, false><<<gDF, 256, 0, stream>>>(hn, W1 + (size_t)l * DIM * FFN, tF, TT, FFN, DIM, nullptr, nullptr);
            gemm_nn<true, false, false, false><<<gDD, 256, 0, stream>>>(tF, W2 + (size_t)l * FFN * DIM, h, TT, DIM, FFN, nullptr, nullptr);
        }
        if (tier == 2) {
            cvt_hilo<<<(TT * DIM / 4 + 255) / 256, 256, 0, stream>>>(h, hHi, hLo, TT * DIM / 4);
            cvt_hilo<<<(NVOCAB * DIM / 4 + 255) / 256, 256, 0, stream>>>(head, headHi, headLo, NVOCAB * DIM / 4);
            gemm_l_mfma<3><<<dim3(TT / 128, NVOCAB / 128), 256, 0, stream>>>(hHi, hLo, headHi, headLo, out, nullptr, nullptr, NVOCAB, DIM);
        } else {
            gemm_nt_head<false><<<gHead, 256, 0, stream>>>(h, head, out, nullptr, nullptr, NVOCAB, DIM);
        }
        conf_exit<false><<<TT, 256, 0, stream>>>(out, flags, nullptr, nullptr, THR[0]);
    }
    compact_kernel<<<1, 256, 0, stream>>>(flags, idxl, cntp);

    // ---------- blocks 1,2: compacted active rows (fp32 path; ~empty on this input) ----------
    for (int b = 1; b < 3; ++b) {
        for (int li = 0; li < 2; ++li) {
            int l = b * 2 + li;
            ln_kernel<true><<<TT / 4, 256, 0, stream>>>(h, ln1s + l * DIM, ln1b + l * DIM, hn, idxl, cntp);
            gemm_nn<false, false, true, false><<<gDD, 256, 0, stream>>>(hn, Wv + (size_t)l * DIM * DIM, tA, TT, DIM, DIM, idxl, cntp);
            gemm_nn<true, false, true, true><<<gDD, 256, 0, stream>>>(tA, Wo + (size_t)l * DIM * DIM, h, TT, DIM, DIM, idxl, cntp);
            ln_kernel<true><<<TT / 4, 256, 0, stream>>>(h, ln2s + l * DIM, ln2b + l * DIM, hn, idxl, cntp);
            gemm_nn<false, true, true, false><<<gDF, 256, 0, stream>>>(hn, W1 + (size_t)l * DIM * FFN, tF, TT, FFN, DIM, idxl, cntp);
            gemm_nn<true, false, true, true><<<gDD, 256, 0, stream>>>(tF, W2 + (size_t)l * FFN * DIM, h, TT, DIM, FFN, idxl, cntp);
        }
        gemm_nt_head<true><<<gHead, 256, 0, stream>>>(h, head, out, idxl, cntp, NVOCAB, DIM);
        if (b == 1) {
            conf_exit<true><<<TT, 256, 0, stream>>>(out, flags, idxl, cntp, THR[1]);
            compact_kernel<<<1, 256, 0, stream>>>(flags, idxl, cntp);
        }
    }
}

// Round 10
// 968.212 us; speedup vs baseline: 1.1075x; 1.0765x over previous
//
#include <hip/hip_runtime.h>
#include <hip/hip_bf16.h>
#include <math.h>

#define TT 4096
#define DIM 512
#define FFN 2048
#define NVOCAB 32000

typedef __attribute__((ext_vector_type(8))) short short8_t;
typedef __attribute__((ext_vector_type(4))) float f32x4;

__device__ __forceinline__ float gelu_f(float x) {
    float x3 = x * x * x;
    float u = 0.7978845608028654f * (x + 0.044715f * x3);
    return 0.5f * x * (1.0f + tanhf(u));
}

__device__ __forceinline__ unsigned short f2bf_rn(float f) {
    unsigned u = __float_as_uint(f);
    u += 0x7FFFu + ((u >> 16) & 1u);
    return (unsigned short)(u >> 16);
}

// -------------------- embedding gather + flag init --------------------
__global__ __launch_bounds__(128) void gather_kernel(const int* __restrict__ x,
                                                     const float* __restrict__ emb,
                                                     float* __restrict__ h,
                                                     int* __restrict__ flags) {
    int t = blockIdx.x;
    int idx = x[t];
    const float4 v = *(const float4*)&emb[(size_t)idx * DIM + threadIdx.x * 4];
    *(float4*)&h[(size_t)t * DIM + threadIdx.x * 4] = v;
    if (threadIdx.x == 0) flags[t] = 1;
}

// -------------------- fp32 -> bf16 hi/lo split (flat) --------------------
__global__ __launch_bounds__(256) void cvt_hilo(const float* __restrict__ src,
                                                short* __restrict__ hi,
                                                short* __restrict__ lo, int n4) {
    int i = blockIdx.x * 256 + threadIdx.x;
    if (i >= n4) return;
    float4 v = *(const float4*)&src[(size_t)i * 4];
    float f[4] = {v.x, v.y, v.z, v.w};
    short4 hv, lv;
    short* hp = &hv.x;
    short* lp = &lv.x;
#pragma unroll
    for (int j = 0; j < 4; ++j) {
        unsigned short hb = f2bf_rn(f[j]);
        float hf = __uint_as_float((unsigned)hb << 16);
        unsigned short lb = f2bf_rn(f[j] - hf);
        hp[j] = (short)hb;
        lp[j] = (short)lb;
    }
    *(short4*)&hi[(size_t)i * 4] = hv;
    *(short4*)&lo[(size_t)i * 4] = lv;
}

// -------------------- fp32 W (K,N) -> bf16 hi/lo transposed (N,K) --------------------
__global__ __launch_bounds__(256) void cvt_w_t(const float* __restrict__ W,
                                               short* __restrict__ hiT,
                                               short* __restrict__ loT,
                                               int K, int N) {
    __shared__ short hs[32][36];
    __shared__ short ls[32][36];
    const int n0 = blockIdx.x * 32, k0 = blockIdx.y * 32;
    const int r = threadIdx.x >> 3, c4 = (threadIdx.x & 7) << 2;
    float4 v = *(const float4*)&W[(size_t)(k0 + r) * N + n0 + c4];
    float f[4] = {v.x, v.y, v.z, v.w};
#pragma unroll
    for (int j = 0; j < 4; ++j) {
        unsigned short hb = f2bf_rn(f[j]);
        float hf = __uint_as_float((unsigned)hb << 16);
        unsigned short lb = f2bf_rn(f[j] - hf);
        hs[r][c4 + j] = (short)hb;
        ls[r][c4 + j] = (short)lb;
    }
    __syncthreads();
    const int nr = threadIdx.x >> 3, kc4 = (threadIdx.x & 7) << 2;
    short4 hv, lv;
    short* hp = &hv.x;
    short* lp = &lv.x;
#pragma unroll
    for (int j = 0; j < 4; ++j) {
        hp[j] = hs[kc4 + j][nr];
        lp[j] = ls[kc4 + j][nr];
    }
    *(short4*)&hiT[(size_t)(n0 + nr) * K + k0 + kc4] = hv;
    *(short4*)&loT[(size_t)(n0 + nr) * K + k0 + kc4] = lv;
}

// -------------------- LayerNorm (fp32 out; optional index gather) --------------------
template<bool IDX>
__global__ __launch_bounds__(256) void ln_kernel(const float* __restrict__ x,
                                                 const float* __restrict__ gam,
                                                 const float* __restrict__ bet,
                                                 float* __restrict__ out,
                                                 const int* __restrict__ idx,
                                                 const int* __restrict__ cnt) {
    int wv = threadIdx.x >> 6, lane = threadIdx.x & 63;
    int p = (blockIdx.x << 2) | wv;
    if (IDX && p >= *cnt) return;
    int t = IDX ? idx[p] : p;
    const float* row = x + (size_t)t * DIM;
    int base = lane * 8;
    float4 v0 = *(const float4*)&row[base];
    float4 v1 = *(const float4*)&row[base + 4];
    float s = v0.x + v0.y + v0.z + v0.w + v1.x + v1.y + v1.z + v1.w;
#pragma unroll
    for (int o = 32; o; o >>= 1) s += __shfl_xor(s, o, 64);
    float mean = s * (1.0f / (float)DIM);
    float d0 = v0.x - mean, d1 = v0.y - mean, d2 = v0.z - mean, d3 = v0.w - mean;
    float d4 = v1.x - mean, d5 = v1.y - mean, d6 = v1.z - mean, d7 = v1.w - mean;
    float q = d0*d0 + d1*d1 + d2*d2 + d3*d3 + d4*d4 + d5*d5 + d6*d6 + d7*d7;
#pragma unroll
    for (int o = 32; o; o >>= 1) q += __shfl_xor(q, o, 64);
    float var = q * (1.0f / (float)DIM);
    float rs = 1.0f / sqrtf(var + 1e-5f);
    float4 g0 = *(const float4*)&gam[base];
    float4 g1 = *(const float4*)&gam[base + 4];
    float4 b0 = *(const float4*)&bet[base];
    float4 b1 = *(const float4*)&bet[base + 4];
    float4 o0, o1;
    o0.x = d0 * rs * g0.x + b0.x;  o0.y = d1 * rs * g0.y + b0.y;
    o0.z = d2 * rs * g0.z + b0.z;  o0.w = d3 * rs * g0.w + b0.w;
    o1.x = d4 * rs * g1.x + b1.x;  o1.y = d5 * rs * g1.y + b1.y;
    o1.z = d6 * rs * g1.z + b1.z;  o1.w = d7 * rs * g1.w + b1.w;
    float* orow = out + (size_t)p * DIM;
    *(float4*)&orow[base] = o0;
    *(float4*)&orow[base + 4] = o1;
}

// -------------------- LayerNorm -> bf16 hi/lo (dense, block 0) --------------------
__global__ __launch_bounds__(256) void ln_hilo(const float* __restrict__ x,
                                               const float* __restrict__ gam,
                                               const float* __restrict__ bet,
                                               short* __restrict__ ohi,
                                               short* __restrict__ olo) {
    int wv = threadIdx.x >> 6, lane = threadIdx.x & 63;
    int t = (blockIdx.x << 2) | wv;
    const float* row = x + (size_t)t * DIM;
    int base = lane * 8;
    float4 v0 = *(const float4*)&row[base];
    float4 v1 = *(const float4*)&row[base + 4];
    float s = v0.x + v0.y + v0.z + v0.w + v1.x + v1.y + v1.z + v1.w;
#pragma unroll
    for (int o = 32; o; o >>= 1) s += __shfl_xor(s, o, 64);
    float mean = s * (1.0f / (float)DIM);
    float d[8] = {v0.x - mean, v0.y - mean, v0.z - mean, v0.w - mean,
                  v1.x - mean, v1.y - mean, v1.z - mean, v1.w - mean};
    float q = 0.0f;
#pragma unroll
    for (int j = 0; j < 8; ++j) q += d[j] * d[j];
#pragma unroll
    for (int o = 32; o; o >>= 1) q += __shfl_xor(q, o, 64);
    float var = q * (1.0f / (float)DIM);
    float rs = 1.0f / sqrtf(var + 1e-5f);
    float g[8], bb[8];
    *(float4*)&g[0] = *(const float4*)&gam[base];
    *(float4*)&g[4] = *(const float4*)&gam[base + 4];
    *(float4*)&bb[0] = *(const float4*)&bet[base];
    *(float4*)&bb[4] = *(const float4*)&bet[base + 4];
    short8_t hv, lv;
#pragma unroll
    for (int j = 0; j < 8; ++j) {
        float val = d[j] * rs * g[j] + bb[j];
        unsigned short hb = f2bf_rn(val);
        float hf = __uint_as_float((unsigned)hb << 16);
        hv[j] = (short)hb;
        lv[j] = (short)f2bf_rn(val - hf);
    }
    *(short8_t*)&ohi[(size_t)t * DIM + base] = hv;
    *(short8_t*)&olo[(size_t)t * DIM + base] = lv;
}

// -------------------- split-bf16 MFMA GEMM (128x128): C(M,N) = A(M,K) @ B(N,K)^T -----
// EPI: 0 = store hi/lo bf16; 1 = gelu + store hi/lo; 2 = residual add into Cf;
//      3 = plain fp32 store; 4 = residual add into Cf AND store hi/lo of the sum.
template<int EPI>
__global__ __launch_bounds__(256) void gemm_l_mfma(const short* __restrict__ Ah,
                                                   const short* __restrict__ Al,
                                                   const short* __restrict__ Bh,
                                                   const short* __restrict__ Bl,
                                                   float* __restrict__ Cf,
                                                   short* __restrict__ oHi,
                                                   short* __restrict__ oLo,
                                                   int N, int K) {
    __shared__ __align__(16) short sm[16384];
    short* sAh = sm;
    short* sAl = sm + 4096;
    short* sBh = sm + 8192;
    short* sBl = sm + 12288;
    const int tid = threadIdx.x;
    const int wv = tid >> 6, lane = tid & 63;
    const int m0 = blockIdx.x * 128;
    const int n0 = blockIdx.y * 128;
    const int wm = (wv & 1) * 64, wn = (wv >> 1) * 64;
    const int r16 = lane >> 2;
    const int gsw = ((lane & 3) ^ (r16 & 3)) << 3;
    const int fr = lane & 15;
    const int q = lane >> 4;

    f32x4 acc[4][4];
#pragma unroll
    for (int i = 0; i < 4; ++i)
#pragma unroll
        for (int j = 0; j < 4; ++j)
            acc[i][j] = (f32x4){0.0f, 0.0f, 0.0f, 0.0f};

    const int NKT = K >> 5;
    for (int kt = 0; kt < NKT; ++kt) {
        const int k0 = kt << 5;
        __syncthreads();
#pragma unroll
        for (int j = 0; j < 2; ++j) {
            const int rr = (wv << 5) + (j << 4);
            const int gr = rr + r16;
            const short* ga_h = Ah + (size_t)(m0 + gr) * K + k0 + gsw;
            const short* ga_l = Al + (size_t)(m0 + gr) * K + k0 + gsw;
            const short* gb_h = Bh + (size_t)(n0 + gr) * K + k0 + gsw;
            const short* gb_l = Bl + (size_t)(n0 + gr) * K + k0 + gsw;
            __builtin_amdgcn_global_load_lds((const __attribute__((address_space(1))) void*)ga_h,
                                             (__attribute__((address_space(3))) void*)(sAh + rr * 32), 16, 0, 0);
            __builtin_amdgcn_global_load_lds((const __attribute__((address_space(1))) void*)ga_l,
                                             (__attribute__((address_space(3))) void*)(sAl + rr * 32), 16, 0, 0);
            __builtin_amdgcn_global_load_lds((const __attribute__((address_space(1))) void*)gb_h,
                                             (__attribute__((address_space(3))) void*)(sBh + rr * 32), 16, 0, 0);
            __builtin_amdgcn_global_load_lds((const __attribute__((address_space(1))) void*)gb_l,
                                             (__attribute__((address_space(3))) void*)(sBl + rr * 32), 16, 0, 0);
        }
        __syncthreads();
        short8_t ah[4], al[4], bh[4], bl[4];
#pragma unroll
        for (int i = 0; i < 4; ++i) {
            const int ra = wm + i * 16 + fr;
            const int rb = wn + i * 16 + fr;
            const int swa = (q ^ (fr & 3)) << 3;
            ah[i] = *(const short8_t*)&sAh[ra * 32 + swa];
            al[i] = *(const short8_t*)&sAl[ra * 32 + swa];
            bh[i] = *(const short8_t*)&sBh[rb * 32 + swa];
            bl[i] = *(const short8_t*)&sBl[rb * 32 + swa];
        }
#pragma unroll
        for (int i = 0; i < 4; ++i)
#pragma unroll
            for (int j = 0; j < 4; ++j) {
                acc[i][j] = __builtin_amdgcn_mfma_f32_16x16x32_bf16(ah[i], bh[j], acc[i][j], 0, 0, 0);
                acc[i][j] = __builtin_amdgcn_mfma_f32_16x16x32_bf16(ah[i], bl[j], acc[i][j], 0, 0, 0);
                acc[i][j] = __builtin_amdgcn_mfma_f32_16x16x32_bf16(al[i], bh[j], acc[i][j], 0, 0, 0);
            }
    }
    const int row_base = (lane >> 4) << 2;
#pragma unroll
    for (int i = 0; i < 4; ++i)
#pragma unroll
        for (int j = 0; j < 4; ++j) {
            const int row = m0 + wm + i * 16 + row_base;
            const int col = n0 + wn + j * 16 + fr;
#pragma unroll
            for (int r = 0; r < 4; ++r) {
                float val = acc[i][j][r];
                if (EPI == 3) {
                    Cf[(size_t)(row + r) * N + col] = val;
                } else if (EPI == 2) {
                    Cf[(size_t)(row + r) * N + col] += val;
                } else if (EPI == 4) {
                    float* cp = &Cf[(size_t)(row + r) * N + col];
                    float nv = *cp + val;
                    *cp = nv;
                    unsigned short hb = f2bf_rn(nv);
                    float hf = __uint_as_float((unsigned)hb << 16);
                    oHi[(size_t)(row + r) * N + col] = (short)hb;
                    oLo[(size_t)(row + r) * N + col] = (short)f2bf_rn(nv - hf);
                } else {
                    if (EPI == 1) val = gelu_f(val);
                    unsigned short hb = f2bf_rn(val);
                    float hf = __uint_as_float((unsigned)hb << 16);
                    oHi[(size_t)(row + r) * N + col] = (short)hb;
                    oLo[(size_t)(row + r) * N + col] = (short)f2bf_rn(val - hf);
                }
            }
        }
}

// -------------------- split-bf16 MFMA GEMM (64x128 tile) for N=512 GEMMs --------------------
// Same staging/swizzle/3-product pattern as gemm_l_mfma; BM=64 doubles grid occupancy.
// Wave tile 32x64 (2x2 waves). Grid (M/64, N/128).
template<int EPI>
__global__ __launch_bounds__(256) void gemm_l64(const short* __restrict__ Ah,
                                                const short* __restrict__ Al,
                                                const short* __restrict__ Bh,
                                                const short* __restrict__ Bl,
                                                float* __restrict__ Cf,
                                                short* __restrict__ oHi,
                                                short* __restrict__ oLo,
                                                int N, int K) {
    __shared__ __align__(16) short sm[12288];   // A 2x2048 + B 2x4096 shorts = 24 KiB
    short* sAh = sm;
    short* sAl = sm + 2048;
    short* sBh = sm + 4096;
    short* sBl = sm + 8192;
    const int tid = threadIdx.x;
    const int wv = tid >> 6, lane = tid & 63;
    const int m0 = blockIdx.x * 64;
    const int n0 = blockIdx.y * 128;
    const int wm = (wv & 1) * 32, wn = (wv >> 1) * 64;
    const int r16 = lane >> 2;
    const int gsw = ((lane & 3) ^ (r16 & 3)) << 3;
    const int fr = lane & 15;
    const int q = lane >> 4;

    f32x4 acc[2][4];
#pragma unroll
    for (int i = 0; i < 2; ++i)
#pragma unroll
        for (int j = 0; j < 4; ++j)
            acc[i][j] = (f32x4){0.0f, 0.0f, 0.0f, 0.0f};

    const int NKT = K >> 5;
    for (int kt = 0; kt < NKT; ++kt) {
        const int k0 = kt << 5;
        __syncthreads();
        {   // A: 64 rows, one 16-row round per wave
            const int rr = wv << 4;
            const int gr = rr + r16;
            const short* ga_h = Ah + (size_t)(m0 + gr) * K + k0 + gsw;
            const short* ga_l = Al + (size_t)(m0 + gr) * K + k0 + gsw;
            __builtin_amdgcn_global_load_lds((const __attribute__((address_space(1))) void*)ga_h,
                                             (__attribute__((address_space(3))) void*)(sAh + rr * 32), 16, 0, 0);
            __builtin_amdgcn_global_load_lds((const __attribute__((address_space(1))) void*)ga_l,
                                             (__attribute__((address_space(3))) void*)(sAl + rr * 32), 16, 0, 0);
        }
#pragma unroll
        for (int j = 0; j < 2; ++j) {   // B: 128 rows, two rounds per wave
            const int rr = (wv << 5) + (j << 4);
            const int gr = rr + r16;
            const short* gb_h = Bh + (size_t)(n0 + gr) * K + k0 + gsw;
            const short* gb_l = Bl + (size_t)(n0 + gr) * K + k0 + gsw;
            __builtin_amdgcn_global_load_lds((const __attribute__((address_space(1))) void*)gb_h,
                                             (__attribute__((address_space(3))) void*)(sBh + rr * 32), 16, 0, 0);
            __builtin_amdgcn_global_load_lds((const __attribute__((address_space(1))) void*)gb_l,
                                             (__attribute__((address_space(3))) void*)(sBl + rr * 32), 16, 0, 0);
        }
        __syncthreads();
        short8_t ah[2], al[2], bh[4], bl[4];
        const int swa = (q ^ (fr & 3)) << 3;
#pragma unroll
        for (int i = 0; i < 2; ++i) {
            const int ra = wm + i * 16 + fr;
            ah[i] = *(const short8_t*)&sAh[ra * 32 + swa];
            al[i] = *(const short8_t*)&sAl[ra * 32 + swa];
        }
#pragma unroll
        for (int j = 0; j < 4; ++j) {
            const int rb = wn + j * 16 + fr;
            bh[j] = *(const short8_t*)&sBh[rb * 32 + swa];
            bl[j] = *(const short8_t*)&sBl[rb * 32 + swa];
        }
#pragma unroll
        for (int i = 0; i < 2; ++i)
#pragma unroll
            for (int j = 0; j < 4; ++j) {
                acc[i][j] = __builtin_amdgcn_mfma_f32_16x16x32_bf16(ah[i], bh[j], acc[i][j], 0, 0, 0);
                acc[i][j] = __builtin_amdgcn_mfma_f32_16x16x32_bf16(ah[i], bl[j], acc[i][j], 0, 0, 0);
                acc[i][j] = __builtin_amdgcn_mfma_f32_16x16x32_bf16(al[i], bh[j], acc[i][j], 0, 0, 0);
            }
    }
    const int row_base = (lane >> 4) << 2;
#pragma unroll
    for (int i = 0; i < 2; ++i)
#pragma unroll
        for (int j = 0; j < 4; ++j) {
            const int row = m0 + wm + i * 16 + row_base;
            const int col = n0 + wn + j * 16 + fr;
#pragma unroll
            for (int r = 0; r < 4; ++r) {
                float val = acc[i][j][r];
                if (EPI == 3) {
                    Cf[(size_t)(row + r) * N + col] = val;
                } else if (EPI == 2) {
                    Cf[(size_t)(row + r) * N + col] += val;
                } else if (EPI == 4) {
                    float* cp = &Cf[(size_t)(row + r) * N + col];
                    float nv = *cp + val;
                    *cp = nv;
                    unsigned short hb = f2bf_rn(nv);
                    float hf = __uint_as_float((unsigned)hb << 16);
                    oHi[(size_t)(row + r) * N + col] = (short)hb;
                    oLo[(size_t)(row + r) * N + col] = (short)f2bf_rn(nv - hf);
                } else {
                    if (EPI == 1) val = gelu_f(val);
                    unsigned short hb = f2bf_rn(val);
                    float hf = __uint_as_float((unsigned)hb << 16);
                    oHi[(size_t)(row + r) * N + col] = (short)hb;
                    oLo[(size_t)(row + r) * N + col] = (short)f2bf_rn(val - hf);
                }
            }
        }
}

// -------------------- fp32 tiled GEMM (tier 2/3 dense block-0 path) --------------------
template<bool ADD, bool GELU>
__global__ __launch_bounds__(256) void gemm_nn(const float* __restrict__ A,
                                               const float* __restrict__ B,
                                               float* __restrict__ C,
                                               int M, int N, int K) {
    const int m0 = blockIdx.y * 64, n0 = blockIdx.x * 64;
    __shared__ float As[16][68];
    __shared__ float Bs[16][68];
    const int tid = threadIdx.x;
    const int am = tid >> 2, ak = (tid & 3) << 2;
    const int bk = tid >> 4, bn = (tid & 15) << 2;
    const int tn = tid & 15, tm = tid >> 4;
    float acc[4][4] = {};
    for (int k0 = 0; k0 < K; k0 += 16) {
        float4 a4 = *(const float4*)&A[(size_t)(m0 + am) * K + k0 + ak];
        float4 b4 = *(const float4*)&B[(size_t)(k0 + bk) * N + n0 + bn];
        __syncthreads();
        As[ak + 0][am] = a4.x;
        As[ak + 1][am] = a4.y;
        As[ak + 2][am] = a4.z;
        As[ak + 3][am] = a4.w;
        *(float4*)&Bs[bk][bn] = b4;
        __syncthreads();
#pragma unroll
        for (int kk = 0; kk < 16; ++kk) {
            float4 av = *(const float4*)&As[kk][tm << 2];
            float4 bv = *(const float4*)&Bs[kk][tn << 2];
            float a[4] = {av.x, av.y, av.z, av.w};
            float b[4] = {bv.x, bv.y, bv.z, bv.w};
#pragma unroll
            for (int i = 0; i < 4; ++i)
#pragma unroll
                for (int j = 0; j < 4; ++j)
                    acc[i][j] = fmaf(a[i], b[j], acc[i][j]);
        }
    }
#pragma unroll
    for (int i = 0; i < 4; ++i) {
        size_t row = (size_t)(m0 + (tm << 2) + i);
        float* cp = &C[row * (size_t)N + n0 + (tn << 2)];
        float rr[4] = {acc[i][0], acc[i][1], acc[i][2], acc[i][3]};
        if (GELU) {
#pragma unroll
            for (int j = 0; j < 4; ++j) rr[j] = gelu_f(rr[j]);
        }
        if (ADD) {
            float4 cc = *(const float4*)cp;
            rr[0] += cc.x; rr[1] += cc.y; rr[2] += cc.z; rr[3] += cc.w;
        }
        float4 rv = {rr[0], rr[1], rr[2], rr[3]};
        *(float4*)cp = rv;
    }
}

// -------------------- grid-stride fp32 GEMM over compacted rows (blocks 1-2) ----------
// Tiles over ceil(cnt/64) x N/64; when cnt==0 exits after one load.
template<bool ADD, bool GELU, bool SCAT>
__global__ __launch_bounds__(256) void gemm_nn_gs(const float* __restrict__ A,
                                                  const float* __restrict__ B,
                                                  float* __restrict__ C,
                                                  int N, int K,
                                                  const int* __restrict__ idx,
                                                  const int* __restrict__ cnt) {
    const int c = *cnt;
    const int ntm = (c + 63) >> 6;
    const int ntn = N >> 6;
    const int total = ntm * ntn;
    __shared__ float As[16][68];
    __shared__ float Bs[16][68];
    const int tid = threadIdx.x;
    const int am = tid >> 2, ak = (tid & 3) << 2;
    const int bk = tid >> 4, bn = (tid & 15) << 2;
    const int tn = tid & 15, tm = tid >> 4;
    for (int tile = blockIdx.x; tile < total; tile += gridDim.x) {
        const int m0 = (tile % ntm) << 6, n0 = (tile / ntm) << 6;
        int ar = m0 + am;
        ar = ar < c ? ar : c - 1;
        float acc[4][4] = {};
        for (int k0 = 0; k0 < K; k0 += 16) {
            float4 a4 = *(const float4*)&A[(size_t)ar * K + k0 + ak];
            float4 b4 = *(const float4*)&B[(size_t)(k0 + bk) * N + n0 + bn];
            __syncthreads();
            As[ak + 0][am] = a4.x;
            As[ak + 1][am] = a4.y;
            As[ak + 2][am] = a4.z;
            As[ak + 3][am] = a4.w;
            *(float4*)&Bs[bk][bn] = b4;
            __syncthreads();
#pragma unroll
            for (int kk = 0; kk < 16; ++kk) {
                float4 av = *(const float4*)&As[kk][tm << 2];
                float4 bv = *(const float4*)&Bs[kk][tn << 2];
                float a[4] = {av.x, av.y, av.z, av.w};
                float b[4] = {bv.x, bv.y, bv.z, bv.w};
#pragma unroll
                for (int i = 0; i < 4; ++i)
#pragma unroll
                    for (int j = 0; j < 4; ++j)
                        acc[i][j] = fmaf(a[i], b[j], acc[i][j]);
            }
        }
#pragma unroll
        for (int i = 0; i < 4; ++i) {
            int p = m0 + (tm << 2) + i;
            if (p >= c) continue;
            int r = SCAT ? idx[p] : p;
            float* cp = &C[(size_t)r * N + n0 + (tn << 2)];
            float rr[4] = {acc[i][0], acc[i][1], acc[i][2], acc[i][3]};
            if (GELU) {
#pragma unroll
                for (int j = 0; j < 4; ++j) rr[j] = gelu_f(rr[j]);
            }
            if (ADD) {
                float4 cc = *(const float4*)cp;
                rr[0] += cc.x; rr[1] += cc.y; rr[2] += cc.z; rr[3] += cc.w;
            }
            float4 rv = {rr[0], rr[1], rr[2], rr[3]};
            *(float4*)cp = rv;
        }
        __syncthreads();
    }
}

// -------------------- grid-stride fp32 head GEMM over compacted rows (blocks 1-2) -----
__global__ __launch_bounds__(256) void gemm_nt_head_gs(const float* __restrict__ A,
                                                       const float* __restrict__ Bt,
                                                       float* __restrict__ C,
                                                       const int* __restrict__ idx,
                                                       const int* __restrict__ cnt) {
    const int c = *cnt;
    const int ntm = (c + 63) >> 6;
    const int ntn = NVOCAB >> 6;  // 500
    const int total = ntm * ntn;
    __shared__ float As[16][68];
    __shared__ float Bs[16][68];
    const int tid = threadIdx.x;
    const int am = tid >> 2, ak = (tid & 3) << 2;
    const int tn = tid & 15, tm = tid >> 4;
    for (int tile = blockIdx.x; tile < total; tile += gridDim.x) {
        const int m0 = (tile % ntm) << 6, n0 = (tile / ntm) << 6;
        int ap = m0 + am;
        int ar = idx[ap < c ? ap : c - 1];
        float acc[4][4] = {};
        for (int k0 = 0; k0 < DIM; k0 += 16) {
            float4 a4 = *(const float4*)&A[(size_t)ar * DIM + k0 + ak];
            float4 b4 = *(const float4*)&Bt[(size_t)(n0 + am) * DIM + k0 + ak];
            __syncthreads();
            As[ak + 0][am] = a4.x;
            As[ak + 1][am] = a4.y;
            As[ak + 2][am] = a4.z;
            As[ak + 3][am] = a4.w;
            Bs[ak + 0][am] = b4.x;
            Bs[ak + 1][am] = b4.y;
            Bs[ak + 2][am] = b4.z;
            Bs[ak + 3][am] = b4.w;
            __syncthreads();
#pragma unroll
            for (int kk = 0; kk < 16; ++kk) {
                float4 av = *(const float4*)&As[kk][tm << 2];
                float4 bv = *(const float4*)&Bs[kk][tn << 2];
                float a[4] = {av.x, av.y, av.z, av.w};
                float b[4] = {bv.x, bv.y, bv.z, bv.w};
#pragma unroll
                for (int i = 0; i < 4; ++i)
#pragma unroll
                    for (int j = 0; j < 4; ++j)
                        acc[i][j] = fmaf(a[i], b[j], acc[i][j]);
            }
        }
#pragma unroll
        for (int i = 0; i < 4; ++i) {
            int p = m0 + (tm << 2) + i;
            if (p >= c) continue;
            int r = idx[p];
            float4 rv = {acc[i][0], acc[i][1], acc[i][2], acc[i][3]};
            *(float4*)&C[(size_t)r * NVOCAB + n0 + (tn << 2)] = rv;
        }
        __syncthreads();
    }
}

// -------------------- confidence + exit (vectorized full-row read) --------------------
template<bool IDX>
__global__ __launch_bounds__(256) void conf_exit(const float* __restrict__ out,
                                                 int* __restrict__ flags,
                                                 const int* __restrict__ idx,
                                                 const int* __restrict__ cnt,
                                                 float thr) {
    int t;
    if (IDX) {
        if (blockIdx.x >= *cnt) return;
        t = idx[blockIdx.x];
    } else {
        t = blockIdx.x;
        if (flags[t] == 0) return;
    }
    const float4* row = (const float4*)(out + (size_t)t * NVOCAB);
    float m = -INFINITY, s = 0.0f;
    for (int i = threadIdx.x; i < NVOCAB / 4; i += 256) {
        float4 v = row[i];
        float m4 = fmaxf(fmaxf(v.x, v.y), fmaxf(v.z, v.w));
        float s4 = __expf(v.x - m4) + __expf(v.y - m4) + __expf(v.z - m4) + __expf(v.w - m4);
        if (m4 > m) {
            s = s * __expf(m - m4) + s4;
            m = m4;
        } else {
            s += s4 * __expf(m4 - m);
        }
    }
    __shared__ float ms[256], ss[256];
    ms[threadIdx.x] = m;
    ss[threadIdx.x] = s;
    __syncthreads();
    for (int st = 128; st; st >>= 1) {
        if (threadIdx.x < st) {
            float m1 = ms[threadIdx.x], s1 = ss[threadIdx.x];
            float m2 = ms[threadIdx.x + st], s2 = ss[threadIdx.x + st];
            float mm = fmaxf(m1, m2);
            ss[threadIdx.x] = s1 * __expf(m1 - mm) + s2 * __expf(m2 - mm);
            ms[threadIdx.x] = mm;
        }
        __syncthreads();
    }
    if (threadIdx.x == 0) {
        float conf = 1.0f / ss[0];
        if (conf > thr) flags[t] = 0;
    }
}

// -------------------- ordered compaction of active tokens (single block) --------------------
__global__ __launch_bounds__(256) void compact_kernel(const int* __restrict__ flags,
                                                      int* __restrict__ idx,
                                                      int* __restrict__ cnt) {
    __shared__ int wsum[4];
    __shared__ int base;
    if (threadIdx.x == 0) base = 0;
    int lane = threadIdx.x & 63, wv = threadIdx.x >> 6;
    for (int chunk = 0; chunk < TT; chunk += 256) {
        __syncthreads();
        int t = chunk + threadIdx.x;
        int f = flags[t];
        unsigned long long b = __ballot(f != 0);
        if (lane == 0) wsum[wv] = __popcll(b);
        __syncthreads();
        int off = base;
        for (int w = 0; w < wv; ++w) off += wsum[w];
        off += __popcll(b & ((1ull << lane) - 1));
        if (f) idx[off] = t;
        __syncthreads();
        if (threadIdx.x == 0) base += wsum[0] + wsum[1] + wsum[2] + wsum[3];
    }
    __syncthreads();
    if (threadIdx.x == 0) *cnt = base;
}

extern "C" void kernel_launch(void* const* d_in, const int* in_sizes, int n_in,
                              void* d_out, int out_size, void* d_ws, size_t ws_size,
                              hipStream_t stream) {
    const int* x = (const int*)d_in[0];
    const float* emb = (const float*)d_in[1];
    const float* head = (const float*)d_in[2];
    const float* Wv = (const float*)d_in[3];
    const float* Wo = (const float*)d_in[4];
    const float* W1 = (const float*)d_in[5];
    const float* W2 = (const float*)d_in[6];
    const float* ln1s = (const float*)d_in[7];
    const float* ln1b = (const float*)d_in[8];
    const float* ln2s = (const float*)d_in[9];
    const float* ln2b = (const float*)d_in[10];
    float* out = (float*)d_out;
    float* ws = (float*)d_ws;

    float* h  = ws;                      // TT*DIM fp32
    float* hn = ws + 2097152;            // TT*DIM
    float* tA = ws + 4194304;            // TT*DIM (scratch: WvFlat hi/lo during setup)
    float* tF = ws + 6291456;            // TT*FFN
    short* hnHi = (short*)hn;
    short* hnLo = hnHi + TT * DIM;
    short* tAHi = (short*)tA;
    short* tALo = tAHi + TT * DIM;
    short* tFHi = (short*)tF;
    short* tFLo = tFHi + TT * FFN;
    int* flags = (int*)(ws + 14680064);  // TT
    int* idxl  = flags + TT;             // TT
    int* cntp  = flags + 2 * TT;         // 1
    short* hHi    = (short*)(ws + 14700000);
    short* hLo    = (short*)(ws + 15748576);
    short* headHi = (short*)(ws + 16797152);
    short* headLo = (short*)(ws + 24989152);
    short* wT     = (short*)(ws + 33181152);  // 2 layers x 5242880 shorts
    const size_t LSTRIDE = 5242880;
    const size_t NEED_T2 = (size_t)33181152 * 4;
    const size_t NEED_T1 = (size_t)38424032 * 4;
    const int tier = ws_size >= NEED_T1 ? 1 : (ws_size >= NEED_T2 ? 2 : 3);

    gather_kernel<<<TT, 128, 0, stream>>>(x, emb, h, flags);

    const float THR[3] = {3.5e-05f, 4.0e-05f, 1.0f};
    const dim3 gDD(DIM / 64, TT / 64), gDF(FFN / 64, TT / 64), gHead(NVOCAB / 64, TT / 64);

    // ---------- block 0: dense ----------
    if (tier == 1) {
        // weight prep: WoT, W1T, W2T transpose-splits; W_voT = WoT @ WvFlat (MFMA)
        for (int l = 0; l < 2; ++l) {
            short* wb = wT + (size_t)l * LSTRIDE;
            cvt_hilo<<<(DIM * DIM / 4 + 255) / 256, 256, 0, stream>>>(Wv + (size_t)l * DIM * DIM, tAHi, tALo, DIM * DIM / 4);
            cvt_w_t<<<dim3(DIM / 32, DIM / 32), 256, 0, stream>>>(Wo + (size_t)l * DIM * DIM, wb + 524288, wb + 786432, DIM, DIM);
            gemm_l64<0><<<dim3(DIM / 64, DIM / 128), 256, 0, stream>>>(
                wb + 524288, wb + 786432, tAHi, tALo, nullptr, wb, wb + 262144, DIM, DIM);
            cvt_w_t<<<dim3(FFN / 32, DIM / 32), 256, 0, stream>>>(W1 + (size_t)l * DIM * FFN, wb + 1048576, wb + 2097152, DIM, FFN);
            cvt_w_t<<<dim3(DIM / 32, FFN / 32), 256, 0, stream>>>(W2 + (size_t)l * FFN * DIM, wb + 3145728, wb + 4194304, FFN, DIM);
        }
        for (int l = 0; l < 2; ++l) {
            short* wb = wT + (size_t)l * LSTRIDE;
            ln_hilo<<<TT / 4, 256, 0, stream>>>(h, ln1s + l * DIM, ln1b + l * DIM, hnHi, hnLo);
            gemm_l64<2><<<dim3(TT / 64, DIM / 128), 256, 0, stream>>>(hnHi, hnLo, wb, wb + 262144, h, nullptr, nullptr, DIM, DIM);
            ln_hilo<<<TT / 4, 256, 0, stream>>>(h, ln2s + l * DIM, ln2b + l * DIM, hnHi, hnLo);
            gemm_l_mfma<1><<<dim3(TT / 128, FFN / 128), 256, 0, stream>>>(hnHi, hnLo, wb + 1048576, wb + 2097152, nullptr, tFHi, tFLo, FFN, DIM);
            if (l == 1) {
                gemm_l64<4><<<dim3(TT / 64, DIM / 128), 256, 0, stream>>>(tFHi, tFLo, wb + 3145728, wb + 4194304, h, hHi, hLo, DIM, FFN);
            } else {
                gemm_l64<2><<<dim3(TT / 64, DIM / 128), 256, 0, stream>>>(tFHi, tFLo, wb + 3145728, wb + 4194304, h, nullptr, nullptr, DIM, FFN);
            }
        }
        cvt_hilo<<<(NVOCAB * DIM / 4 + 255) / 256, 256, 0, stream>>>(head, headHi, headLo, NVOCAB * DIM / 4);
        gemm_l_mfma<3><<<dim3(TT / 128, NVOCAB / 128), 256, 0, stream>>>(hHi, hLo, headHi, headLo, out, nullptr, nullptr, NVOCAB, DIM);
        conf_exit<false><<<TT, 256, 0, stream>>>(out, flags, nullptr, nullptr, THR[0]);
    } else {
        for (int l = 0; l < 2; ++l) {
            ln_kernel<false><<<TT / 4, 256, 0, stream>>>(h, ln1s + l * DIM, ln1b + l * DIM, hn, nullptr, nullptr);
            gemm_nn<false, false><<<gDD, 256, 0, stream>>>(hn, Wv + (size_t)l * DIM * DIM, tA, TT, DIM, DIM);
            gemm_nn<true, false><<<gDD, 256, 0, stream>>>(tA, Wo + (size_t)l * DIM * DIM, h, TT, DIM, DIM);
            ln_kernel<false><<<TT / 4, 256, 0, stream>>>(h, ln2s + l * DIM, ln2b + l * DIM, hn, nullptr, nullptr);
            gemm_nn<false, true><<<gDF, 256, 0, stream>>>(hn, W1 + (size_t)l * DIM * FFN, tF, TT, FFN, DIM);
            gemm_nn<true, false><<<gDD, 256, 0, stream>>>(tF, W2 + (size_t)l * FFN * DIM, h, TT, DIM, FFN);
        }
        if (tier == 2) {
            cvt_hilo<<<(TT * DIM / 4 + 255) / 256, 256, 0, stream>>>(h, hHi, hLo, TT * DIM / 4);
            cvt_hilo<<<(NVOCAB * DIM / 4 + 255) / 256, 256, 0, stream>>>(head, headHi, headLo, NVOCAB * DIM / 4);
            gemm_l_mfma<3><<<dim3(TT / 128, NVOCAB / 128), 256, 0, stream>>>(hHi, hLo, headHi, headLo, out, nullptr, nullptr, NVOCAB, DIM);
        } else {
            // tier-3 minimal-workspace fallback: fp32 head via grid-stride over all tokens
            // (flags all 1 here; use dense fp32 gemm via gemm_nn on B^T is unavailable ->
            //  reuse gs head with identity idx by building it from compact of all-ones flags)
            compact_kernel<<<1, 256, 0, stream>>>(flags, idxl, cntp);
            gemm_nt_head_gs<<<2048, 256, 0, stream>>>(h, head, out, idxl, cntp);
        }
        conf_exit<false><<<TT, 256, 0, stream>>>(out, flags, nullptr, nullptr, THR[0]);
    }
    compact_kernel<<<1, 256, 0, stream>>>(flags, idxl, cntp);

    // ---------- blocks 1,2: compacted active rows (grid-stride fp32 path; ~empty) ----------
    for (int b = 1; b < 3; ++b) {
        for (int li = 0; li < 2; ++li) {
            int l = b * 2 + li;
            ln_kernel<true><<<TT / 4, 256, 0, stream>>>(h, ln1s + l * DIM, ln1b + l * DIM, hn, idxl, cntp);
            gemm_nn_gs<false, false, false><<<1024, 256, 0, stream>>>(hn, Wv + (size_t)l * DIM * DIM, tA, DIM, DIM, idxl, cntp);
            gemm_nn_gs<true, false, true><<<1024, 256, 0, stream>>>(tA, Wo + (size_t)l * DIM * DIM, h, DIM, DIM, idxl, cntp);
            ln_kernel<true><<<TT / 4, 256, 0, stream>>>(h, ln2s + l * DIM, ln2b + l * DIM, hn, idxl, cntp);
            gemm_nn_gs<false, true, false><<<1024, 256, 0, stream>>>(hn, W1 + (size_t)l * DIM * FFN, tF, FFN, DIM, idxl, cntp);
            gemm_nn_gs<true, false, true><<<1024, 256, 0, stream>>>(tF, W2 + (size_t)l * FFN * DIM, h, DIM, FFN, idxl, cntp);
        }
        gemm_nt_head_gs<<<2048, 256, 0, stream>>>(h, head, out, idxl, cntp);
        if (b == 1) {
            conf_exit<true><<<TT, 256, 0, stream>>>(out, flags, idxl, cntp, THR[1]);
            compact_kernel<<<1, 256, 0, stream>>>(flags, idxl, cntp);
        }
    }
}

// Round 11
// 793.997 us; speedup vs baseline: 1.3505x; 1.2194x over previous
//
#include <hip/hip_runtime.h>
#include <hip/hip_bf16.h>
#include <math.h>

#define TT 4096
#define DIM 512
#define FFN 2048
#define NVOCAB 32000

typedef __attribute__((ext_vector_type(8))) short short8_t;
typedef __attribute__((ext_vector_type(4))) float f32x4;

__device__ __forceinline__ float gelu_f(float x) {
    float x3 = x * x * x;
    float u = 0.7978845608028654f * (x + 0.044715f * x3);
    return 0.5f * x * (1.0f + tanhf(u));
}

__device__ __forceinline__ unsigned short f2bf_rn(float f) {
    unsigned u = __float_as_uint(f);
    u += 0x7FFFu + ((u >> 16) & 1u);
    return (unsigned short)(u >> 16);
}

// -------------------- embedding gather + flag init --------------------
__global__ __launch_bounds__(128) void gather_kernel(const int* __restrict__ x,
                                                     const float* __restrict__ emb,
                                                     float* __restrict__ h,
                                                     int* __restrict__ flags) {
    int t = blockIdx.x;
    int idx = x[t];
    const float4 v = *(const float4*)&emb[(size_t)idx * DIM + threadIdx.x * 4];
    *(float4*)&h[(size_t)t * DIM + threadIdx.x * 4] = v;
    if (threadIdx.x == 0) flags[t] = 1;
}

// -------------------- fp32 -> bf16 hi/lo split (flat) --------------------
__global__ __launch_bounds__(256) void cvt_hilo(const float* __restrict__ src,
                                                short* __restrict__ hi,
                                                short* __restrict__ lo, int n4) {
    int i = blockIdx.x * 256 + threadIdx.x;
    if (i >= n4) return;
    float4 v = *(const float4*)&src[(size_t)i * 4];
    float f[4] = {v.x, v.y, v.z, v.w};
    short4 hv, lv;
    short* hp = &hv.x;
    short* lp = &lv.x;
#pragma unroll
    for (int j = 0; j < 4; ++j) {
        unsigned short hb = f2bf_rn(f[j]);
        float hf = __uint_as_float((unsigned)hb << 16);
        unsigned short lb = f2bf_rn(f[j] - hf);
        hp[j] = (short)hb;
        lp[j] = (short)lb;
    }
    *(short4*)&hi[(size_t)i * 4] = hv;
    *(short4*)&lo[(size_t)i * 4] = lv;
}

// -------------------- fp32 -> bf16 (hi only, flat) --------------------
__global__ __launch_bounds__(256) void cvt_bf16(const float* __restrict__ src,
                                                short* __restrict__ hi, int n4) {
    int i = blockIdx.x * 256 + threadIdx.x;
    if (i >= n4) return;
    float4 v = *(const float4*)&src[(size_t)i * 4];
    float f[4] = {v.x, v.y, v.z, v.w};
    short4 hv;
    short* hp = &hv.x;
#pragma unroll
    for (int j = 0; j < 4; ++j) hp[j] = (short)f2bf_rn(f[j]);
    *(short4*)&hi[(size_t)i * 4] = hv;
}

// -------------------- fp32 W (K,N) -> bf16 hi/lo transposed (N,K) --------------------
__global__ __launch_bounds__(256) void cvt_w_t(const float* __restrict__ W,
                                               short* __restrict__ hiT,
                                               short* __restrict__ loT,
                                               int K, int N) {
    __shared__ short hs[32][36];
    __shared__ short ls[32][36];
    const int n0 = blockIdx.x * 32, k0 = blockIdx.y * 32;
    const int r = threadIdx.x >> 3, c4 = (threadIdx.x & 7) << 2;
    float4 v = *(const float4*)&W[(size_t)(k0 + r) * N + n0 + c4];
    float f[4] = {v.x, v.y, v.z, v.w};
#pragma unroll
    for (int j = 0; j < 4; ++j) {
        unsigned short hb = f2bf_rn(f[j]);
        float hf = __uint_as_float((unsigned)hb << 16);
        unsigned short lb = f2bf_rn(f[j] - hf);
        hs[r][c4 + j] = (short)hb;
        ls[r][c4 + j] = (short)lb;
    }
    __syncthreads();
    const int nr = threadIdx.x >> 3, kc4 = (threadIdx.x & 7) << 2;
    short4 hv, lv;
    short* hp = &hv.x;
    short* lp = &lv.x;
#pragma unroll
    for (int j = 0; j < 4; ++j) {
        hp[j] = hs[kc4 + j][nr];
        lp[j] = ls[kc4 + j][nr];
    }
    *(short4*)&hiT[(size_t)(n0 + nr) * K + k0 + kc4] = hv;
    *(short4*)&loT[(size_t)(n0 + nr) * K + k0 + kc4] = lv;
}

// -------------------- LayerNorm (fp32 out; optional index gather) --------------------
template<bool IDX>
__global__ __launch_bounds__(256) void ln_kernel(const float* __restrict__ x,
                                                 const float* __restrict__ gam,
                                                 const float* __restrict__ bet,
                                                 float* __restrict__ out,
                                                 const int* __restrict__ idx,
                                                 const int* __restrict__ cnt) {
    int wv = threadIdx.x >> 6, lane = threadIdx.x & 63;
    int p = (blockIdx.x << 2) | wv;
    if (IDX && p >= *cnt) return;
    int t = IDX ? idx[p] : p;
    const float* row = x + (size_t)t * DIM;
    int base = lane * 8;
    float4 v0 = *(const float4*)&row[base];
    float4 v1 = *(const float4*)&row[base + 4];
    float s = v0.x + v0.y + v0.z + v0.w + v1.x + v1.y + v1.z + v1.w;
#pragma unroll
    for (int o = 32; o; o >>= 1) s += __shfl_xor(s, o, 64);
    float mean = s * (1.0f / (float)DIM);
    float d0 = v0.x - mean, d1 = v0.y - mean, d2 = v0.z - mean, d3 = v0.w - mean;
    float d4 = v1.x - mean, d5 = v1.y - mean, d6 = v1.z - mean, d7 = v1.w - mean;
    float q = d0*d0 + d1*d1 + d2*d2 + d3*d3 + d4*d4 + d5*d5 + d6*d6 + d7*d7;
#pragma unroll
    for (int o = 32; o; o >>= 1) q += __shfl_xor(q, o, 64);
    float var = q * (1.0f / (float)DIM);
    float rs = 1.0f / sqrtf(var + 1e-5f);
    float4 g0 = *(const float4*)&gam[base];
    float4 g1 = *(const float4*)&gam[base + 4];
    float4 b0 = *(const float4*)&bet[base];
    float4 b1 = *(const float4*)&bet[base + 4];
    float4 o0, o1;
    o0.x = d0 * rs * g0.x + b0.x;  o0.y = d1 * rs * g0.y + b0.y;
    o0.z = d2 * rs * g0.z + b0.z;  o0.w = d3 * rs * g0.w + b0.w;
    o1.x = d4 * rs * g1.x + b1.x;  o1.y = d5 * rs * g1.y + b1.y;
    o1.z = d6 * rs * g1.z + b1.z;  o1.w = d7 * rs * g1.w + b1.w;
    float* orow = out + (size_t)p * DIM;
    *(float4*)&orow[base] = o0;
    *(float4*)&orow[base + 4] = o1;
}

// -------------------- LayerNorm -> bf16 hi/lo (dense, block 0) --------------------
__global__ __launch_bounds__(256) void ln_hilo(const float* __restrict__ x,
                                               const float* __restrict__ gam,
                                               const float* __restrict__ bet,
                                               short* __restrict__ ohi,
                                               short* __restrict__ olo) {
    int wv = threadIdx.x >> 6, lane = threadIdx.x & 63;
    int t = (blockIdx.x << 2) | wv;
    const float* row = x + (size_t)t * DIM;
    int base = lane * 8;
    float4 v0 = *(const float4*)&row[base];
    float4 v1 = *(const float4*)&row[base + 4];
    float s = v0.x + v0.y + v0.z + v0.w + v1.x + v1.y + v1.z + v1.w;
#pragma unroll
    for (int o = 32; o; o >>= 1) s += __shfl_xor(s, o, 64);
    float mean = s * (1.0f / (float)DIM);
    float d[8] = {v0.x - mean, v0.y - mean, v0.z - mean, v0.w - mean,
                  v1.x - mean, v1.y - mean, v1.z - mean, v1.w - mean};
    float q = 0.0f;
#pragma unroll
    for (int j = 0; j < 8; ++j) q += d[j] * d[j];
#pragma unroll
    for (int o = 32; o; o >>= 1) q += __shfl_xor(q, o, 64);
    float var = q * (1.0f / (float)DIM);
    float rs = 1.0f / sqrtf(var + 1e-5f);
    float g[8], bb[8];
    *(float4*)&g[0] = *(const float4*)&gam[base];
    *(float4*)&g[4] = *(const float4*)&gam[base + 4];
    *(float4*)&bb[0] = *(const float4*)&bet[base];
    *(float4*)&bb[4] = *(const float4*)&bet[base + 4];
    short8_t hv, lv;
#pragma unroll
    for (int j = 0; j < 8; ++j) {
        float val = d[j] * rs * g[j] + bb[j];
        unsigned short hb = f2bf_rn(val);
        float hf = __uint_as_float((unsigned)hb << 16);
        hv[j] = (short)hb;
        lv[j] = (short)f2bf_rn(val - hf);
    }
    *(short8_t*)&ohi[(size_t)t * DIM + base] = hv;
    *(short8_t*)&olo[(size_t)t * DIM + base] = lv;
}

// -------------------- split-bf16 MFMA GEMM (128x128): C(M,N) = A(M,K) @ B(N,K)^T -----
// EPI: 0 = store hi/lo bf16; 1 = gelu + store hi/lo; 2 = residual add into Cf;
//      3 = plain fp32 store; 4 = residual add into Cf AND store hi/lo of the sum.
template<int EPI>
__global__ __launch_bounds__(256) void gemm_l_mfma(const short* __restrict__ Ah,
                                                   const short* __restrict__ Al,
                                                   const short* __restrict__ Bh,
                                                   const short* __restrict__ Bl,
                                                   float* __restrict__ Cf,
                                                   short* __restrict__ oHi,
                                                   short* __restrict__ oLo,
                                                   int N, int K) {
    __shared__ __align__(16) short sm[16384];
    short* sAh = sm;
    short* sAl = sm + 4096;
    short* sBh = sm + 8192;
    short* sBl = sm + 12288;
    const int tid = threadIdx.x;
    const int wv = tid >> 6, lane = tid & 63;
    const int m0 = blockIdx.x * 128;
    const int n0 = blockIdx.y * 128;
    const int wm = (wv & 1) * 64, wn = (wv >> 1) * 64;
    const int r16 = lane >> 2;
    const int gsw = ((lane & 3) ^ (r16 & 3)) << 3;
    const int fr = lane & 15;
    const int q = lane >> 4;

    f32x4 acc[4][4];
#pragma unroll
    for (int i = 0; i < 4; ++i)
#pragma unroll
        for (int j = 0; j < 4; ++j)
            acc[i][j] = (f32x4){0.0f, 0.0f, 0.0f, 0.0f};

    const int NKT = K >> 5;
    for (int kt = 0; kt < NKT; ++kt) {
        const int k0 = kt << 5;
        __syncthreads();
#pragma unroll
        for (int j = 0; j < 2; ++j) {
            const int rr = (wv << 5) + (j << 4);
            const int gr = rr + r16;
            const short* ga_h = Ah + (size_t)(m0 + gr) * K + k0 + gsw;
            const short* ga_l = Al + (size_t)(m0 + gr) * K + k0 + gsw;
            const short* gb_h = Bh + (size_t)(n0 + gr) * K + k0 + gsw;
            const short* gb_l = Bl + (size_t)(n0 + gr) * K + k0 + gsw;
            __builtin_amdgcn_global_load_lds((const __attribute__((address_space(1))) void*)ga_h,
                                             (__attribute__((address_space(3))) void*)(sAh + rr * 32), 16, 0, 0);
            __builtin_amdgcn_global_load_lds((const __attribute__((address_space(1))) void*)ga_l,
                                             (__attribute__((address_space(3))) void*)(sAl + rr * 32), 16, 0, 0);
            __builtin_amdgcn_global_load_lds((const __attribute__((address_space(1))) void*)gb_h,
                                             (__attribute__((address_space(3))) void*)(sBh + rr * 32), 16, 0, 0);
            __builtin_amdgcn_global_load_lds((const __attribute__((address_space(1))) void*)gb_l,
                                             (__attribute__((address_space(3))) void*)(sBl + rr * 32), 16, 0, 0);
        }
        __syncthreads();
        short8_t ah[4], al[4], bh[4], bl[4];
#pragma unroll
        for (int i = 0; i < 4; ++i) {
            const int ra = wm + i * 16 + fr;
            const int rb = wn + i * 16 + fr;
            const int swa = (q ^ (fr & 3)) << 3;
            ah[i] = *(const short8_t*)&sAh[ra * 32 + swa];
            al[i] = *(const short8_t*)&sAl[ra * 32 + swa];
            bh[i] = *(const short8_t*)&sBh[rb * 32 + swa];
            bl[i] = *(const short8_t*)&sBl[rb * 32 + swa];
        }
#pragma unroll
        for (int i = 0; i < 4; ++i)
#pragma unroll
            for (int j = 0; j < 4; ++j) {
                acc[i][j] = __builtin_amdgcn_mfma_f32_16x16x32_bf16(ah[i], bh[j], acc[i][j], 0, 0, 0);
                acc[i][j] = __builtin_amdgcn_mfma_f32_16x16x32_bf16(ah[i], bl[j], acc[i][j], 0, 0, 0);
                acc[i][j] = __builtin_amdgcn_mfma_f32_16x16x32_bf16(al[i], bh[j], acc[i][j], 0, 0, 0);
            }
    }
    const int row_base = (lane >> 4) << 2;
#pragma unroll
    for (int i = 0; i < 4; ++i)
#pragma unroll
        for (int j = 0; j < 4; ++j) {
            const int row = m0 + wm + i * 16 + row_base;
            const int col = n0 + wn + j * 16 + fr;
#pragma unroll
            for (int r = 0; r < 4; ++r) {
                float val = acc[i][j][r];
                if (EPI == 3) {
                    Cf[(size_t)(row + r) * N + col] = val;
                } else if (EPI == 2) {
                    Cf[(size_t)(row + r) * N + col] += val;
                } else if (EPI == 4) {
                    float* cp = &Cf[(size_t)(row + r) * N + col];
                    float nv = *cp + val;
                    *cp = nv;
                    unsigned short hb = f2bf_rn(nv);
                    float hf = __uint_as_float((unsigned)hb << 16);
                    oHi[(size_t)(row + r) * N + col] = (short)hb;
                    oLo[(size_t)(row + r) * N + col] = (short)f2bf_rn(nv - hf);
                } else {
                    if (EPI == 1) val = gelu_f(val);
                    unsigned short hb = f2bf_rn(val);
                    float hf = __uint_as_float((unsigned)hb << 16);
                    oHi[(size_t)(row + r) * N + col] = (short)hb;
                    oLo[(size_t)(row + r) * N + col] = (short)f2bf_rn(val - hf);
                }
            }
        }
}

// -------------------- PLAIN bf16 MFMA head GEMM (128x128, m97 structure) --------------------
// C = Ah @ Bh^T, single product. 2 stage arrays, 16 MFMA/kt, same verified both-side swizzle.
__global__ __launch_bounds__(256) void gemm_head_bf16(const short* __restrict__ Ah,
                                                      const short* __restrict__ Bh,
                                                      float* __restrict__ C,
                                                      int N, int K) {
    __shared__ __align__(16) short sm[8192];   // 2 x [128][32]
    short* sA = sm;
    short* sB = sm + 4096;
    const int tid = threadIdx.x;
    const int wv = tid >> 6, lane = tid & 63;
    const int m0 = blockIdx.x * 128;
    const int n0 = blockIdx.y * 128;
    const int wm = (wv & 1) * 64, wn = (wv >> 1) * 64;
    const int r16 = lane >> 2;
    const int gsw = ((lane & 3) ^ (r16 & 3)) << 3;
    const int fr = lane & 15;
    const int q = lane >> 4;

    f32x4 acc[4][4];
#pragma unroll
    for (int i = 0; i < 4; ++i)
#pragma unroll
        for (int j = 0; j < 4; ++j)
            acc[i][j] = (f32x4){0.0f, 0.0f, 0.0f, 0.0f};

    const int NKT = K >> 5;
    for (int kt = 0; kt < NKT; ++kt) {
        const int k0 = kt << 5;
        __syncthreads();
#pragma unroll
        for (int j = 0; j < 2; ++j) {
            const int rr = (wv << 5) + (j << 4);
            const int gr = rr + r16;
            const short* ga = Ah + (size_t)(m0 + gr) * K + k0 + gsw;
            const short* gb = Bh + (size_t)(n0 + gr) * K + k0 + gsw;
            __builtin_amdgcn_global_load_lds((const __attribute__((address_space(1))) void*)ga,
                                             (__attribute__((address_space(3))) void*)(sA + rr * 32), 16, 0, 0);
            __builtin_amdgcn_global_load_lds((const __attribute__((address_space(1))) void*)gb,
                                             (__attribute__((address_space(3))) void*)(sB + rr * 32), 16, 0, 0);
        }
        __syncthreads();
        short8_t ah[4], bh[4];
        const int swa = (q ^ (fr & 3)) << 3;
#pragma unroll
        for (int i = 0; i < 4; ++i) {
            ah[i] = *(const short8_t*)&sA[(wm + i * 16 + fr) * 32 + swa];
            bh[i] = *(const short8_t*)&sB[(wn + i * 16 + fr) * 32 + swa];
        }
#pragma unroll
        for (int i = 0; i < 4; ++i)
#pragma unroll
            for (int j = 0; j < 4; ++j)
                acc[i][j] = __builtin_amdgcn_mfma_f32_16x16x32_bf16(ah[i], bh[j], acc[i][j], 0, 0, 0);
    }
    const int row_base = (lane >> 4) << 2;
#pragma unroll
    for (int i = 0; i < 4; ++i)
#pragma unroll
        for (int j = 0; j < 4; ++j) {
            const int row = m0 + wm + i * 16 + row_base;
            const int col = n0 + wn + j * 16 + fr;
#pragma unroll
            for (int r = 0; r < 4; ++r)
                C[(size_t)(row + r) * N + col] = acc[i][j][r];
        }
}

// -------------------- split-bf16 MFMA GEMM (64x128 tile) for N=512 GEMMs --------------------
template<int EPI>
__global__ __launch_bounds__(256) void gemm_l64(const short* __restrict__ Ah,
                                                const short* __restrict__ Al,
                                                const short* __restrict__ Bh,
                                                const short* __restrict__ Bl,
                                                float* __restrict__ Cf,
                                                short* __restrict__ oHi,
                                                short* __restrict__ oLo,
                                                int N, int K) {
    __shared__ __align__(16) short sm[12288];
    short* sAh = sm;
    short* sAl = sm + 2048;
    short* sBh = sm + 4096;
    short* sBl = sm + 8192;
    const int tid = threadIdx.x;
    const int wv = tid >> 6, lane = tid & 63;
    const int m0 = blockIdx.x * 64;
    const int n0 = blockIdx.y * 128;
    const int wm = (wv & 1) * 32, wn = (wv >> 1) * 64;
    const int r16 = lane >> 2;
    const int gsw = ((lane & 3) ^ (r16 & 3)) << 3;
    const int fr = lane & 15;
    const int q = lane >> 4;

    f32x4 acc[2][4];
#pragma unroll
    for (int i = 0; i < 2; ++i)
#pragma unroll
        for (int j = 0; j < 4; ++j)
            acc[i][j] = (f32x4){0.0f, 0.0f, 0.0f, 0.0f};

    const int NKT = K >> 5;
    for (int kt = 0; kt < NKT; ++kt) {
        const int k0 = kt << 5;
        __syncthreads();
        {
            const int rr = wv << 4;
            const int gr = rr + r16;
            const short* ga_h = Ah + (size_t)(m0 + gr) * K + k0 + gsw;
            const short* ga_l = Al + (size_t)(m0 + gr) * K + k0 + gsw;
            __builtin_amdgcn_global_load_lds((const __attribute__((address_space(1))) void*)ga_h,
                                             (__attribute__((address_space(3))) void*)(sAh + rr * 32), 16, 0, 0);
            __builtin_amdgcn_global_load_lds((const __attribute__((address_space(1))) void*)ga_l,
                                             (__attribute__((address_space(3))) void*)(sAl + rr * 32), 16, 0, 0);
        }
#pragma unroll
        for (int j = 0; j < 2; ++j) {
            const int rr = (wv << 5) + (j << 4);
            const int gr = rr + r16;
            const short* gb_h = Bh + (size_t)(n0 + gr) * K + k0 + gsw;
            const short* gb_l = Bl + (size_t)(n0 + gr) * K + k0 + gsw;
            __builtin_amdgcn_global_load_lds((const __attribute__((address_space(1))) void*)gb_h,
                                             (__attribute__((address_space(3))) void*)(sBh + rr * 32), 16, 0, 0);
            __builtin_amdgcn_global_load_lds((const __attribute__((address_space(1))) void*)gb_l,
                                             (__attribute__((address_space(3))) void*)(sBl + rr * 32), 16, 0, 0);
        }
        __syncthreads();
        short8_t ah[2], al[2], bh[4], bl[4];
        const int swa = (q ^ (fr & 3)) << 3;
#pragma unroll
        for (int i = 0; i < 2; ++i) {
            const int ra = wm + i * 16 + fr;
            ah[i] = *(const short8_t*)&sAh[ra * 32 + swa];
            al[i] = *(const short8_t*)&sAl[ra * 32 + swa];
        }
#pragma unroll
        for (int j = 0; j < 4; ++j) {
            const int rb = wn + j * 16 + fr;
            bh[j] = *(const short8_t*)&sBh[rb * 32 + swa];
            bl[j] = *(const short8_t*)&sBl[rb * 32 + swa];
        }
#pragma unroll
        for (int i = 0; i < 2; ++i)
#pragma unroll
            for (int j = 0; j < 4; ++j) {
                acc[i][j] = __builtin_amdgcn_mfma_f32_16x16x32_bf16(ah[i], bh[j], acc[i][j], 0, 0, 0);
                acc[i][j] = __builtin_amdgcn_mfma_f32_16x16x32_bf16(ah[i], bl[j], acc[i][j], 0, 0, 0);
                acc[i][j] = __builtin_amdgcn_mfma_f32_16x16x32_bf16(al[i], bh[j], acc[i][j], 0, 0, 0);
            }
    }
    const int row_base = (lane >> 4) << 2;
#pragma unroll
    for (int i = 0; i < 2; ++i)
#pragma unroll
        for (int j = 0; j < 4; ++j) {
            const int row = m0 + wm + i * 16 + row_base;
            const int col = n0 + wn + j * 16 + fr;
#pragma unroll
            for (int r = 0; r < 4; ++r) {
                float val = acc[i][j][r];
                if (EPI == 3) {
                    Cf[(size_t)(row + r) * N + col] = val;
                } else if (EPI == 2) {
                    Cf[(size_t)(row + r) * N + col] += val;
                } else if (EPI == 4) {
                    float* cp = &Cf[(size_t)(row + r) * N + col];
                    float nv = *cp + val;
                    *cp = nv;
                    unsigned short hb = f2bf_rn(nv);
                    float hf = __uint_as_float((unsigned)hb << 16);
                    oHi[(size_t)(row + r) * N + col] = (short)hb;
                    oLo[(size_t)(row + r) * N + col] = (short)f2bf_rn(nv - hf);
                } else {
                    if (EPI == 1) val = gelu_f(val);
                    unsigned short hb = f2bf_rn(val);
                    float hf = __uint_as_float((unsigned)hb << 16);
                    oHi[(size_t)(row + r) * N + col] = (short)hb;
                    oLo[(size_t)(row + r) * N + col] = (short)f2bf_rn(val - hf);
                }
            }
        }
}

// -------------------- fp32 tiled GEMM (tier 2/3 dense block-0 path) --------------------
template<bool ADD, bool GELU>
__global__ __launch_bounds__(256) void gemm_nn(const float* __restrict__ A,
                                               const float* __restrict__ B,
                                               float* __restrict__ C,
                                               int M, int N, int K) {
    const int m0 = blockIdx.y * 64, n0 = blockIdx.x * 64;
    __shared__ float As[16][68];
    __shared__ float Bs[16][68];
    const int tid = threadIdx.x;
    const int am = tid >> 2, ak = (tid & 3) << 2;
    const int bk = tid >> 4, bn = (tid & 15) << 2;
    const int tn = tid & 15, tm = tid >> 4;
    float acc[4][4] = {};
    for (int k0 = 0; k0 < K; k0 += 16) {
        float4 a4 = *(const float4*)&A[(size_t)(m0 + am) * K + k0 + ak];
        float4 b4 = *(const float4*)&B[(size_t)(k0 + bk) * N + n0 + bn];
        __syncthreads();
        As[ak + 0][am] = a4.x;
        As[ak + 1][am] = a4.y;
        As[ak + 2][am] = a4.z;
        As[ak + 3][am] = a4.w;
        *(float4*)&Bs[bk][bn] = b4;
        __syncthreads();
#pragma unroll
        for (int kk = 0; kk < 16; ++kk) {
            float4 av = *(const float4*)&As[kk][tm << 2];
            float4 bv = *(const float4*)&Bs[kk][tn << 2];
            float a[4] = {av.x, av.y, av.z, av.w};
            float b[4] = {bv.x, bv.y, bv.z, bv.w};
#pragma unroll
            for (int i = 0; i < 4; ++i)
#pragma unroll
                for (int j = 0; j < 4; ++j)
                    acc[i][j] = fmaf(a[i], b[j], acc[i][j]);
        }
    }
#pragma unroll
    for (int i = 0; i < 4; ++i) {
        size_t row = (size_t)(m0 + (tm << 2) + i);
        float* cp = &C[row * (size_t)N + n0 + (tn << 2)];
        float rr[4] = {acc[i][0], acc[i][1], acc[i][2], acc[i][3]};
        if (GELU) {
#pragma unroll
            for (int j = 0; j < 4; ++j) rr[j] = gelu_f(rr[j]);
        }
        if (ADD) {
            float4 cc = *(const float4*)cp;
            rr[0] += cc.x; rr[1] += cc.y; rr[2] += cc.z; rr[3] += cc.w;
        }
        float4 rv = {rr[0], rr[1], rr[2], rr[3]};
        *(float4*)cp = rv;
    }
}

// -------------------- grid-stride fp32 GEMM over compacted rows (blocks 1-2) ----------
template<bool ADD, bool GELU, bool SCAT>
__global__ __launch_bounds__(256) void gemm_nn_gs(const float* __restrict__ A,
                                                  const float* __restrict__ B,
                                                  float* __restrict__ C,
                                                  int N, int K,
                                                  const int* __restrict__ idx,
                                                  const int* __restrict__ cnt) {
    const int c = *cnt;
    const int ntm = (c + 63) >> 6;
    const int ntn = N >> 6;
    const int total = ntm * ntn;
    __shared__ float As[16][68];
    __shared__ float Bs[16][68];
    const int tid = threadIdx.x;
    const int am = tid >> 2, ak = (tid & 3) << 2;
    const int bk = tid >> 4, bn = (tid & 15) << 2;
    const int tn = tid & 15, tm = tid >> 4;
    for (int tile = blockIdx.x; tile < total; tile += gridDim.x) {
        const int m0 = (tile % ntm) << 6, n0 = (tile / ntm) << 6;
        int ar = m0 + am;
        ar = ar < c ? ar : c - 1;
        float acc[4][4] = {};
        for (int k0 = 0; k0 < K; k0 += 16) {
            float4 a4 = *(const float4*)&A[(size_t)ar * K + k0 + ak];
            float4 b4 = *(const float4*)&B[(size_t)(k0 + bk) * N + n0 + bn];
            __syncthreads();
            As[ak + 0][am] = a4.x;
            As[ak + 1][am] = a4.y;
            As[ak + 2][am] = a4.z;
            As[ak + 3][am] = a4.w;
            *(float4*)&Bs[bk][bn] = b4;
            __syncthreads();
#pragma unroll
            for (int kk = 0; kk < 16; ++kk) {
                float4 av = *(const float4*)&As[kk][tm << 2];
                float4 bv = *(const float4*)&Bs[kk][tn << 2];
                float a[4] = {av.x, av.y, av.z, av.w};
                float b[4] = {bv.x, bv.y, bv.z, bv.w};
#pragma unroll
                for (int i = 0; i < 4; ++i)
#pragma unroll
                    for (int j = 0; j < 4; ++j)
                        acc[i][j] = fmaf(a[i], b[j], acc[i][j]);
            }
        }
#pragma unroll
        for (int i = 0; i < 4; ++i) {
            int p = m0 + (tm << 2) + i;
            if (p >= c) continue;
            int r = SCAT ? idx[p] : p;
            float* cp = &C[(size_t)r * N + n0 + (tn << 2)];
            float rr[4] = {acc[i][0], acc[i][1], acc[i][2], acc[i][3]};
            if (GELU) {
#pragma unroll
                for (int j = 0; j < 4; ++j) rr[j] = gelu_f(rr[j]);
            }
            if (ADD) {
                float4 cc = *(const float4*)cp;
                rr[0] += cc.x; rr[1] += cc.y; rr[2] += cc.z; rr[3] += cc.w;
            }
            float4 rv = {rr[0], rr[1], rr[2], rr[3]};
            *(float4*)cp = rv;
        }
        __syncthreads();
    }
}

// -------------------- grid-stride fp32 head GEMM over compacted rows (blocks 1-2) -----
__global__ __launch_bounds__(256) void gemm_nt_head_gs(const float* __restrict__ A,
                                                       const float* __restrict__ Bt,
                                                       float* __restrict__ C,
                                                       const int* __restrict__ idx,
                                                       const int* __restrict__ cnt) {
    const int c = *cnt;
    const int ntm = (c + 63) >> 6;
    const int ntn = NVOCAB >> 6;  // 500
    const int total = ntm * ntn;
    __shared__ float As[16][68];
    __shared__ float Bs[16][68];
    const int tid = threadIdx.x;
    const int am = tid >> 2, ak = (tid & 3) << 2;
    const int tn = tid & 15, tm = tid >> 4;
    for (int tile = blockIdx.x; tile < total; tile += gridDim.x) {
        const int m0 = (tile % ntm) << 6, n0 = (tile / ntm) << 6;
        int ap = m0 + am;
        int ar = idx[ap < c ? ap : c - 1];
        float acc[4][4] = {};
        for (int k0 = 0; k0 < DIM; k0 += 16) {
            float4 a4 = *(const float4*)&A[(size_t)ar * DIM + k0 + ak];
            float4 b4 = *(const float4*)&Bt[(size_t)(n0 + am) * DIM + k0 + ak];
            __syncthreads();
            As[ak + 0][am] = a4.x;
            As[ak + 1][am] = a4.y;
            As[ak + 2][am] = a4.z;
            As[ak + 3][am] = a4.w;
            Bs[ak + 0][am] = b4.x;
            Bs[ak + 1][am] = b4.y;
            Bs[ak + 2][am] = b4.z;
            Bs[ak + 3][am] = b4.w;
            __syncthreads();
#pragma unroll
            for (int kk = 0; kk < 16; ++kk) {
                float4 av = *(const float4*)&As[kk][tm << 2];
                float4 bv = *(const float4*)&Bs[kk][tn << 2];
                float a[4] = {av.x, av.y, av.z, av.w};
                float b[4] = {bv.x, bv.y, bv.z, bv.w};
#pragma unroll
                for (int i = 0; i < 4; ++i)
#pragma unroll
                    for (int j = 0; j < 4; ++j)
                        acc[i][j] = fmaf(a[i], b[j], acc[i][j]);
            }
        }
#pragma unroll
        for (int i = 0; i < 4; ++i) {
            int p = m0 + (tm << 2) + i;
            if (p >= c) continue;
            int r = idx[p];
            float4 rv = {acc[i][0], acc[i][1], acc[i][2], acc[i][3]};
            *(float4*)&C[(size_t)r * NVOCAB + n0 + (tn << 2)] = rv;
        }
        __syncthreads();
    }
}

// -------------------- confidence + exit (vectorized full-row read) --------------------
template<bool IDX>
__global__ __launch_bounds__(256) void conf_exit(const float* __restrict__ out,
                                                 int* __restrict__ flags,
                                                 const int* __restrict__ idx,
                                                 const int* __restrict__ cnt,
                                                 float thr) {
    int t;
    if (IDX) {
        if (blockIdx.x >= *cnt) return;
        t = idx[blockIdx.x];
    } else {
        t = blockIdx.x;
        if (flags[t] == 0) return;
    }
    const float4* row = (const float4*)(out + (size_t)t * NVOCAB);
    float m = -INFINITY, s = 0.0f;
    for (int i = threadIdx.x; i < NVOCAB / 4; i += 256) {
        float4 v = row[i];
        float m4 = fmaxf(fmaxf(v.x, v.y), fmaxf(v.z, v.w));
        float s4 = __expf(v.x - m4) + __expf(v.y - m4) + __expf(v.z - m4) + __expf(v.w - m4);
        if (m4 > m) {
            s = s * __expf(m - m4) + s4;
            m = m4;
        } else {
            s += s4 * __expf(m4 - m);
        }
    }
    __shared__ float ms[256], ss[256];
    ms[threadIdx.x] = m;
    ss[threadIdx.x] = s;
    __syncthreads();
    for (int st = 128; st; st >>= 1) {
        if (threadIdx.x < st) {
            float m1 = ms[threadIdx.x], s1 = ss[threadIdx.x];
            float m2 = ms[threadIdx.x + st], s2 = ss[threadIdx.x + st];
            float mm = fmaxf(m1, m2);
            ss[threadIdx.x] = s1 * __expf(m1 - mm) + s2 * __expf(m2 - mm);
            ms[threadIdx.x] = mm;
        }
        __syncthreads();
    }
    if (threadIdx.x == 0) {
        float conf = 1.0f / ss[0];
        if (conf > thr) flags[t] = 0;
    }
}

// -------------------- ordered compaction of active tokens (single block) --------------------
__global__ __launch_bounds__(256) void compact_kernel(const int* __restrict__ flags,
                                                      int* __restrict__ idx,
                                                      int* __restrict__ cnt) {
    __shared__ int wsum[4];
    __shared__ int base;
    if (threadIdx.x == 0) base = 0;
    int lane = threadIdx.x & 63, wv = threadIdx.x >> 6;
    for (int chunk = 0; chunk < TT; chunk += 256) {
        __syncthreads();
        int t = chunk + threadIdx.x;
        int f = flags[t];
        unsigned long long b = __ballot(f != 0);
        if (lane == 0) wsum[wv] = __popcll(b);
        __syncthreads();
        int off = base;
        for (int w = 0; w < wv; ++w) off += wsum[w];
        off += __popcll(b & ((1ull << lane) - 1));
        if (f) idx[off] = t;
        __syncthreads();
        if (threadIdx.x == 0) base += wsum[0] + wsum[1] + wsum[2] + wsum[3];
    }
    __syncthreads();
    if (threadIdx.x == 0) *cnt = base;
}

extern "C" void kernel_launch(void* const* d_in, const int* in_sizes, int n_in,
                              void* d_out, int out_size, void* d_ws, size_t ws_size,
                              hipStream_t stream) {
    const int* x = (const int*)d_in[0];
    const float* emb = (const float*)d_in[1];
    const float* head = (const float*)d_in[2];
    const float* Wv = (const float*)d_in[3];
    const float* Wo = (const float*)d_in[4];
    const float* W1 = (const float*)d_in[5];
    const float* W2 = (const float*)d_in[6];
    const float* ln1s = (const float*)d_in[7];
    const float* ln1b = (const float*)d_in[8];
    const float* ln2s = (const float*)d_in[9];
    const float* ln2b = (const float*)d_in[10];
    float* out = (float*)d_out;
    float* ws = (float*)d_ws;

    float* h  = ws;                      // TT*DIM fp32
    float* hn = ws + 2097152;            // TT*DIM
    float* tA = ws + 4194304;            // TT*DIM (scratch: WvFlat hi/lo during setup)
    float* tF = ws + 6291456;            // TT*FFN
    short* hnHi = (short*)hn;
    short* hnLo = hnHi + TT * DIM;
    short* tAHi = (short*)tA;
    short* tALo = tAHi + TT * DIM;
    short* tFHi = (short*)tF;
    short* tFLo = tFHi + TT * FFN;
    int* flags = (int*)(ws + 14680064);  // TT
    int* idxl  = flags + TT;             // TT
    int* cntp  = flags + 2 * TT;         // 1
    short* hHi    = (short*)(ws + 14700000);
    short* hLo    = (short*)(ws + 15748576);
    short* headHi = (short*)(ws + 16797152);
    short* headLo = (short*)(ws + 24989152);
    short* wT     = (short*)(ws + 33181152);  // 2 layers x 5242880 shorts
    const size_t LSTRIDE = 5242880;
    const size_t NEED_T2 = (size_t)33181152 * 4;
    const size_t NEED_T1 = (size_t)38424032 * 4;
    const int tier = ws_size >= NEED_T1 ? 1 : (ws_size >= NEED_T2 ? 2 : 3);

    gather_kernel<<<TT, 128, 0, stream>>>(x, emb, h, flags);

    const float THR[3] = {3.5e-05f, 4.0e-05f, 1.0f};
    const dim3 gDD(DIM / 64, TT / 64), gDF(FFN / 64, TT / 64), gHead(NVOCAB / 64, TT / 64);

    // ---------- block 0: dense ----------
    if (tier == 1) {
        // weight prep: WoT, W1T, W2T transpose-splits; W_voT = WoT @ WvFlat (MFMA)
        for (int l = 0; l < 2; ++l) {
            short* wb = wT + (size_t)l * LSTRIDE;
            cvt_hilo<<<(DIM * DIM / 4 + 255) / 256, 256, 0, stream>>>(Wv + (size_t)l * DIM * DIM, tAHi, tALo, DIM * DIM / 4);
            cvt_w_t<<<dim3(DIM / 32, DIM / 32), 256, 0, stream>>>(Wo + (size_t)l * DIM * DIM, wb + 524288, wb + 786432, DIM, DIM);
            gemm_l64<0><<<dim3(DIM / 64, DIM / 128), 256, 0, stream>>>(
                wb + 524288, wb + 786432, tAHi, tALo, nullptr, wb, wb + 262144, DIM, DIM);
            cvt_w_t<<<dim3(FFN / 32, DIM / 32), 256, 0, stream>>>(W1 + (size_t)l * DIM * FFN, wb + 1048576, wb + 2097152, DIM, FFN);
            cvt_w_t<<<dim3(DIM / 32, FFN / 32), 256, 0, stream>>>(W2 + (size_t)l * FFN * DIM, wb + 3145728, wb + 4194304, FFN, DIM);
        }
        for (int l = 0; l < 2; ++l) {
            short* wb = wT + (size_t)l * LSTRIDE;
            ln_hilo<<<TT / 4, 256, 0, stream>>>(h, ln1s + l * DIM, ln1b + l * DIM, hnHi, hnLo);
            gemm_l64<2><<<dim3(TT / 64, DIM / 128), 256, 0, stream>>>(hnHi, hnLo, wb, wb + 262144, h, nullptr, nullptr, DIM, DIM);
            ln_hilo<<<TT / 4, 256, 0, stream>>>(h, ln2s + l * DIM, ln2b + l * DIM, hnHi, hnLo);
            gemm_l_mfma<1><<<dim3(TT / 128, FFN / 128), 256, 0, stream>>>(hnHi, hnLo, wb + 1048576, wb + 2097152, nullptr, tFHi, tFLo, FFN, DIM);
            if (l == 1) {
                gemm_l64<4><<<dim3(TT / 64, DIM / 128), 256, 0, stream>>>(tFHi, tFLo, wb + 3145728, wb + 4194304, h, hHi, hLo, DIM, FFN);
            } else {
                gemm_l64<2><<<dim3(TT / 64, DIM / 128), 256, 0, stream>>>(tFHi, tFLo, wb + 3145728, wb + 4194304, h, nullptr, nullptr, DIM, FFN);
            }
        }
        cvt_bf16<<<(NVOCAB * DIM / 4 + 255) / 256, 256, 0, stream>>>(head, headHi, NVOCAB * DIM / 4);
        gemm_head_bf16<<<dim3(TT / 128, NVOCAB / 128), 256, 0, stream>>>(hHi, headHi, out, NVOCAB, DIM);
        conf_exit<false><<<TT, 256, 0, stream>>>(out, flags, nullptr, nullptr, THR[0]);
    } else {
        for (int l = 0; l < 2; ++l) {
            ln_kernel<false><<<TT / 4, 256, 0, stream>>>(h, ln1s + l * DIM, ln1b + l * DIM, hn, nullptr, nullptr);
            gemm_nn<false, false><<<gDD, 256, 0, stream>>>(hn, Wv + (size_t)l * DIM * DIM, tA, TT, DIM, DIM);
            gemm_nn<true, false><<<gDD, 256, 0, stream>>>(tA, Wo + (size_t)l * DIM * DIM, h, TT, DIM, DIM);
            ln_kernel<false><<<TT / 4, 256, 0, stream>>>(h, ln2s + l * DIM, ln2b + l * DIM, hn, nullptr, nullptr);
            gemm_nn<false, true><<<gDF, 256, 0, stream>>>(hn, W1 + (size_t)l * DIM * FFN, tF, TT, FFN, DIM);
            gemm_nn<true, false><<<gDD, 256, 0, stream>>>(tF, W2 + (size_t)l * FFN * DIM, h, TT, DIM, FFN);
        }
        if (tier == 2) {
            cvt_hilo<<<(TT * DIM / 4 + 255) / 256, 256, 0, stream>>>(h, hHi, hLo, TT * DIM / 4);
            cvt_hilo<<<(NVOCAB * DIM / 4 + 255) / 256, 256, 0, stream>>>(head, headHi, headLo, NVOCAB * DIM / 4);
            gemm_l_mfma<3><<<dim3(TT / 128, NVOCAB / 128), 256, 0, stream>>>(hHi, hLo, headHi, headLo, out, nullptr, nullptr, NVOCAB, DIM);
        } else {
            compact_kernel<<<1, 256, 0, stream>>>(flags, idxl, cntp);
            gemm_nt_head_gs<<<2048, 256, 0, stream>>>(h, head, out, idxl, cntp);
        }
        conf_exit<false><<<TT, 256, 0, stream>>>(out, flags, nullptr, nullptr, THR[0]);
    }
    compact_kernel<<<1, 256, 0, stream>>>(flags, idxl, cntp);

    // ---------- blocks 1,2: compacted active rows (grid-stride fp32 path; ~empty) ----------
    for (int b = 1; b < 3; ++b) {
        for (int li = 0; li < 2; ++li) {
            int l = b * 2 + li;
            ln_kernel<true><<<TT / 4, 256, 0, stream>>>(h, ln1s + l * DIM, ln1b + l * DIM, hn, idxl, cntp);
            gemm_nn_gs<false, false, false><<<1024, 256, 0, stream>>>(hn, Wv + (size_t)l * DIM * DIM, tA, DIM, DIM, idxl, cntp);
            gemm_nn_gs<true, false, true><<<1024, 256, 0, stream>>>(tA, Wo + (size_t)l * DIM * DIM, h, DIM, DIM, idxl, cntp);
            ln_kernel<true><<<TT / 4, 256, 0, stream>>>(h, ln2s + l * DIM, ln2b + l * DIM, hn, idxl, cntp);
            gemm_nn_gs<false, true, false><<<1024, 256, 0, stream>>>(hn, W1 + (size_t)l * DIM * FFN, tF, FFN, DIM, idxl, cntp);
            gemm_nn_gs<true, false, true><<<1024, 256, 0, stream>>>(tF, W2 + (size_t)l * FFN * DIM, h, DIM, FFN, idxl, cntp);
        }
        gemm_nt_head_gs<<<2048, 256, 0, stream>>>(h, head, out, idxl, cntp);
        if (b == 1) {
            conf_exit<true><<<TT, 256, 0, stream>>>(out, flags, idxl, cntp, THR[1]);
            compact_kernel<<<1, 256, 0, stream>>>(flags, idxl, cntp);
        }
    }
}

// Round 12
// 742.097 us; speedup vs baseline: 1.4449x; 1.0699x over previous
//
#include <hip/hip_runtime.h>
#include <hip/hip_bf16.h>
#include <math.h>

#define TT 4096
#define DIM 512
#define FFN 2048
#define NVOCAB 32000

typedef __attribute__((ext_vector_type(8))) short short8_t;
typedef __attribute__((ext_vector_type(4))) float f32x4;

__device__ __forceinline__ float gelu_f(float x) {
    float x3 = x * x * x;
    float u = 0.7978845608028654f * (x + 0.044715f * x3);
    return 0.5f * x * (1.0f + tanhf(u));
}

__device__ __forceinline__ unsigned short f2bf_rn(float f) {
    unsigned u = __float_as_uint(f);
    u += 0x7FFFu + ((u >> 16) & 1u);
    return (unsigned short)(u >> 16);
}

// -------------------- embedding gather + flag init --------------------
__global__ __launch_bounds__(128) void gather_kernel(const int* __restrict__ x,
                                                     const float* __restrict__ emb,
                                                     float* __restrict__ h,
                                                     int* __restrict__ flags) {
    int t = blockIdx.x;
    int idx = x[t];
    const float4 v = *(const float4*)&emb[(size_t)idx * DIM + threadIdx.x * 4];
    *(float4*)&h[(size_t)t * DIM + threadIdx.x * 4] = v;
    if (threadIdx.x == 0) flags[t] = 1;
}

// -------------------- fp32 -> bf16 hi/lo split (flat) --------------------
__global__ __launch_bounds__(256) void cvt_hilo(const float* __restrict__ src,
                                                short* __restrict__ hi,
                                                short* __restrict__ lo, int n4) {
    int i = blockIdx.x * 256 + threadIdx.x;
    if (i >= n4) return;
    float4 v = *(const float4*)&src[(size_t)i * 4];
    float f[4] = {v.x, v.y, v.z, v.w};
    short4 hv, lv;
    short* hp = &hv.x;
    short* lp = &lv.x;
#pragma unroll
    for (int j = 0; j < 4; ++j) {
        unsigned short hb = f2bf_rn(f[j]);
        float hf = __uint_as_float((unsigned)hb << 16);
        unsigned short lb = f2bf_rn(f[j] - hf);
        hp[j] = (short)hb;
        lp[j] = (short)lb;
    }
    *(short4*)&hi[(size_t)i * 4] = hv;
    *(short4*)&lo[(size_t)i * 4] = lv;
}

// -------------------- fp32 -> bf16 (hi only, flat) --------------------
__global__ __launch_bounds__(256) void cvt_bf16(const float* __restrict__ src,
                                                short* __restrict__ hi, int n4) {
    int i = blockIdx.x * 256 + threadIdx.x;
    if (i >= n4) return;
    float4 v = *(const float4*)&src[(size_t)i * 4];
    float f[4] = {v.x, v.y, v.z, v.w};
    short4 hv;
    short* hp = &hv.x;
#pragma unroll
    for (int j = 0; j < 4; ++j) hp[j] = (short)f2bf_rn(f[j]);
    *(short4*)&hi[(size_t)i * 4] = hv;
}

// -------------------- fp32 W (K,N) -> bf16 hi/lo transposed (N,K) --------------------
__global__ __launch_bounds__(256) void cvt_w_t(const float* __restrict__ W,
                                               short* __restrict__ hiT,
                                               short* __restrict__ loT,
                                               int K, int N) {
    __shared__ short hs[32][36];
    __shared__ short ls[32][36];
    const int n0 = blockIdx.x * 32, k0 = blockIdx.y * 32;
    const int r = threadIdx.x >> 3, c4 = (threadIdx.x & 7) << 2;
    float4 v = *(const float4*)&W[(size_t)(k0 + r) * N + n0 + c4];
    float f[4] = {v.x, v.y, v.z, v.w};
#pragma unroll
    for (int j = 0; j < 4; ++j) {
        unsigned short hb = f2bf_rn(f[j]);
        float hf = __uint_as_float((unsigned)hb << 16);
        unsigned short lb = f2bf_rn(f[j] - hf);
        hs[r][c4 + j] = (short)hb;
        ls[r][c4 + j] = (short)lb;
    }
    __syncthreads();
    const int nr = threadIdx.x >> 3, kc4 = (threadIdx.x & 7) << 2;
    short4 hv, lv;
    short* hp = &hv.x;
    short* lp = &lv.x;
#pragma unroll
    for (int j = 0; j < 4; ++j) {
        hp[j] = hs[kc4 + j][nr];
        lp[j] = ls[kc4 + j][nr];
    }
    *(short4*)&hiT[(size_t)(n0 + nr) * K + k0 + kc4] = hv;
    *(short4*)&loT[(size_t)(n0 + nr) * K + k0 + kc4] = lv;
}

// -------------------- LayerNorm (fp32 out; optional index gather) --------------------
template<bool IDX>
__global__ __launch_bounds__(256) void ln_kernel(const float* __restrict__ x,
                                                 const float* __restrict__ gam,
                                                 const float* __restrict__ bet,
                                                 float* __restrict__ out,
                                                 const int* __restrict__ idx,
                                                 const int* __restrict__ cnt) {
    int wv = threadIdx.x >> 6, lane = threadIdx.x & 63;
    int p = (blockIdx.x << 2) | wv;
    if (IDX && p >= *cnt) return;
    int t = IDX ? idx[p] : p;
    const float* row = x + (size_t)t * DIM;
    int base = lane * 8;
    float4 v0 = *(const float4*)&row[base];
    float4 v1 = *(const float4*)&row[base + 4];
    float s = v0.x + v0.y + v0.z + v0.w + v1.x + v1.y + v1.z + v1.w;
#pragma unroll
    for (int o = 32; o; o >>= 1) s += __shfl_xor(s, o, 64);
    float mean = s * (1.0f / (float)DIM);
    float d0 = v0.x - mean, d1 = v0.y - mean, d2 = v0.z - mean, d3 = v0.w - mean;
    float d4 = v1.x - mean, d5 = v1.y - mean, d6 = v1.z - mean, d7 = v1.w - mean;
    float q = d0*d0 + d1*d1 + d2*d2 + d3*d3 + d4*d4 + d5*d5 + d6*d6 + d7*d7;
#pragma unroll
    for (int o = 32; o; o >>= 1) q += __shfl_xor(q, o, 64);
    float var = q * (1.0f / (float)DIM);
    float rs = 1.0f / sqrtf(var + 1e-5f);
    float4 g0 = *(const float4*)&gam[base];
    float4 g1 = *(const float4*)&gam[base + 4];
    float4 b0 = *(const float4*)&bet[base];
    float4 b1 = *(const float4*)&bet[base + 4];
    float4 o0, o1;
    o0.x = d0 * rs * g0.x + b0.x;  o0.y = d1 * rs * g0.y + b0.y;
    o0.z = d2 * rs * g0.z + b0.z;  o0.w = d3 * rs * g0.w + b0.w;
    o1.x = d4 * rs * g1.x + b1.x;  o1.y = d5 * rs * g1.y + b1.y;
    o1.z = d6 * rs * g1.z + b1.z;  o1.w = d7 * rs * g1.w + b1.w;
    float* orow = out + (size_t)p * DIM;
    *(float4*)&orow[base] = o0;
    *(float4*)&orow[base + 4] = o1;
}

// -------------------- LayerNorm -> bf16 hi/lo (dense, block 0) --------------------
__global__ __launch_bounds__(256) void ln_hilo(const float* __restrict__ x,
                                               const float* __restrict__ gam,
                                               const float* __restrict__ bet,
                                               short* __restrict__ ohi,
                                               short* __restrict__ olo) {
    int wv = threadIdx.x >> 6, lane = threadIdx.x & 63;
    int t = (blockIdx.x << 2) | wv;
    const float* row = x + (size_t)t * DIM;
    int base = lane * 8;
    float4 v0 = *(const float4*)&row[base];
    float4 v1 = *(const float4*)&row[base + 4];
    float s = v0.x + v0.y + v0.z + v0.w + v1.x + v1.y + v1.z + v1.w;
#pragma unroll
    for (int o = 32; o; o >>= 1) s += __shfl_xor(s, o, 64);
    float mean = s * (1.0f / (float)DIM);
    float d[8] = {v0.x - mean, v0.y - mean, v0.z - mean, v0.w - mean,
                  v1.x - mean, v1.y - mean, v1.z - mean, v1.w - mean};
    float q = 0.0f;
#pragma unroll
    for (int j = 0; j < 8; ++j) q += d[j] * d[j];
#pragma unroll
    for (int o = 32; o; o >>= 1) q += __shfl_xor(q, o, 64);
    float var = q * (1.0f / (float)DIM);
    float rs = 1.0f / sqrtf(var + 1e-5f);
    float g[8], bb[8];
    *(float4*)&g[0] = *(const float4*)&gam[base];
    *(float4*)&g[4] = *(const float4*)&gam[base + 4];
    *(float4*)&bb[0] = *(const float4*)&bet[base];
    *(float4*)&bb[4] = *(const float4*)&bet[base + 4];
    short8_t hv, lv;
#pragma unroll
    for (int j = 0; j < 8; ++j) {
        float val = d[j] * rs * g[j] + bb[j];
        unsigned short hb = f2bf_rn(val);
        float hf = __uint_as_float((unsigned)hb << 16);
        hv[j] = (short)hb;
        lv[j] = (short)f2bf_rn(val - hf);
    }
    *(short8_t*)&ohi[(size_t)t * DIM + base] = hv;
    *(short8_t*)&olo[(size_t)t * DIM + base] = lv;
}

// ==================== EPILOGUE helper ====================
__device__ __forceinline__ void epi_store(int EPI, float val, size_t off,
                                          float* Cf, short* oHi, short* oLo) {
    if (EPI == 3) {
        Cf[off] = val;
    } else if (EPI == 2) {
        Cf[off] += val;
    } else if (EPI == 4) {
        float nv = Cf[off] + val;
        Cf[off] = nv;
        unsigned short hb = f2bf_rn(nv);
        float hf = __uint_as_float((unsigned)hb << 16);
        oHi[off] = (short)hb;
        oLo[off] = (short)f2bf_rn(nv - hf);
    } else {
        if (EPI == 1) val = gelu_f(val);
        unsigned short hb = f2bf_rn(val);
        float hf = __uint_as_float((unsigned)hb << 16);
        oHi[off] = (short)hb;
        oLo[off] = (short)f2bf_rn(val - hf);
    }
}

// -------------------- 3-product split-bf16 MFMA GEMM (128x128) --------------------
template<int EPI>
__global__ __launch_bounds__(256) void gemm_l_mfma(const short* __restrict__ Ah,
                                                   const short* __restrict__ Al,
                                                   const short* __restrict__ Bh,
                                                   const short* __restrict__ Bl,
                                                   float* __restrict__ Cf,
                                                   short* __restrict__ oHi,
                                                   short* __restrict__ oLo,
                                                   int N, int K) {
    __shared__ __align__(16) short sm[16384];
    short* sAh = sm;
    short* sAl = sm + 4096;
    short* sBh = sm + 8192;
    short* sBl = sm + 12288;
    const int tid = threadIdx.x;
    const int wv = tid >> 6, lane = tid & 63;
    const int m0 = blockIdx.x * 128;
    const int n0 = blockIdx.y * 128;
    const int wm = (wv & 1) * 64, wn = (wv >> 1) * 64;
    const int r16 = lane >> 2;
    const int gsw = ((lane & 3) ^ (r16 & 3)) << 3;
    const int fr = lane & 15;
    const int q = lane >> 4;

    f32x4 acc[4][4];
#pragma unroll
    for (int i = 0; i < 4; ++i)
#pragma unroll
        for (int j = 0; j < 4; ++j)
            acc[i][j] = (f32x4){0.0f, 0.0f, 0.0f, 0.0f};

    const int NKT = K >> 5;
    for (int kt = 0; kt < NKT; ++kt) {
        const int k0 = kt << 5;
        __syncthreads();
#pragma unroll
        for (int j = 0; j < 2; ++j) {
            const int rr = (wv << 5) + (j << 4);
            const int gr = rr + r16;
            const short* ga_h = Ah + (size_t)(m0 + gr) * K + k0 + gsw;
            const short* ga_l = Al + (size_t)(m0 + gr) * K + k0 + gsw;
            const short* gb_h = Bh + (size_t)(n0 + gr) * K + k0 + gsw;
            const short* gb_l = Bl + (size_t)(n0 + gr) * K + k0 + gsw;
            __builtin_amdgcn_global_load_lds((const __attribute__((address_space(1))) void*)ga_h,
                                             (__attribute__((address_space(3))) void*)(sAh + rr * 32), 16, 0, 0);
            __builtin_amdgcn_global_load_lds((const __attribute__((address_space(1))) void*)ga_l,
                                             (__attribute__((address_space(3))) void*)(sAl + rr * 32), 16, 0, 0);
            __builtin_amdgcn_global_load_lds((const __attribute__((address_space(1))) void*)gb_h,
                                             (__attribute__((address_space(3))) void*)(sBh + rr * 32), 16, 0, 0);
            __builtin_amdgcn_global_load_lds((const __attribute__((address_space(1))) void*)gb_l,
                                             (__attribute__((address_space(3))) void*)(sBl + rr * 32), 16, 0, 0);
        }
        __syncthreads();
        short8_t ah[4], al[4], bh[4], bl[4];
#pragma unroll
        for (int i = 0; i < 4; ++i) {
            const int ra = wm + i * 16 + fr;
            const int rb = wn + i * 16 + fr;
            const int swa = (q ^ (fr & 3)) << 3;
            ah[i] = *(const short8_t*)&sAh[ra * 32 + swa];
            al[i] = *(const short8_t*)&sAl[ra * 32 + swa];
            bh[i] = *(const short8_t*)&sBh[rb * 32 + swa];
            bl[i] = *(const short8_t*)&sBl[rb * 32 + swa];
        }
#pragma unroll
        for (int i = 0; i < 4; ++i)
#pragma unroll
            for (int j = 0; j < 4; ++j) {
                acc[i][j] = __builtin_amdgcn_mfma_f32_16x16x32_bf16(ah[i], bh[j], acc[i][j], 0, 0, 0);
                acc[i][j] = __builtin_amdgcn_mfma_f32_16x16x32_bf16(ah[i], bl[j], acc[i][j], 0, 0, 0);
                acc[i][j] = __builtin_amdgcn_mfma_f32_16x16x32_bf16(al[i], bh[j], acc[i][j], 0, 0, 0);
            }
    }
    const int row_base = (lane >> 4) << 2;
#pragma unroll
    for (int i = 0; i < 4; ++i)
#pragma unroll
        for (int j = 0; j < 4; ++j) {
            const int row = m0 + wm + i * 16 + row_base;
            const int col = n0 + wn + j * 16 + fr;
#pragma unroll
            for (int r = 0; r < 4; ++r)
                epi_store(EPI, acc[i][j][r], (size_t)(row + r) * N + col, Cf, oHi, oLo);
        }
}

// -------------------- 2-product GEMM (128x128): A hi/lo, B hi only --------------------
template<int EPI>
__global__ __launch_bounds__(256) void gemm_l2(const short* __restrict__ Ah,
                                               const short* __restrict__ Al,
                                               const short* __restrict__ Bh,
                                               float* __restrict__ Cf,
                                               short* __restrict__ oHi,
                                               short* __restrict__ oLo,
                                               int N, int K) {
    __shared__ __align__(16) short sm[12288];
    short* sAh = sm;
    short* sAl = sm + 4096;
    short* sBh = sm + 8192;
    const int tid = threadIdx.x;
    const int wv = tid >> 6, lane = tid & 63;
    const int m0 = blockIdx.x * 128;
    const int n0 = blockIdx.y * 128;
    const int wm = (wv & 1) * 64, wn = (wv >> 1) * 64;
    const int r16 = lane >> 2;
    const int gsw = ((lane & 3) ^ (r16 & 3)) << 3;
    const int fr = lane & 15;
    const int q = lane >> 4;

    f32x4 acc[4][4];
#pragma unroll
    for (int i = 0; i < 4; ++i)
#pragma unroll
        for (int j = 0; j < 4; ++j)
            acc[i][j] = (f32x4){0.0f, 0.0f, 0.0f, 0.0f};

    const int NKT = K >> 5;
    for (int kt = 0; kt < NKT; ++kt) {
        const int k0 = kt << 5;
        __syncthreads();
#pragma unroll
        for (int j = 0; j < 2; ++j) {
            const int rr = (wv << 5) + (j << 4);
            const int gr = rr + r16;
            const short* ga_h = Ah + (size_t)(m0 + gr) * K + k0 + gsw;
            const short* ga_l = Al + (size_t)(m0 + gr) * K + k0 + gsw;
            const short* gb_h = Bh + (size_t)(n0 + gr) * K + k0 + gsw;
            __builtin_amdgcn_global_load_lds((const __attribute__((address_space(1))) void*)ga_h,
                                             (__attribute__((address_space(3))) void*)(sAh + rr * 32), 16, 0, 0);
            __builtin_amdgcn_global_load_lds((const __attribute__((address_space(1))) void*)ga_l,
                                             (__attribute__((address_space(3))) void*)(sAl + rr * 32), 16, 0, 0);
            __builtin_amdgcn_global_load_lds((const __attribute__((address_space(1))) void*)gb_h,
                                             (__attribute__((address_space(3))) void*)(sBh + rr * 32), 16, 0, 0);
        }
        __syncthreads();
        short8_t ah[4], al[4], bh[4];
#pragma unroll
        for (int i = 0; i < 4; ++i) {
            const int ra = wm + i * 16 + fr;
            const int rb = wn + i * 16 + fr;
            const int swa = (q ^ (fr & 3)) << 3;
            ah[i] = *(const short8_t*)&sAh[ra * 32 + swa];
            al[i] = *(const short8_t*)&sAl[ra * 32 + swa];
            bh[i] = *(const short8_t*)&sBh[rb * 32 + swa];
        }
#pragma unroll
        for (int i = 0; i < 4; ++i)
#pragma unroll
            for (int j = 0; j < 4; ++j) {
                acc[i][j] = __builtin_amdgcn_mfma_f32_16x16x32_bf16(ah[i], bh[j], acc[i][j], 0, 0, 0);
                acc[i][j] = __builtin_amdgcn_mfma_f32_16x16x32_bf16(al[i], bh[j], acc[i][j], 0, 0, 0);
            }
    }
    const int row_base = (lane >> 4) << 2;
#pragma unroll
    for (int i = 0; i < 4; ++i)
#pragma unroll
        for (int j = 0; j < 4; ++j) {
            const int row = m0 + wm + i * 16 + row_base;
            const int col = n0 + wn + j * 16 + fr;
#pragma unroll
            for (int r = 0; r < 4; ++r)
                epi_store(EPI, acc[i][j][r], (size_t)(row + r) * N + col, Cf, oHi, oLo);
        }
}

// -------------------- 2-product GEMM (64x128): A hi/lo, B hi only --------------------
template<int EPI>
__global__ __launch_bounds__(256) void gemm_l64b(const short* __restrict__ Ah,
                                                 const short* __restrict__ Al,
                                                 const short* __restrict__ Bh,
                                                 float* __restrict__ Cf,
                                                 short* __restrict__ oHi,
                                                 short* __restrict__ oLo,
                                                 int N, int K) {
    __shared__ __align__(16) short sm[8192];
    short* sAh = sm;
    short* sAl = sm + 2048;
    short* sBh = sm + 4096;
    const int tid = threadIdx.x;
    const int wv = tid >> 6, lane = tid & 63;
    const int m0 = blockIdx.x * 64;
    const int n0 = blockIdx.y * 128;
    const int wm = (wv & 1) * 32, wn = (wv >> 1) * 64;
    const int r16 = lane >> 2;
    const int gsw = ((lane & 3) ^ (r16 & 3)) << 3;
    const int fr = lane & 15;
    const int q = lane >> 4;

    f32x4 acc[2][4];
#pragma unroll
    for (int i = 0; i < 2; ++i)
#pragma unroll
        for (int j = 0; j < 4; ++j)
            acc[i][j] = (f32x4){0.0f, 0.0f, 0.0f, 0.0f};

    const int NKT = K >> 5;
    for (int kt = 0; kt < NKT; ++kt) {
        const int k0 = kt << 5;
        __syncthreads();
        {
            const int rr = wv << 4;
            const int gr = rr + r16;
            const short* ga_h = Ah + (size_t)(m0 + gr) * K + k0 + gsw;
            const short* ga_l = Al + (size_t)(m0 + gr) * K + k0 + gsw;
            __builtin_amdgcn_global_load_lds((const __attribute__((address_space(1))) void*)ga_h,
                                             (__attribute__((address_space(3))) void*)(sAh + rr * 32), 16, 0, 0);
            __builtin_amdgcn_global_load_lds((const __attribute__((address_space(1))) void*)ga_l,
                                             (__attribute__((address_space(3))) void*)(sAl + rr * 32), 16, 0, 0);
        }
#pragma unroll
        for (int j = 0; j < 2; ++j) {
            const int rr = (wv << 5) + (j << 4);
            const int gr = rr + r16;
            const short* gb_h = Bh + (size_t)(n0 + gr) * K + k0 + gsw;
            __builtin_amdgcn_global_load_lds((const __attribute__((address_space(1))) void*)gb_h,
                                             (__attribute__((address_space(3))) void*)(sBh + rr * 32), 16, 0, 0);
        }
        __syncthreads();
        short8_t ah[2], al[2], bh[4];
        const int swa = (q ^ (fr & 3)) << 3;
#pragma unroll
        for (int i = 0; i < 2; ++i) {
            const int ra = wm + i * 16 + fr;
            ah[i] = *(const short8_t*)&sAh[ra * 32 + swa];
            al[i] = *(const short8_t*)&sAl[ra * 32 + swa];
        }
#pragma unroll
        for (int j = 0; j < 4; ++j) {
            const int rb = wn + j * 16 + fr;
            bh[j] = *(const short8_t*)&sBh[rb * 32 + swa];
        }
#pragma unroll
        for (int i = 0; i < 2; ++i)
#pragma unroll
            for (int j = 0; j < 4; ++j) {
                acc[i][j] = __builtin_amdgcn_mfma_f32_16x16x32_bf16(ah[i], bh[j], acc[i][j], 0, 0, 0);
                acc[i][j] = __builtin_amdgcn_mfma_f32_16x16x32_bf16(al[i], bh[j], acc[i][j], 0, 0, 0);
            }
    }
    const int row_base = (lane >> 4) << 2;
#pragma unroll
    for (int i = 0; i < 2; ++i)
#pragma unroll
        for (int j = 0; j < 4; ++j) {
            const int row = m0 + wm + i * 16 + row_base;
            const int col = n0 + wn + j * 16 + fr;
#pragma unroll
            for (int r = 0; r < 4; ++r)
                epi_store(EPI, acc[i][j][r], (size_t)(row + r) * N + col, Cf, oHi, oLo);
        }
}

// -------------------- 3-product GEMM (64x128) — W_vo prep only --------------------
template<int EPI>
__global__ __launch_bounds__(256) void gemm_l64(const short* __restrict__ Ah,
                                                const short* __restrict__ Al,
                                                const short* __restrict__ Bh,
                                                const short* __restrict__ Bl,
                                                float* __restrict__ Cf,
                                                short* __restrict__ oHi,
                                                short* __restrict__ oLo,
                                                int N, int K) {
    __shared__ __align__(16) short sm[12288];
    short* sAh = sm;
    short* sAl = sm + 2048;
    short* sBh = sm + 4096;
    short* sBl = sm + 8192;
    const int tid = threadIdx.x;
    const int wv = tid >> 6, lane = tid & 63;
    const int m0 = blockIdx.x * 64;
    const int n0 = blockIdx.y * 128;
    const int wm = (wv & 1) * 32, wn = (wv >> 1) * 64;
    const int r16 = lane >> 2;
    const int gsw = ((lane & 3) ^ (r16 & 3)) << 3;
    const int fr = lane & 15;
    const int q = lane >> 4;

    f32x4 acc[2][4];
#pragma unroll
    for (int i = 0; i < 2; ++i)
#pragma unroll
        for (int j = 0; j < 4; ++j)
            acc[i][j] = (f32x4){0.0f, 0.0f, 0.0f, 0.0f};

    const int NKT = K >> 5;
    for (int kt = 0; kt < NKT; ++kt) {
        const int k0 = kt << 5;
        __syncthreads();
        {
            const int rr = wv << 4;
            const int gr = rr + r16;
            const short* ga_h = Ah + (size_t)(m0 + gr) * K + k0 + gsw;
            const short* ga_l = Al + (size_t)(m0 + gr) * K + k0 + gsw;
            __builtin_amdgcn_global_load_lds((const __attribute__((address_space(1))) void*)ga_h,
                                             (__attribute__((address_space(3))) void*)(sAh + rr * 32), 16, 0, 0);
            __builtin_amdgcn_global_load_lds((const __attribute__((address_space(1))) void*)ga_l,
                                             (__attribute__((address_space(3))) void*)(sAl + rr * 32), 16, 0, 0);
        }
#pragma unroll
        for (int j = 0; j < 2; ++j) {
            const int rr = (wv << 5) + (j << 4);
            const int gr = rr + r16;
            const short* gb_h = Bh + (size_t)(n0 + gr) * K + k0 + gsw;
            const short* gb_l = Bl + (size_t)(n0 + gr) * K + k0 + gsw;
            __builtin_amdgcn_global_load_lds((const __attribute__((address_space(1))) void*)gb_h,
                                             (__attribute__((address_space(3))) void*)(sBh + rr * 32), 16, 0, 0);
            __builtin_amdgcn_global_load_lds((const __attribute__((address_space(1))) void*)gb_l,
                                             (__attribute__((address_space(3))) void*)(sBl + rr * 32), 16, 0, 0);
        }
        __syncthreads();
        short8_t ah[2], al[2], bh[4], bl[4];
        const int swa = (q ^ (fr & 3)) << 3;
#pragma unroll
        for (int i = 0; i < 2; ++i) {
            const int ra = wm + i * 16 + fr;
            ah[i] = *(const short8_t*)&sAh[ra * 32 + swa];
            al[i] = *(const short8_t*)&sAl[ra * 32 + swa];
        }
#pragma unroll
        for (int j = 0; j < 4; ++j) {
            const int rb = wn + j * 16 + fr;
            bh[j] = *(const short8_t*)&sBh[rb * 32 + swa];
            bl[j] = *(const short8_t*)&sBl[rb * 32 + swa];
        }
#pragma unroll
        for (int i = 0; i < 2; ++i)
#pragma unroll
            for (int j = 0; j < 4; ++j) {
                acc[i][j] = __builtin_amdgcn_mfma_f32_16x16x32_bf16(ah[i], bh[j], acc[i][j], 0, 0, 0);
                acc[i][j] = __builtin_amdgcn_mfma_f32_16x16x32_bf16(ah[i], bl[j], acc[i][j], 0, 0, 0);
                acc[i][j] = __builtin_amdgcn_mfma_f32_16x16x32_bf16(al[i], bh[j], acc[i][j], 0, 0, 0);
            }
    }
    const int row_base = (lane >> 4) << 2;
#pragma unroll
    for (int i = 0; i < 2; ++i)
#pragma unroll
        for (int j = 0; j < 4; ++j) {
            const int row = m0 + wm + i * 16 + row_base;
            const int col = n0 + wn + j * 16 + fr;
#pragma unroll
            for (int r = 0; r < 4; ++r)
                epi_store(EPI, acc[i][j][r], (size_t)(row + r) * N + col, Cf, oHi, oLo);
        }
}

// -------------------- PLAIN bf16 MFMA head GEMM (128x128, m97 structure) --------------------
__global__ __launch_bounds__(256) void gemm_head_bf16(const short* __restrict__ Ah,
                                                      const short* __restrict__ Bh,
                                                      float* __restrict__ C,
                                                      int N, int K) {
    __shared__ __align__(16) short sm[8192];
    short* sA = sm;
    short* sB = sm + 4096;
    const int tid = threadIdx.x;
    const int wv = tid >> 6, lane = tid & 63;
    const int m0 = blockIdx.x * 128;
    const int n0 = blockIdx.y * 128;
    const int wm = (wv & 1) * 64, wn = (wv >> 1) * 64;
    const int r16 = lane >> 2;
    const int gsw = ((lane & 3) ^ (r16 & 3)) << 3;
    const int fr = lane & 15;
    const int q = lane >> 4;

    f32x4 acc[4][4];
#pragma unroll
    for (int i = 0; i < 4; ++i)
#pragma unroll
        for (int j = 0; j < 4; ++j)
            acc[i][j] = (f32x4){0.0f, 0.0f, 0.0f, 0.0f};

    const int NKT = K >> 5;
    for (int kt = 0; kt < NKT; ++kt) {
        const int k0 = kt << 5;
        __syncthreads();
#pragma unroll
        for (int j = 0; j < 2; ++j) {
            const int rr = (wv << 5) + (j << 4);
            const int gr = rr + r16;
            const short* ga = Ah + (size_t)(m0 + gr) * K + k0 + gsw;
            const short* gb = Bh + (size_t)(n0 + gr) * K + k0 + gsw;
            __builtin_amdgcn_global_load_lds((const __attribute__((address_space(1))) void*)ga,
                                             (__attribute__((address_space(3))) void*)(sA + rr * 32), 16, 0, 0);
            __builtin_amdgcn_global_load_lds((const __attribute__((address_space(1))) void*)gb,
                                             (__attribute__((address_space(3))) void*)(sB + rr * 32), 16, 0, 0);
        }
        __syncthreads();
        short8_t ah[4], bh[4];
        const int swa = (q ^ (fr & 3)) << 3;
#pragma unroll
        for (int i = 0; i < 4; ++i) {
            ah[i] = *(const short8_t*)&sA[(wm + i * 16 + fr) * 32 + swa];
            bh[i] = *(const short8_t*)&sB[(wn + i * 16 + fr) * 32 + swa];
        }
#pragma unroll
        for (int i = 0; i < 4; ++i)
#pragma unroll
            for (int j = 0; j < 4; ++j)
                acc[i][j] = __builtin_amdgcn_mfma_f32_16x16x32_bf16(ah[i], bh[j], acc[i][j], 0, 0, 0);
    }
    const int row_base = (lane >> 4) << 2;
#pragma unroll
    for (int i = 0; i < 4; ++i)
#pragma unroll
        for (int j = 0; j < 4; ++j) {
            const int row = m0 + wm + i * 16 + row_base;
            const int col = n0 + wn + j * 16 + fr;
#pragma unroll
            for (int r = 0; r < 4; ++r)
                C[(size_t)(row + r) * N + col] = acc[i][j][r];
        }
}

// -------------------- fp32 tiled GEMM (tier 2/3 dense block-0 path) --------------------
template<bool ADD, bool GELU>
__global__ __launch_bounds__(256) void gemm_nn(const float* __restrict__ A,
                                               const float* __restrict__ B,
                                               float* __restrict__ C,
                                               int M, int N, int K) {
    const int m0 = blockIdx.y * 64, n0 = blockIdx.x * 64;
    __shared__ float As[16][68];
    __shared__ float Bs[16][68];
    const int tid = threadIdx.x;
    const int am = tid >> 2, ak = (tid & 3) << 2;
    const int bk = tid >> 4, bn = (tid & 15) << 2;
    const int tn = tid & 15, tm = tid >> 4;
    float acc[4][4] = {};
    for (int k0 = 0; k0 < K; k0 += 16) {
        float4 a4 = *(const float4*)&A[(size_t)(m0 + am) * K + k0 + ak];
        float4 b4 = *(const float4*)&B[(size_t)(k0 + bk) * N + n0 + bn];
        __syncthreads();
        As[ak + 0][am] = a4.x;
        As[ak + 1][am] = a4.y;
        As[ak + 2][am] = a4.z;
        As[ak + 3][am] = a4.w;
        *(float4*)&Bs[bk][bn] = b4;
        __syncthreads();
#pragma unroll
        for (int kk = 0; kk < 16; ++kk) {
            float4 av = *(const float4*)&As[kk][tm << 2];
            float4 bv = *(const float4*)&Bs[kk][tn << 2];
            float a[4] = {av.x, av.y, av.z, av.w};
            float b[4] = {bv.x, bv.y, bv.z, bv.w};
#pragma unroll
            for (int i = 0; i < 4; ++i)
#pragma unroll
                for (int j = 0; j < 4; ++j)
                    acc[i][j] = fmaf(a[i], b[j], acc[i][j]);
        }
    }
#pragma unroll
    for (int i = 0; i < 4; ++i) {
        size_t row = (size_t)(m0 + (tm << 2) + i);
        float* cp = &C[row * (size_t)N + n0 + (tn << 2)];
        float rr[4] = {acc[i][0], acc[i][1], acc[i][2], acc[i][3]};
        if (GELU) {
#pragma unroll
            for (int j = 0; j < 4; ++j) rr[j] = gelu_f(rr[j]);
        }
        if (ADD) {
            float4 cc = *(const float4*)cp;
            rr[0] += cc.x; rr[1] += cc.y; rr[2] += cc.z; rr[3] += cc.w;
        }
        float4 rv = {rr[0], rr[1], rr[2], rr[3]};
        *(float4*)cp = rv;
    }
}

// -------------------- grid-stride fp32 GEMM over compacted rows (blocks 1-2) ----------
template<bool ADD, bool GELU, bool SCAT>
__global__ __launch_bounds__(256) void gemm_nn_gs(const float* __restrict__ A,
                                                  const float* __restrict__ B,
                                                  float* __restrict__ C,
                                                  int N, int K,
                                                  const int* __restrict__ idx,
                                                  const int* __restrict__ cnt) {
    const int c = *cnt;
    const int ntm = (c + 63) >> 6;
    const int ntn = N >> 6;
    const int total = ntm * ntn;
    __shared__ float As[16][68];
    __shared__ float Bs[16][68];
    const int tid = threadIdx.x;
    const int am = tid >> 2, ak = (tid & 3) << 2;
    const int bk = tid >> 4, bn = (tid & 15) << 2;
    const int tn = tid & 15, tm = tid >> 4;
    for (int tile = blockIdx.x; tile < total; tile += gridDim.x) {
        const int m0 = (tile % ntm) << 6, n0 = (tile / ntm) << 6;
        int ar = m0 + am;
        ar = ar < c ? ar : c - 1;
        float acc[4][4] = {};
        for (int k0 = 0; k0 < K; k0 += 16) {
            float4 a4 = *(const float4*)&A[(size_t)ar * K + k0 + ak];
            float4 b4 = *(const float4*)&B[(size_t)(k0 + bk) * N + n0 + bn];
            __syncthreads();
            As[ak + 0][am] = a4.x;
            As[ak + 1][am] = a4.y;
            As[ak + 2][am] = a4.z;
            As[ak + 3][am] = a4.w;
            *(float4*)&Bs[bk][bn] = b4;
            __syncthreads();
#pragma unroll
            for (int kk = 0; kk < 16; ++kk) {
                float4 av = *(const float4*)&As[kk][tm << 2];
                float4 bv = *(const float4*)&Bs[kk][tn << 2];
                float a[4] = {av.x, av.y, av.z, av.w};
                float b[4] = {bv.x, bv.y, bv.z, bv.w};
#pragma unroll
                for (int i = 0; i < 4; ++i)
#pragma unroll
                    for (int j = 0; j < 4; ++j)
                        acc[i][j] = fmaf(a[i], b[j], acc[i][j]);
            }
        }
#pragma unroll
        for (int i = 0; i < 4; ++i) {
            int p = m0 + (tm << 2) + i;
            if (p >= c) continue;
            int r = SCAT ? idx[p] : p;
            float* cp = &C[(size_t)r * N + n0 + (tn << 2)];
            float rr[4] = {acc[i][0], acc[i][1], acc[i][2], acc[i][3]};
            if (GELU) {
#pragma unroll
                for (int j = 0; j < 4; ++j) rr[j] = gelu_f(rr[j]);
            }
            if (ADD) {
                float4 cc = *(const float4*)cp;
                rr[0] += cc.x; rr[1] += cc.y; rr[2] += cc.z; rr[3] += cc.w;
            }
            float4 rv = {rr[0], rr[1], rr[2], rr[3]};
            *(float4*)cp = rv;
        }
        __syncthreads();
    }
}

// -------------------- grid-stride fp32 head GEMM over compacted rows (blocks 1-2) -----
__global__ __launch_bounds__(256) void gemm_nt_head_gs(const float* __restrict__ A,
                                                       const float* __restrict__ Bt,
                                                       float* __restrict__ C,
                                                       const int* __restrict__ idx,
                                                       const int* __restrict__ cnt) {
    const int c = *cnt;
    const int ntm = (c + 63) >> 6;
    const int ntn = NVOCAB >> 6;
    const int total = ntm * ntn;
    __shared__ float As[16][68];
    __shared__ float Bs[16][68];
    const int tid = threadIdx.x;
    const int am = tid >> 2, ak = (tid & 3) << 2;
    const int tn = tid & 15, tm = tid >> 4;
    for (int tile = blockIdx.x; tile < total; tile += gridDim.x) {
        const int m0 = (tile % ntm) << 6, n0 = (tile / ntm) << 6;
        int ap = m0 + am;
        int ar = idx[ap < c ? ap : c - 1];
        float acc[4][4] = {};
        for (int k0 = 0; k0 < DIM; k0 += 16) {
            float4 a4 = *(const float4*)&A[(size_t)ar * DIM + k0 + ak];
            float4 b4 = *(const float4*)&Bt[(size_t)(n0 + am) * DIM + k0 + ak];
            __syncthreads();
            As[ak + 0][am] = a4.x;
            As[ak + 1][am] = a4.y;
            As[ak + 2][am] = a4.z;
            As[ak + 3][am] = a4.w;
            Bs[ak + 0][am] = b4.x;
            Bs[ak + 1][am] = b4.y;
            Bs[ak + 2][am] = b4.z;
            Bs[ak + 3][am] = b4.w;
            __syncthreads();
#pragma unroll
            for (int kk = 0; kk < 16; ++kk) {
                float4 av = *(const float4*)&As[kk][tm << 2];
                float4 bv = *(const float4*)&Bs[kk][tn << 2];
                float a[4] = {av.x, av.y, av.z, av.w};
                float b[4] = {bv.x, bv.y, bv.z, bv.w};
#pragma unroll
                for (int i = 0; i < 4; ++i)
#pragma unroll
                    for (int j = 0; j < 4; ++j)
                        acc[i][j] = fmaf(a[i], b[j], acc[i][j]);
            }
        }
#pragma unroll
        for (int i = 0; i < 4; ++i) {
            int p = m0 + (tm << 2) + i;
            if (p >= c) continue;
            int r = idx[p];
            float4 rv = {acc[i][0], acc[i][1], acc[i][2], acc[i][3]};
            *(float4*)&C[(size_t)r * NVOCAB + n0 + (tn << 2)] = rv;
        }
        __syncthreads();
    }
}

// -------------------- confidence + exit (vectorized full-row read) --------------------
template<bool IDX>
__global__ __launch_bounds__(256) void conf_exit(const float* __restrict__ out,
                                                 int* __restrict__ flags,
                                                 const int* __restrict__ idx,
                                                 const int* __restrict__ cnt,
                                                 float thr) {
    int t;
    if (IDX) {
        if (blockIdx.x >= *cnt) return;
        t = idx[blockIdx.x];
    } else {
        t = blockIdx.x;
        if (flags[t] == 0) return;
    }
    const float4* row = (const float4*)(out + (size_t)t * NVOCAB);
    float m = -INFINITY, s = 0.0f;
    for (int i = threadIdx.x; i < NVOCAB / 4; i += 256) {
        float4 v = row[i];
        float m4 = fmaxf(fmaxf(v.x, v.y), fmaxf(v.z, v.w));
        float s4 = __expf(v.x - m4) + __expf(v.y - m4) + __expf(v.z - m4) + __expf(v.w - m4);
        if (m4 > m) {
            s = s * __expf(m - m4) + s4;
            m = m4;
        } else {
            s += s4 * __expf(m4 - m);
        }
    }
    __shared__ float ms[256], ss[256];
    ms[threadIdx.x] = m;
    ss[threadIdx.x] = s;
    __syncthreads();
    for (int st = 128; st; st >>= 1) {
        if (threadIdx.x < st) {
            float m1 = ms[threadIdx.x], s1 = ss[threadIdx.x];
            float m2 = ms[threadIdx.x + st], s2 = ss[threadIdx.x + st];
            float mm = fmaxf(m1, m2);
            ss[threadIdx.x] = s1 * __expf(m1 - mm) + s2 * __expf(m2 - mm);
            ms[threadIdx.x] = mm;
        }
        __syncthreads();
    }
    if (threadIdx.x == 0) {
        float conf = 1.0f / ss[0];
        if (conf > thr) flags[t] = 0;
    }
}

// -------------------- ordered compaction of active tokens (single block) --------------------
__global__ __launch_bounds__(256) void compact_kernel(const int* __restrict__ flags,
                                                      int* __restrict__ idx,
                                                      int* __restrict__ cnt) {
    __shared__ int wsum[4];
    __shared__ int base;
    if (threadIdx.x == 0) base = 0;
    int lane = threadIdx.x & 63, wv = threadIdx.x >> 6;
    for (int chunk = 0; chunk < TT; chunk += 256) {
        __syncthreads();
        int t = chunk + threadIdx.x;
        int f = flags[t];
        unsigned long long b = __ballot(f != 0);
        if (lane == 0) wsum[wv] = __popcll(b);
        __syncthreads();
        int off = base;
        for (int w = 0; w < wv; ++w) off += wsum[w];
        off += __popcll(b & ((1ull << lane) - 1));
        if (f) idx[off] = t;
        __syncthreads();
        if (threadIdx.x == 0) base += wsum[0] + wsum[1] + wsum[2] + wsum[3];
    }
    __syncthreads();
    if (threadIdx.x == 0) *cnt = base;
}

extern "C" void kernel_launch(void* const* d_in, const int* in_sizes, int n_in,
                              void* d_out, int out_size, void* d_ws, size_t ws_size,
                              hipStream_t stream) {
    const int* x = (const int*)d_in[0];
    const float* emb = (const float*)d_in[1];
    const float* head = (const float*)d_in[2];
    const float* Wv = (const float*)d_in[3];
    const float* Wo = (const float*)d_in[4];
    const float* W1 = (const float*)d_in[5];
    const float* W2 = (const float*)d_in[6];
    const float* ln1s = (const float*)d_in[7];
    const float* ln1b = (const float*)d_in[8];
    const float* ln2s = (const float*)d_in[9];
    const float* ln2b = (const float*)d_in[10];
    float* out = (float*)d_out;
    float* ws = (float*)d_ws;

    float* h  = ws;                      // TT*DIM fp32
    float* hn = ws + 2097152;            // TT*DIM
    float* tA = ws + 4194304;            // TT*DIM (scratch: WvFlat hi/lo during setup)
    float* tF = ws + 6291456;            // TT*FFN
    short* hnHi = (short*)hn;
    short* hnLo = hnHi + TT * DIM;
    short* tAHi = (short*)tA;
    short* tALo = tAHi + TT * DIM;
    short* tFHi = (short*)tF;
    short* tFLo = tFHi + TT * FFN;
    int* flags = (int*)(ws + 14680064);  // TT
    int* idxl  = flags + TT;             // TT
    int* cntp  = flags + 2 * TT;         // 1
    short* hHi    = (short*)(ws + 14700000);
    short* hLo    = (short*)(ws + 15748576);
    short* headHi = (short*)(ws + 16797152);
    short* headLo = (short*)(ws + 24989152);
    short* wT     = (short*)(ws + 33181152);  // 2 layers x 5242880 shorts
    const size_t LSTRIDE = 5242880;
    const size_t NEED_T2 = (size_t)33181152 * 4;
    const size_t NEED_T1 = (size_t)38424032 * 4;
    const int tier = ws_size >= NEED_T1 ? 1 : (ws_size >= NEED_T2 ? 2 : 3);

    gather_kernel<<<TT, 128, 0, stream>>>(x, emb, h, flags);

    const float THR[3] = {3.5e-05f, 4.0e-05f, 1.0f};
    const dim3 gDD(DIM / 64, TT / 64), gDF(FFN / 64, TT / 64), gHead(NVOCAB / 64, TT / 64);

    // ---------- block 0: dense ----------
    if (tier == 1) {
        // weight prep: transpose-splits; W_voT = WoT @ WvFlat (3-product MFMA)
        for (int l = 0; l < 2; ++l) {
            short* wb = wT + (size_t)l * LSTRIDE;
            cvt_hilo<<<(DIM * DIM / 4 + 255) / 256, 256, 0, stream>>>(Wv + (size_t)l * DIM * DIM, tAHi, tALo, DIM * DIM / 4);
            cvt_w_t<<<dim3(DIM / 32, DIM / 32), 256, 0, stream>>>(Wo + (size_t)l * DIM * DIM, wb + 524288, wb + 786432, DIM, DIM);
            gemm_l64<0><<<dim3(DIM / 64, DIM / 128), 256, 0, stream>>>(
                wb + 524288, wb + 786432, tAHi, tALo, nullptr, wb, wb + 262144, DIM, DIM);
            cvt_w_t<<<dim3(FFN / 32, DIM / 32), 256, 0, stream>>>(W1 + (size_t)l * DIM * FFN, wb + 1048576, wb + 2097152, DIM, FFN);
            cvt_w_t<<<dim3(DIM / 32, FFN / 32), 256, 0, stream>>>(W2 + (size_t)l * FFN * DIM, wb + 3145728, wb + 4194304, FFN, DIM);
        }
        for (int l = 0; l < 2; ++l) {
            short* wb = wT + (size_t)l * LSTRIDE;
            ln_hilo<<<TT / 4, 256, 0, stream>>>(h, ln1s + l * DIM, ln1b + l * DIM, hnHi, hnLo);
            gemm_l64b<2><<<dim3(TT / 64, DIM / 128), 256, 0, stream>>>(hnHi, hnLo, wb, h, nullptr, nullptr, DIM, DIM);
            ln_hilo<<<TT / 4, 256, 0, stream>>>(h, ln2s + l * DIM, ln2b + l * DIM, hnHi, hnLo);
            gemm_l2<1><<<dim3(TT / 128, FFN / 128), 256, 0, stream>>>(hnHi, hnLo, wb + 1048576, nullptr, tFHi, tFLo, FFN, DIM);
            if (l == 1) {
                gemm_l64b<4><<<dim3(TT / 64, DIM / 128), 256, 0, stream>>>(tFHi, tFLo, wb + 3145728, h, hHi, hLo, DIM, FFN);
            } else {
                gemm_l64b<2><<<dim3(TT / 64, DIM / 128), 256, 0, stream>>>(tFHi, tFLo, wb + 3145728, h, nullptr, nullptr, DIM, FFN);
            }
        }
        cvt_bf16<<<(NVOCAB * DIM / 4 + 255) / 256, 256, 0, stream>>>(head, headHi, NVOCAB * DIM / 4);
        gemm_head_bf16<<<dim3(TT / 128, NVOCAB / 128), 256, 0, stream>>>(hHi, headHi, out, NVOCAB, DIM);
        conf_exit<false><<<TT, 256, 0, stream>>>(out, flags, nullptr, nullptr, THR[0]);
    } else {
        for (int l = 0; l < 2; ++l) {
            ln_kernel<false><<<TT / 4, 256, 0, stream>>>(h, ln1s + l * DIM, ln1b + l * DIM, hn, nullptr, nullptr);
            gemm_nn<false, false><<<gDD, 256, 0, stream>>>(hn, Wv + (size_t)l * DIM * DIM, tA, TT, DIM, DIM);
            gemm_nn<true, false><<<gDD, 256, 0, stream>>>(tA, Wo + (size_t)l * DIM * DIM, h, TT, DIM, DIM);
            ln_kernel<false><<<TT / 4, 256, 0, stream>>>(h, ln2s + l * DIM, ln2b + l * DIM, hn, nullptr, nullptr);
            gemm_nn<false, true><<<gDF, 256, 0, stream>>>(hn, W1 + (size_t)l * DIM * FFN, tF, TT, FFN, DIM);
            gemm_nn<true, false><<<gDD, 256, 0, stream>>>(tF, W2 + (size_t)l * FFN * DIM, h, TT, DIM, FFN);
        }
        if (tier == 2) {
            cvt_hilo<<<(TT * DIM / 4 + 255) / 256, 256, 0, stream>>>(h, hHi, hLo, TT * DIM / 4);
            cvt_hilo<<<(NVOCAB * DIM / 4 + 255) / 256, 256, 0, stream>>>(head, headHi, headLo, NVOCAB * DIM / 4);
            gemm_l_mfma<3><<<dim3(TT / 128, NVOCAB / 128), 256, 0, stream>>>(hHi, hLo, headHi, headLo, out, nullptr, nullptr, NVOCAB, DIM);
        } else {
            compact_kernel<<<1, 256, 0, stream>>>(flags, idxl, cntp);
            gemm_nt_head_gs<<<512, 256, 0, stream>>>(h, head, out, idxl, cntp);
        }
        conf_exit<false><<<TT, 256, 0, stream>>>(out, flags, nullptr, nullptr, THR[0]);
    }
    compact_kernel<<<1, 256, 0, stream>>>(flags, idxl, cntp);

    // ---------- blocks 1,2: compacted active rows (grid-stride fp32 path; ~empty) ----------
    for (int b = 1; b < 3; ++b) {
        for (int li = 0; li < 2; ++li) {
            int l = b * 2 + li;
            ln_kernel<true><<<TT / 4, 256, 0, stream>>>(h, ln1s + l * DIM, ln1b + l * DIM, hn, idxl, cntp);
            gemm_nn_gs<false, false, false><<<256, 256, 0, stream>>>(hn, Wv + (size_t)l * DIM * DIM, tA, DIM, DIM, idxl, cntp);
            gemm_nn_gs<true, false, true><<<256, 256, 0, stream>>>(tA, Wo + (size_t)l * DIM * DIM, h, DIM, DIM, idxl, cntp);
            ln_kernel<true><<<TT / 4, 256, 0, stream>>>(h, ln2s + l * DIM, ln2b + l * DIM, hn, idxl, cntp);
            gemm_nn_gs<false, true, false><<<256, 256, 0, stream>>>(hn, W1 + (size_t)l * DIM * FFN, tF, FFN, DIM, idxl, cntp);
            gemm_nn_gs<true, false, true><<<256, 256, 0, stream>>>(tF, W2 + (size_t)l * FFN * DIM, h, DIM, FFN, idxl, cntp);
        }
        gemm_nt_head_gs<<<512, 256, 0, stream>>>(h, head, out, idxl, cntp);
        if (b == 1) {
            conf_exit<true><<<TT, 256, 0, stream>>>(out, flags, idxl, cntp, THR[1]);
            compact_kernel<<<1, 256, 0, stream>>>(flags, idxl, cntp);
        }
    }
}

// Round 13
// 686.668 us; speedup vs baseline: 1.5616x; 1.0807x over previous
//
#include <hip/hip_runtime.h>
#include <hip/hip_bf16.h>
#include <math.h>

#define TT 4096
#define DIM 512
#define FFN 2048
#define NVOCAB 32000
#define NGRP 500   // conf partial groups per token (250 n-tiles x 2 wave strips)

typedef __attribute__((ext_vector_type(8))) short short8_t;
typedef __attribute__((ext_vector_type(4))) float f32x4;

__device__ __forceinline__ float gelu_f(float x) {
    float x3 = x * x * x;
    float u = 0.7978845608028654f * (x + 0.044715f * x3);
    return 0.5f * x * (1.0f + tanhf(u));
}

__device__ __forceinline__ unsigned short f2bf_rn(float f) {
    unsigned u = __float_as_uint(f);
    u += 0x7FFFu + ((u >> 16) & 1u);
    return (unsigned short)(u >> 16);
}

// -------------------- embedding gather + flag init --------------------
__global__ __launch_bounds__(128) void gather_kernel(const int* __restrict__ x,
                                                     const float* __restrict__ emb,
                                                     float* __restrict__ h,
                                                     int* __restrict__ flags) {
    int t = blockIdx.x;
    int idx = x[t];
    const float4 v = *(const float4*)&emb[(size_t)idx * DIM + threadIdx.x * 4];
    *(float4*)&h[(size_t)t * DIM + threadIdx.x * 4] = v;
    if (threadIdx.x == 0) flags[t] = 1;
}

// -------------------- fp32 -> bf16 hi/lo split (flat) --------------------
__global__ __launch_bounds__(256) void cvt_hilo(const float* __restrict__ src,
                                                short* __restrict__ hi,
                                                short* __restrict__ lo, int n4) {
    int i = blockIdx.x * 256 + threadIdx.x;
    if (i >= n4) return;
    float4 v = *(const float4*)&src[(size_t)i * 4];
    float f[4] = {v.x, v.y, v.z, v.w};
    short4 hv, lv;
    short* hp = &hv.x;
    short* lp = &lv.x;
#pragma unroll
    for (int j = 0; j < 4; ++j) {
        unsigned short hb = f2bf_rn(f[j]);
        float hf = __uint_as_float((unsigned)hb << 16);
        unsigned short lb = f2bf_rn(f[j] - hf);
        hp[j] = (short)hb;
        lp[j] = (short)lb;
    }
    *(short4*)&hi[(size_t)i * 4] = hv;
    *(short4*)&lo[(size_t)i * 4] = lv;
}

// -------------------- fp32 -> bf16 (hi only, flat) --------------------
__global__ __launch_bounds__(256) void cvt_bf16(const float* __restrict__ src,
                                                short* __restrict__ hi, int n4) {
    int i = blockIdx.x * 256 + threadIdx.x;
    if (i >= n4) return;
    float4 v = *(const float4*)&src[(size_t)i * 4];
    float f[4] = {v.x, v.y, v.z, v.w};
    short4 hv;
    short* hp = &hv.x;
#pragma unroll
    for (int j = 0; j < 4; ++j) hp[j] = (short)f2bf_rn(f[j]);
    *(short4*)&hi[(size_t)i * 4] = hv;
}

// -------------------- fp32 W (K,N) -> bf16 hi/lo transposed (N,K) --------------------
__global__ __launch_bounds__(256) void cvt_w_t(const float* __restrict__ W,
                                               short* __restrict__ hiT,
                                               short* __restrict__ loT,
                                               int K, int N) {
    __shared__ short hs[32][36];
    __shared__ short ls[32][36];
    const int n0 = blockIdx.x * 32, k0 = blockIdx.y * 32;
    const int r = threadIdx.x >> 3, c4 = (threadIdx.x & 7) << 2;
    float4 v = *(const float4*)&W[(size_t)(k0 + r) * N + n0 + c4];
    float f[4] = {v.x, v.y, v.z, v.w};
#pragma unroll
    for (int j = 0; j < 4; ++j) {
        unsigned short hb = f2bf_rn(f[j]);
        float hf = __uint_as_float((unsigned)hb << 16);
        unsigned short lb = f2bf_rn(f[j] - hf);
        hs[r][c4 + j] = (short)hb;
        ls[r][c4 + j] = (short)lb;
    }
    __syncthreads();
    const int nr = threadIdx.x >> 3, kc4 = (threadIdx.x & 7) << 2;
    short4 hv, lv;
    short* hp = &hv.x;
    short* lp = &lv.x;
#pragma unroll
    for (int j = 0; j < 4; ++j) {
        hp[j] = hs[kc4 + j][nr];
        lp[j] = ls[kc4 + j][nr];
    }
    *(short4*)&hiT[(size_t)(n0 + nr) * K + k0 + kc4] = hv;
    *(short4*)&loT[(size_t)(n0 + nr) * K + k0 + kc4] = lv;
}

// -------------------- fp32 W (K,N) -> bf16 hi transposed only --------------------
__global__ __launch_bounds__(256) void cvt_w_t_hi(const float* __restrict__ W,
                                                  short* __restrict__ hiT,
                                                  int K, int N) {
    __shared__ short hs[32][36];
    const int n0 = blockIdx.x * 32, k0 = blockIdx.y * 32;
    const int r = threadIdx.x >> 3, c4 = (threadIdx.x & 7) << 2;
    float4 v = *(const float4*)&W[(size_t)(k0 + r) * N + n0 + c4];
    float f[4] = {v.x, v.y, v.z, v.w};
#pragma unroll
    for (int j = 0; j < 4; ++j) hs[r][c4 + j] = (short)f2bf_rn(f[j]);
    __syncthreads();
    const int nr = threadIdx.x >> 3, kc4 = (threadIdx.x & 7) << 2;
    short4 hv;
    short* hp = &hv.x;
#pragma unroll
    for (int j = 0; j < 4; ++j) hp[j] = hs[kc4 + j][nr];
    *(short4*)&hiT[(size_t)(n0 + nr) * K + k0 + kc4] = hv;
}

// -------------------- LayerNorm (fp32 out; optional index gather) --------------------
template<bool IDX>
__global__ __launch_bounds__(256) void ln_kernel(const float* __restrict__ x,
                                                 const float* __restrict__ gam,
                                                 const float* __restrict__ bet,
                                                 float* __restrict__ out,
                                                 const int* __restrict__ idx,
                                                 const int* __restrict__ cnt) {
    int wv = threadIdx.x >> 6, lane = threadIdx.x & 63;
    int p = (blockIdx.x << 2) | wv;
    if (IDX && p >= *cnt) return;
    int t = IDX ? idx[p] : p;
    const float* row = x + (size_t)t * DIM;
    int base = lane * 8;
    float4 v0 = *(const float4*)&row[base];
    float4 v1 = *(const float4*)&row[base + 4];
    float s = v0.x + v0.y + v0.z + v0.w + v1.x + v1.y + v1.z + v1.w;
#pragma unroll
    for (int o = 32; o; o >>= 1) s += __shfl_xor(s, o, 64);
    float mean = s * (1.0f / (float)DIM);
    float d0 = v0.x - mean, d1 = v0.y - mean, d2 = v0.z - mean, d3 = v0.w - mean;
    float d4 = v1.x - mean, d5 = v1.y - mean, d6 = v1.z - mean, d7 = v1.w - mean;
    float q = d0*d0 + d1*d1 + d2*d2 + d3*d3 + d4*d4 + d5*d5 + d6*d6 + d7*d7;
#pragma unroll
    for (int o = 32; o; o >>= 1) q += __shfl_xor(q, o, 64);
    float var = q * (1.0f / (float)DIM);
    float rs = 1.0f / sqrtf(var + 1e-5f);
    float4 g0 = *(const float4*)&gam[base];
    float4 g1 = *(const float4*)&gam[base + 4];
    float4 b0 = *(const float4*)&bet[base];
    float4 b1 = *(const float4*)&bet[base + 4];
    float4 o0, o1;
    o0.x = d0 * rs * g0.x + b0.x;  o0.y = d1 * rs * g0.y + b0.y;
    o0.z = d2 * rs * g0.z + b0.z;  o0.w = d3 * rs * g0.w + b0.w;
    o1.x = d4 * rs * g1.x + b1.x;  o1.y = d5 * rs * g1.y + b1.y;
    o1.z = d6 * rs * g1.z + b1.z;  o1.w = d7 * rs * g1.w + b1.w;
    float* orow = out + (size_t)p * DIM;
    *(float4*)&orow[base] = o0;
    *(float4*)&orow[base + 4] = o1;
}

// -------------------- LayerNorm -> bf16 hi/lo (dense, block 0) --------------------
__global__ __launch_bounds__(256) void ln_hilo(const float* __restrict__ x,
                                               const float* __restrict__ gam,
                                               const float* __restrict__ bet,
                                               short* __restrict__ ohi,
                                               short* __restrict__ olo) {
    int wv = threadIdx.x >> 6, lane = threadIdx.x & 63;
    int t = (blockIdx.x << 2) | wv;
    const float* row = x + (size_t)t * DIM;
    int base = lane * 8;
    float4 v0 = *(const float4*)&row[base];
    float4 v1 = *(const float4*)&row[base + 4];
    float s = v0.x + v0.y + v0.z + v0.w + v1.x + v1.y + v1.z + v1.w;
#pragma unroll
    for (int o = 32; o; o >>= 1) s += __shfl_xor(s, o, 64);
    float mean = s * (1.0f / (float)DIM);
    float d[8] = {v0.x - mean, v0.y - mean, v0.z - mean, v0.w - mean,
                  v1.x - mean, v1.y - mean, v1.z - mean, v1.w - mean};
    float q = 0.0f;
#pragma unroll
    for (int j = 0; j < 8; ++j) q += d[j] * d[j];
#pragma unroll
    for (int o = 32; o; o >>= 1) q += __shfl_xor(q, o, 64);
    float var = q * (1.0f / (float)DIM);
    float rs = 1.0f / sqrtf(var + 1e-5f);
    float g[8], bb[8];
    *(float4*)&g[0] = *(const float4*)&gam[base];
    *(float4*)&g[4] = *(const float4*)&gam[base + 4];
    *(float4*)&bb[0] = *(const float4*)&bet[base];
    *(float4*)&bb[4] = *(const float4*)&bet[base + 4];
    short8_t hv, lv;
#pragma unroll
    for (int j = 0; j < 8; ++j) {
        float val = d[j] * rs * g[j] + bb[j];
        unsigned short hb = f2bf_rn(val);
        float hf = __uint_as_float((unsigned)hb << 16);
        hv[j] = (short)hb;
        lv[j] = (short)f2bf_rn(val - hf);
    }
    *(short8_t*)&ohi[(size_t)t * DIM + base] = hv;
    *(short8_t*)&olo[(size_t)t * DIM + base] = lv;
}

// ==================== EPILOGUE helper ====================
__device__ __forceinline__ void epi_store(int EPI, float val, size_t off,
                                          float* Cf, short* oHi, short* oLo) {
    if (EPI == 3) {
        Cf[off] = val;
    } else if (EPI == 2) {
        Cf[off] += val;
    } else if (EPI == 4) {
        float nv = Cf[off] + val;
        Cf[off] = nv;
        unsigned short hb = f2bf_rn(nv);
        float hf = __uint_as_float((unsigned)hb << 16);
        oHi[off] = (short)hb;
        oLo[off] = (short)f2bf_rn(nv - hf);
    } else {
        if (EPI == 1) val = gelu_f(val);
        unsigned short hb = f2bf_rn(val);
        float hf = __uint_as_float((unsigned)hb << 16);
        oHi[off] = (short)hb;
        oLo[off] = (short)f2bf_rn(val - hf);
    }
}

// -------------------- 3-product split-bf16 MFMA GEMM (128x128) --------------------
template<int EPI>
__global__ __launch_bounds__(256) void gemm_l_mfma(const short* __restrict__ Ah,
                                                   const short* __restrict__ Al,
                                                   const short* __restrict__ Bh,
                                                   const short* __restrict__ Bl,
                                                   float* __restrict__ Cf,
                                                   short* __restrict__ oHi,
                                                   short* __restrict__ oLo,
                                                   int N, int K) {
    __shared__ __align__(16) short sm[16384];
    short* sAh = sm;
    short* sAl = sm + 4096;
    short* sBh = sm + 8192;
    short* sBl = sm + 12288;
    const int tid = threadIdx.x;
    const int wv = tid >> 6, lane = tid & 63;
    const int m0 = blockIdx.x * 128;
    const int n0 = blockIdx.y * 128;
    const int wm = (wv & 1) * 64, wn = (wv >> 1) * 64;
    const int r16 = lane >> 2;
    const int gsw = ((lane & 3) ^ (r16 & 3)) << 3;
    const int fr = lane & 15;
    const int q = lane >> 4;

    f32x4 acc[4][4];
#pragma unroll
    for (int i = 0; i < 4; ++i)
#pragma unroll
        for (int j = 0; j < 4; ++j)
            acc[i][j] = (f32x4){0.0f, 0.0f, 0.0f, 0.0f};

    const int NKT = K >> 5;
    for (int kt = 0; kt < NKT; ++kt) {
        const int k0 = kt << 5;
        __syncthreads();
#pragma unroll
        for (int j = 0; j < 2; ++j) {
            const int rr = (wv << 5) + (j << 4);
            const int gr = rr + r16;
            const short* ga_h = Ah + (size_t)(m0 + gr) * K + k0 + gsw;
            const short* ga_l = Al + (size_t)(m0 + gr) * K + k0 + gsw;
            const short* gb_h = Bh + (size_t)(n0 + gr) * K + k0 + gsw;
            const short* gb_l = Bl + (size_t)(n0 + gr) * K + k0 + gsw;
            __builtin_amdgcn_global_load_lds((const __attribute__((address_space(1))) void*)ga_h,
                                             (__attribute__((address_space(3))) void*)(sAh + rr * 32), 16, 0, 0);
            __builtin_amdgcn_global_load_lds((const __attribute__((address_space(1))) void*)ga_l,
                                             (__attribute__((address_space(3))) void*)(sAl + rr * 32), 16, 0, 0);
            __builtin_amdgcn_global_load_lds((const __attribute__((address_space(1))) void*)gb_h,
                                             (__attribute__((address_space(3))) void*)(sBh + rr * 32), 16, 0, 0);
            __builtin_amdgcn_global_load_lds((const __attribute__((address_space(1))) void*)gb_l,
                                             (__attribute__((address_space(3))) void*)(sBl + rr * 32), 16, 0, 0);
        }
        __syncthreads();
        short8_t ah[4], al[4], bh[4], bl[4];
#pragma unroll
        for (int i = 0; i < 4; ++i) {
            const int ra = wm + i * 16 + fr;
            const int rb = wn + i * 16 + fr;
            const int swa = (q ^ (fr & 3)) << 3;
            ah[i] = *(const short8_t*)&sAh[ra * 32 + swa];
            al[i] = *(const short8_t*)&sAl[ra * 32 + swa];
            bh[i] = *(const short8_t*)&sBh[rb * 32 + swa];
            bl[i] = *(const short8_t*)&sBl[rb * 32 + swa];
        }
#pragma unroll
        for (int i = 0; i < 4; ++i)
#pragma unroll
            for (int j = 0; j < 4; ++j) {
                acc[i][j] = __builtin_amdgcn_mfma_f32_16x16x32_bf16(ah[i], bh[j], acc[i][j], 0, 0, 0);
                acc[i][j] = __builtin_amdgcn_mfma_f32_16x16x32_bf16(ah[i], bl[j], acc[i][j], 0, 0, 0);
                acc[i][j] = __builtin_amdgcn_mfma_f32_16x16x32_bf16(al[i], bh[j], acc[i][j], 0, 0, 0);
            }
    }
    const int row_base = (lane >> 4) << 2;
#pragma unroll
    for (int i = 0; i < 4; ++i)
#pragma unroll
        for (int j = 0; j < 4; ++j) {
            const int row = m0 + wm + i * 16 + row_base;
            const int col = n0 + wn + j * 16 + fr;
#pragma unroll
            for (int r = 0; r < 4; ++r)
                epi_store(EPI, acc[i][j][r], (size_t)(row + r) * N + col, Cf, oHi, oLo);
        }
}

// -------------------- 2-product GEMM (128x128): A hi/lo, B hi only --------------------
template<int EPI>
__global__ __launch_bounds__(256) void gemm_l2(const short* __restrict__ Ah,
                                               const short* __restrict__ Al,
                                               const short* __restrict__ Bh,
                                               float* __restrict__ Cf,
                                               short* __restrict__ oHi,
                                               short* __restrict__ oLo,
                                               int N, int K) {
    __shared__ __align__(16) short sm[12288];
    short* sAh = sm;
    short* sAl = sm + 4096;
    short* sBh = sm + 8192;
    const int tid = threadIdx.x;
    const int wv = tid >> 6, lane = tid & 63;
    const int m0 = blockIdx.x * 128;
    const int n0 = blockIdx.y * 128;
    const int wm = (wv & 1) * 64, wn = (wv >> 1) * 64;
    const int r16 = lane >> 2;
    const int gsw = ((lane & 3) ^ (r16 & 3)) << 3;
    const int fr = lane & 15;
    const int q = lane >> 4;

    f32x4 acc[4][4];
#pragma unroll
    for (int i = 0; i < 4; ++i)
#pragma unroll
        for (int j = 0; j < 4; ++j)
            acc[i][j] = (f32x4){0.0f, 0.0f, 0.0f, 0.0f};

    const int NKT = K >> 5;
    for (int kt = 0; kt < NKT; ++kt) {
        const int k0 = kt << 5;
        __syncthreads();
#pragma unroll
        for (int j = 0; j < 2; ++j) {
            const int rr = (wv << 5) + (j << 4);
            const int gr = rr + r16;
            const short* ga_h = Ah + (size_t)(m0 + gr) * K + k0 + gsw;
            const short* ga_l = Al + (size_t)(m0 + gr) * K + k0 + gsw;
            const short* gb_h = Bh + (size_t)(n0 + gr) * K + k0 + gsw;
            __builtin_amdgcn_global_load_lds((const __attribute__((address_space(1))) void*)ga_h,
                                             (__attribute__((address_space(3))) void*)(sAh + rr * 32), 16, 0, 0);
            __builtin_amdgcn_global_load_lds((const __attribute__((address_space(1))) void*)ga_l,
                                             (__attribute__((address_space(3))) void*)(sAl + rr * 32), 16, 0, 0);
            __builtin_amdgcn_global_load_lds((const __attribute__((address_space(1))) void*)gb_h,
                                             (__attribute__((address_space(3))) void*)(sBh + rr * 32), 16, 0, 0);
        }
        __syncthreads();
        short8_t ah[4], al[4], bh[4];
#pragma unroll
        for (int i = 0; i < 4; ++i) {
            const int ra = wm + i * 16 + fr;
            const int rb = wn + i * 16 + fr;
            const int swa = (q ^ (fr & 3)) << 3;
            ah[i] = *(const short8_t*)&sAh[ra * 32 + swa];
            al[i] = *(const short8_t*)&sAl[ra * 32 + swa];
            bh[i] = *(const short8_t*)&sBh[rb * 32 + swa];
        }
#pragma unroll
        for (int i = 0; i < 4; ++i)
#pragma unroll
            for (int j = 0; j < 4; ++j) {
                acc[i][j] = __builtin_amdgcn_mfma_f32_16x16x32_bf16(ah[i], bh[j], acc[i][j], 0, 0, 0);
                acc[i][j] = __builtin_amdgcn_mfma_f32_16x16x32_bf16(al[i], bh[j], acc[i][j], 0, 0, 0);
            }
    }
    const int row_base = (lane >> 4) << 2;
#pragma unroll
    for (int i = 0; i < 4; ++i)
#pragma unroll
        for (int j = 0; j < 4; ++j) {
            const int row = m0 + wm + i * 16 + row_base;
            const int col = n0 + wn + j * 16 + fr;
#pragma unroll
            for (int r = 0; r < 4; ++r)
                epi_store(EPI, acc[i][j][r], (size_t)(row + r) * N + col, Cf, oHi, oLo);
        }
}

// -------------------- 2-product GEMM (64x128): A hi/lo, B hi only --------------------
template<int EPI>
__global__ __launch_bounds__(256) void gemm_l64b(const short* __restrict__ Ah,
                                                 const short* __restrict__ Al,
                                                 const short* __restrict__ Bh,
                                                 float* __restrict__ Cf,
                                                 short* __restrict__ oHi,
                                                 short* __restrict__ oLo,
                                                 int N, int K) {
    __shared__ __align__(16) short sm[8192];
    short* sAh = sm;
    short* sAl = sm + 2048;
    short* sBh = sm + 4096;
    const int tid = threadIdx.x;
    const int wv = tid >> 6, lane = tid & 63;
    const int m0 = blockIdx.x * 64;
    const int n0 = blockIdx.y * 128;
    const int wm = (wv & 1) * 32, wn = (wv >> 1) * 64;
    const int r16 = lane >> 2;
    const int gsw = ((lane & 3) ^ (r16 & 3)) << 3;
    const int fr = lane & 15;
    const int q = lane >> 4;

    f32x4 acc[2][4];
#pragma unroll
    for (int i = 0; i < 2; ++i)
#pragma unroll
        for (int j = 0; j < 4; ++j)
            acc[i][j] = (f32x4){0.0f, 0.0f, 0.0f, 0.0f};

    const int NKT = K >> 5;
    for (int kt = 0; kt < NKT; ++kt) {
        const int k0 = kt << 5;
        __syncthreads();
        {
            const int rr = wv << 4;
            const int gr = rr + r16;
            const short* ga_h = Ah + (size_t)(m0 + gr) * K + k0 + gsw;
            const short* ga_l = Al + (size_t)(m0 + gr) * K + k0 + gsw;
            __builtin_amdgcn_global_load_lds((const __attribute__((address_space(1))) void*)ga_h,
                                             (__attribute__((address_space(3))) void*)(sAh + rr * 32), 16, 0, 0);
            __builtin_amdgcn_global_load_lds((const __attribute__((address_space(1))) void*)ga_l,
                                             (__attribute__((address_space(3))) void*)(sAl + rr * 32), 16, 0, 0);
        }
#pragma unroll
        for (int j = 0; j < 2; ++j) {
            const int rr = (wv << 5) + (j << 4);
            const int gr = rr + r16;
            const short* gb_h = Bh + (size_t)(n0 + gr) * K + k0 + gsw;
            __builtin_amdgcn_global_load_lds((const __attribute__((address_space(1))) void*)gb_h,
                                             (__attribute__((address_space(3))) void*)(sBh + rr * 32), 16, 0, 0);
        }
        __syncthreads();
        short8_t ah[2], al[2], bh[4];
        const int swa = (q ^ (fr & 3)) << 3;
#pragma unroll
        for (int i = 0; i < 2; ++i) {
            const int ra = wm + i * 16 + fr;
            ah[i] = *(const short8_t*)&sAh[ra * 32 + swa];
            al[i] = *(const short8_t*)&sAl[ra * 32 + swa];
        }
#pragma unroll
        for (int j = 0; j < 4; ++j) {
            const int rb = wn + j * 16 + fr;
            bh[j] = *(const short8_t*)&sBh[rb * 32 + swa];
        }
#pragma unroll
        for (int i = 0; i < 2; ++i)
#pragma unroll
            for (int j = 0; j < 4; ++j) {
                acc[i][j] = __builtin_amdgcn_mfma_f32_16x16x32_bf16(ah[i], bh[j], acc[i][j], 0, 0, 0);
                acc[i][j] = __builtin_amdgcn_mfma_f32_16x16x32_bf16(al[i], bh[j], acc[i][j], 0, 0, 0);
            }
    }
    const int row_base = (lane >> 4) << 2;
#pragma unroll
    for (int i = 0; i < 2; ++i)
#pragma unroll
        for (int j = 0; j < 4; ++j) {
            const int row = m0 + wm + i * 16 + row_base;
            const int col = n0 + wn + j * 16 + fr;
#pragma unroll
            for (int r = 0; r < 4; ++r)
                epi_store(EPI, acc[i][j][r], (size_t)(row + r) * N + col, Cf, oHi, oLo);
        }
}

// -------------------- 3-product GEMM (64x128) — W_vo prep only --------------------
template<int EPI>
__global__ __launch_bounds__(256) void gemm_l64(const short* __restrict__ Ah,
                                                const short* __restrict__ Al,
                                                const short* __restrict__ Bh,
                                                const short* __restrict__ Bl,
                                                float* __restrict__ Cf,
                                                short* __restrict__ oHi,
                                                short* __restrict__ oLo,
                                                int N, int K) {
    __shared__ __align__(16) short sm[12288];
    short* sAh = sm;
    short* sAl = sm + 2048;
    short* sBh = sm + 4096;
    short* sBl = sm + 8192;
    const int tid = threadIdx.x;
    const int wv = tid >> 6, lane = tid & 63;
    const int m0 = blockIdx.x * 64;
    const int n0 = blockIdx.y * 128;
    const int wm = (wv & 1) * 32, wn = (wv >> 1) * 64;
    const int r16 = lane >> 2;
    const int gsw = ((lane & 3) ^ (r16 & 3)) << 3;
    const int fr = lane & 15;
    const int q = lane >> 4;

    f32x4 acc[2][4];
#pragma unroll
    for (int i = 0; i < 2; ++i)
#pragma unroll
        for (int j = 0; j < 4; ++j)
            acc[i][j] = (f32x4){0.0f, 0.0f, 0.0f, 0.0f};

    const int NKT = K >> 5;
    for (int kt = 0; kt < NKT; ++kt) {
        const int k0 = kt << 5;
        __syncthreads();
        {
            const int rr = wv << 4;
            const int gr = rr + r16;
            const short* ga_h = Ah + (size_t)(m0 + gr) * K + k0 + gsw;
            const short* ga_l = Al + (size_t)(m0 + gr) * K + k0 + gsw;
            __builtin_amdgcn_global_load_lds((const __attribute__((address_space(1))) void*)ga_h,
                                             (__attribute__((address_space(3))) void*)(sAh + rr * 32), 16, 0, 0);
            __builtin_amdgcn_global_load_lds((const __attribute__((address_space(1))) void*)ga_l,
                                             (__attribute__((address_space(3))) void*)(sAl + rr * 32), 16, 0, 0);
        }
#pragma unroll
        for (int j = 0; j < 2; ++j) {
            const int rr = (wv << 5) + (j << 4);
            const int gr = rr + r16;
            const short* gb_h = Bh + (size_t)(n0 + gr) * K + k0 + gsw;
            const short* gb_l = Bl + (size_t)(n0 + gr) * K + k0 + gsw;
            __builtin_amdgcn_global_load_lds((const __attribute__((address_space(1))) void*)gb_h,
                                             (__attribute__((address_space(3))) void*)(sBh + rr * 32), 16, 0, 0);
            __builtin_amdgcn_global_load_lds((const __attribute__((address_space(1))) void*)gb_l,
                                             (__attribute__((address_space(3))) void*)(sBl + rr * 32), 16, 0, 0);
        }
        __syncthreads();
        short8_t ah[2], al[2], bh[4], bl[4];
        const int swa = (q ^ (fr & 3)) << 3;
#pragma unroll
        for (int i = 0; i < 2; ++i) {
            const int ra = wm + i * 16 + fr;
            ah[i] = *(const short8_t*)&sAh[ra * 32 + swa];
            al[i] = *(const short8_t*)&sAl[ra * 32 + swa];
        }
#pragma unroll
        for (int j = 0; j < 4; ++j) {
            const int rb = wn + j * 16 + fr;
            bh[j] = *(const short8_t*)&sBh[rb * 32 + swa];
            bl[j] = *(const short8_t*)&sBl[rb * 32 + swa];
        }
#pragma unroll
        for (int i = 0; i < 2; ++i)
#pragma unroll
            for (int j = 0; j < 4; ++j) {
                acc[i][j] = __builtin_amdgcn_mfma_f32_16x16x32_bf16(ah[i], bh[j], acc[i][j], 0, 0, 0);
                acc[i][j] = __builtin_amdgcn_mfma_f32_16x16x32_bf16(ah[i], bl[j], acc[i][j], 0, 0, 0);
                acc[i][j] = __builtin_amdgcn_mfma_f32_16x16x32_bf16(al[i], bh[j], acc[i][j], 0, 0, 0);
            }
    }
    const int row_base = (lane >> 4) << 2;
#pragma unroll
    for (int i = 0; i < 2; ++i)
#pragma unroll
        for (int j = 0; j < 4; ++j) {
            const int row = m0 + wm + i * 16 + row_base;
            const int col = n0 + wn + j * 16 + fr;
#pragma unroll
            for (int r = 0; r < 4; ++r)
                epi_store(EPI, acc[i][j][r], (size_t)(row + r) * N + col, Cf, oHi, oLo);
        }
}

// -------------------- PLAIN bf16 head GEMM + lightweight conf partials --------------------
// v3 conf fusion: per-row 16-lane shfl reduce straight from acc, fr==0 lanes write
// (max,sumexp) per 64-col wave strip to pp. No LDS reuse, no extra barriers.
__global__ __launch_bounds__(256) void gemm_head_bf16(const short* __restrict__ Ah,
                                                      const short* __restrict__ Bh,
                                                      float* __restrict__ C,
                                                      float2* __restrict__ pp,
                                                      int N, int K) {
    __shared__ __align__(16) short sm[8192];
    short* sA = sm;
    short* sB = sm + 4096;
    const int tid = threadIdx.x;
    const int wv = tid >> 6, lane = tid & 63;
    const int m0 = blockIdx.x * 128;
    const int n0 = blockIdx.y * 128;
    const int nt = blockIdx.y;
    const int wm = (wv & 1) * 64, wn = (wv >> 1) * 64;
    const int r16 = lane >> 2;
    const int gsw = ((lane & 3) ^ (r16 & 3)) << 3;
    const int fr = lane & 15;
    const int q = lane >> 4;

    f32x4 acc[4][4];
#pragma unroll
    for (int i = 0; i < 4; ++i)
#pragma unroll
        for (int j = 0; j < 4; ++j)
            acc[i][j] = (f32x4){0.0f, 0.0f, 0.0f, 0.0f};

    const int NKT = K >> 5;
    for (int kt = 0; kt < NKT; ++kt) {
        const int k0 = kt << 5;
        __syncthreads();
#pragma unroll
        for (int j = 0; j < 2; ++j) {
            const int rr = (wv << 5) + (j << 4);
            const int gr = rr + r16;
            const short* ga = Ah + (size_t)(m0 + gr) * K + k0 + gsw;
            const short* gb = Bh + (size_t)(n0 + gr) * K + k0 + gsw;
            __builtin_amdgcn_global_load_lds((const __attribute__((address_space(1))) void*)ga,
                                             (__attribute__((address_space(3))) void*)(sA + rr * 32), 16, 0, 0);
            __builtin_amdgcn_global_load_lds((const __attribute__((address_space(1))) void*)gb,
                                             (__attribute__((address_space(3))) void*)(sB + rr * 32), 16, 0, 0);
        }
        __syncthreads();
        short8_t ah[4], bh[4];
        const int swa = (q ^ (fr & 3)) << 3;
#pragma unroll
        for (int i = 0; i < 4; ++i) {
            ah[i] = *(const short8_t*)&sA[(wm + i * 16 + fr) * 32 + swa];
            bh[i] = *(const short8_t*)&sB[(wn + i * 16 + fr) * 32 + swa];
        }
#pragma unroll
        for (int i = 0; i < 4; ++i)
#pragma unroll
            for (int j = 0; j < 4; ++j)
                acc[i][j] = __builtin_amdgcn_mfma_f32_16x16x32_bf16(ah[i], bh[j], acc[i][j], 0, 0, 0);
    }
    const int hi = lane >> 4;
    const int row_base = hi << 2;
    // conf partials (no barrier, no LDS): per (i,r) row, reduce over 16 lanes x 4 j
#pragma unroll
    for (int i = 0; i < 4; ++i)
#pragma unroll
        for (int r = 0; r < 4; ++r) {
            float v0 = acc[i][0][r], v1 = acc[i][1][r];
            float v2 = acc[i][2][r], v3 = acc[i][3][r];
            float mg = fmaxf(fmaxf(v0, v1), fmaxf(v2, v3));
#pragma unroll
            for (int o = 1; o < 16; o <<= 1) mg = fmaxf(mg, __shfl_xor(mg, o, 64));
            float sg = __expf(v0 - mg) + __expf(v1 - mg) + __expf(v2 - mg) + __expf(v3 - mg);
#pragma unroll
            for (int o = 1; o < 16; o <<= 1) sg += __shfl_xor(sg, o, 64);
            if (fr == 0)
                pp[(size_t)(m0 + wm + i * 16 + hi * 4 + r) * NGRP + nt * 2 + (wn >> 6)] =
                    make_float2(mg, sg);
        }
    // C stores last: fire and retire
#pragma unroll
    for (int i = 0; i < 4; ++i)
#pragma unroll
        for (int j = 0; j < 4; ++j) {
            const int row = m0 + wm + i * 16 + row_base;
            const int col = n0 + wn + j * 16 + fr;
#pragma unroll
            for (int r = 0; r < 4; ++r)
                C[(size_t)(row + r) * N + col] = acc[i][j][r];
        }
}

// -------------------- conf reduce over head partials (one wave per token) ---------
__global__ __launch_bounds__(256) void conf_reduce(const float2* __restrict__ pp,
                                                   int* __restrict__ flags, float thr) {
    int wv = threadIdx.x >> 6, lane = threadIdx.x & 63;
    int t = blockIdx.x * 4 + wv;
    float m = -INFINITY, s = 0.0f;
    for (int k = lane; k < NGRP; k += 64) {
        float2 v = pp[(size_t)t * NGRP + k];
        float mm = fmaxf(m, v.x);
        s = s * __expf(m - mm) + v.y * __expf(v.x - mm);
        m = mm;
    }
#pragma unroll
    for (int o = 1; o < 64; o <<= 1) {
        float mo = __shfl_xor(m, o, 64);
        float so = __shfl_xor(s, o, 64);
        float mm = fmaxf(m, mo);
        s = s * __expf(m - mm) + so * __expf(mo - mm);
        m = mm;
    }
    if (lane == 0) {
        float conf = 1.0f / s;
        if (conf > thr) flags[t] = 0;
    }
}

// -------------------- fp32 tiled GEMM (tier 2/3 dense block-0 path) --------------------
template<bool ADD, bool GELU>
__global__ __launch_bounds__(256) void gemm_nn(const float* __restrict__ A,
                                               const float* __restrict__ B,
                                               float* __restrict__ C,
                                               int M, int N, int K) {
    const int m0 = blockIdx.y * 64, n0 = blockIdx.x * 64;
    __shared__ float As[16][68];
    __shared__ float Bs[16][68];
    const int tid = threadIdx.x;
    const int am = tid >> 2, ak = (tid & 3) << 2;
    const int bk = tid >> 4, bn = (tid & 15) << 2;
    const int tn = tid & 15, tm = tid >> 4;
    float acc[4][4] = {};
    for (int k0 = 0; k0 < K; k0 += 16) {
        float4 a4 = *(const float4*)&A[(size_t)(m0 + am) * K + k0 + ak];
        float4 b4 = *(const float4*)&B[(size_t)(k0 + bk) * N + n0 + bn];
        __syncthreads();
        As[ak + 0][am] = a4.x;
        As[ak + 1][am] = a4.y;
        As[ak + 2][am] = a4.z;
        As[ak + 3][am] = a4.w;
        *(float4*)&Bs[bk][bn] = b4;
        __syncthreads();
#pragma unroll
        for (int kk = 0; kk < 16; ++kk) {
            float4 av = *(const float4*)&As[kk][tm << 2];
            float4 bv = *(const float4*)&Bs[kk][tn << 2];
            float a[4] = {av.x, av.y, av.z, av.w};
            float b[4] = {bv.x, bv.y, bv.z, bv.w};
#pragma unroll
            for (int i = 0; i < 4; ++i)
#pragma unroll
                for (int j = 0; j < 4; ++j)
                    acc[i][j] = fmaf(a[i], b[j], acc[i][j]);
        }
    }
#pragma unroll
    for (int i = 0; i < 4; ++i) {
        size_t row = (size_t)(m0 + (tm << 2) + i);
        float* cp = &C[row * (size_t)N + n0 + (tn << 2)];
        float rr[4] = {acc[i][0], acc[i][1], acc[i][2], acc[i][3]};
        if (GELU) {
#pragma unroll
            for (int j = 0; j < 4; ++j) rr[j] = gelu_f(rr[j]);
        }
        if (ADD) {
            float4 cc = *(const float4*)cp;
            rr[0] += cc.x; rr[1] += cc.y; rr[2] += cc.z; rr[3] += cc.w;
        }
        float4 rv = {rr[0], rr[1], rr[2], rr[3]};
        *(float4*)cp = rv;
    }
}

// -------------------- grid-stride fp32 GEMM over compacted rows (blocks 1-2) ----------
template<bool ADD, bool GELU, bool SCAT>
__global__ __launch_bounds__(256) void gemm_nn_gs(const float* __restrict__ A,
                                                  const float* __restrict__ B,
                                                  float* __restrict__ C,
                                                  int N, int K,
                                                  const int* __restrict__ idx,
                                                  const int* __restrict__ cnt) {
    const int c = *cnt;
    const int ntm = (c + 63) >> 6;
    const int ntn = N >> 6;
    const int total = ntm * ntn;
    __shared__ float As[16][68];
    __shared__ float Bs[16][68];
    const int tid = threadIdx.x;
    const int am = tid >> 2, ak = (tid & 3) << 2;
    const int bk = tid >> 4, bn = (tid & 15) << 2;
    const int tn = tid & 15, tm = tid >> 4;
    for (int tile = blockIdx.x; tile < total; tile += gridDim.x) {
        const int m0 = (tile % ntm) << 6, n0 = (tile / ntm) << 6;
        int ar = m0 + am;
        ar = ar < c ? ar : c - 1;
        float acc[4][4] = {};
        for (int k0 = 0; k0 < K; k0 += 16) {
            float4 a4 = *(const float4*)&A[(size_t)ar * K + k0 + ak];
            float4 b4 = *(const float4*)&B[(size_t)(k0 + bk) * N + n0 + bn];
            __syncthreads();
            As[ak + 0][am] = a4.x;
            As[ak + 1][am] = a4.y;
            As[ak + 2][am] = a4.z;
            As[ak + 3][am] = a4.w;
            *(float4*)&Bs[bk][bn] = b4;
            __syncthreads();
#pragma unroll
            for (int kk = 0; kk < 16; ++kk) {
                float4 av = *(const float4*)&As[kk][tm << 2];
                float4 bv = *(const float4*)&Bs[kk][tn << 2];
                float a[4] = {av.x, av.y, av.z, av.w};
                float b[4] = {bv.x, bv.y, bv.z, bv.w};
#pragma unroll
                for (int i = 0; i < 4; ++i)
#pragma unroll
                    for (int j = 0; j < 4; ++j)
                        acc[i][j] = fmaf(a[i], b[j], acc[i][j]);
            }
        }
#pragma unroll
        for (int i = 0; i < 4; ++i) {
            int p = m0 + (tm << 2) + i;
            if (p >= c) continue;
            int r = SCAT ? idx[p] : p;
            float* cp = &C[(size_t)r * N + n0 + (tn << 2)];
            float rr[4] = {acc[i][0], acc[i][1], acc[i][2], acc[i][3]};
            if (GELU) {
#pragma unroll
                for (int j = 0; j < 4; ++j) rr[j] = gelu_f(rr[j]);
            }
            if (ADD) {
                float4 cc = *(const float4*)cp;
                rr[0] += cc.x; rr[1] += cc.y; rr[2] += cc.z; rr[3] += cc.w;
            }
            float4 rv = {rr[0], rr[1], rr[2], rr[3]};
            *(float4*)cp = rv;
        }
        __syncthreads();
    }
}

// -------------------- grid-stride fp32 head GEMM over compacted rows (blocks 1-2) -----
__global__ __launch_bounds__(256) void gemm_nt_head_gs(const float* __restrict__ A,
                                                       const float* __restrict__ Bt,
                                                       float* __restrict__ C,
                                                       const int* __restrict__ idx,
                                                       const int* __restrict__ cnt) {
    const int c = *cnt;
    const int ntm = (c + 63) >> 6;
    const int ntn = NVOCAB >> 6;
    const int total = ntm * ntn;
    __shared__ float As[16][68];
    __shared__ float Bs[16][68];
    const int tid = threadIdx.x;
    const int am = tid >> 2, ak = (tid & 3) << 2;
    const int tn = tid & 15, tm = tid >> 4;
    for (int tile = blockIdx.x; tile < total; tile += gridDim.x) {
        const int m0 = (tile % ntm) << 6, n0 = (tile / ntm) << 6;
        int ap = m0 + am;
        int ar = idx[ap < c ? ap : c - 1];
        float acc[4][4] = {};
        for (int k0 = 0; k0 < DIM; k0 += 16) {
            float4 a4 = *(const float4*)&A[(size_t)ar * DIM + k0 + ak];
            float4 b4 = *(const float4*)&Bt[(size_t)(n0 + am) * DIM + k0 + ak];
            __syncthreads();
            As[ak + 0][am] = a4.x;
            As[ak + 1][am] = a4.y;
            As[ak + 2][am] = a4.z;
            As[ak + 3][am] = a4.w;
            Bs[ak + 0][am] = b4.x;
            Bs[ak + 1][am] = b4.y;
            Bs[ak + 2][am] = b4.z;
            Bs[ak + 3][am] = b4.w;
            __syncthreads();
#pragma unroll
            for (int kk = 0; kk < 16; ++kk) {
                float4 av = *(const float4*)&As[kk][tm << 2];
                float4 bv = *(const float4*)&Bs[kk][tn << 2];
                float a[4] = {av.x, av.y, av.z, av.w};
                float b[4] = {bv.x, bv.y, bv.z, bv.w};
#pragma unroll
                for (int i = 0; i < 4; ++i)
#pragma unroll
                    for (int j = 0; j < 4; ++j)
                        acc[i][j] = fmaf(a[i], b[j], acc[i][j]);
            }
        }
#pragma unroll
        for (int i = 0; i < 4; ++i) {
            int p = m0 + (tm << 2) + i;
            if (p >= c) continue;
            int r = idx[p];
            float4 rv = {acc[i][0], acc[i][1], acc[i][2], acc[i][3]};
            *(float4*)&C[(size_t)r * NVOCAB + n0 + (tn << 2)] = rv;
        }
        __syncthreads();
    }
}

// -------------------- confidence + exit (vectorized full-row read) --------------------
template<bool IDX>
__global__ __launch_bounds__(256) void conf_exit(const float* __restrict__ out,
                                                 int* __restrict__ flags,
                                                 const int* __restrict__ idx,
                                                 const int* __restrict__ cnt,
                                                 float thr) {
    int t;
    if (IDX) {
        if (blockIdx.x >= *cnt) return;
        t = idx[blockIdx.x];
    } else {
        t = blockIdx.x;
        if (flags[t] == 0) return;
    }
    const float4* row = (const float4*)(out + (size_t)t * NVOCAB);
    float m = -INFINITY, s = 0.0f;
    for (int i = threadIdx.x; i < NVOCAB / 4; i += 256) {
        float4 v = row[i];
        float m4 = fmaxf(fmaxf(v.x, v.y), fmaxf(v.z, v.w));
        float s4 = __expf(v.x - m4) + __expf(v.y - m4) + __expf(v.z - m4) + __expf(v.w - m4);
        if (m4 > m) {
            s = s * __expf(m - m4) + s4;
            m = m4;
        } else {
            s += s4 * __expf(m4 - m);
        }
    }
    __shared__ float ms[256], ss[256];
    ms[threadIdx.x] = m;
    ss[threadIdx.x] = s;
    __syncthreads();
    for (int st = 128; st; st >>= 1) {
        if (threadIdx.x < st) {
            float m1 = ms[threadIdx.x], s1 = ss[threadIdx.x];
            float m2 = ms[threadIdx.x + st], s2 = ss[threadIdx.x + st];
            float mm = fmaxf(m1, m2);
            ss[threadIdx.x] = s1 * __expf(m1 - mm) + s2 * __expf(m2 - mm);
            ms[threadIdx.x] = mm;
        }
        __syncthreads();
    }
    if (threadIdx.x == 0) {
        float conf = 1.0f / ss[0];
        if (conf > thr) flags[t] = 0;
    }
}

// -------------------- ordered compaction of active tokens (single block) --------------------
__global__ __launch_bounds__(256) void compact_kernel(const int* __restrict__ flags,
                                                      int* __restrict__ idx,
                                                      int* __restrict__ cnt) {
    __shared__ int wsum[4];
    __shared__ int base;
    if (threadIdx.x == 0) base = 0;
    int lane = threadIdx.x & 63, wv = threadIdx.x >> 6;
    for (int chunk = 0; chunk < TT; chunk += 256) {
        __syncthreads();
        int t = chunk + threadIdx.x;
        int f = flags[t];
        unsigned long long b = __ballot(f != 0);
        if (lane == 0) wsum[wv] = __popcll(b);
        __syncthreads();
        int off = base;
        for (int w = 0; w < wv; ++w) off += wsum[w];
        off += __popcll(b & ((1ull << lane) - 1));
        if (f) idx[off] = t;
        __syncthreads();
        if (threadIdx.x == 0) base += wsum[0] + wsum[1] + wsum[2] + wsum[3];
    }
    __syncthreads();
    if (threadIdx.x == 0) *cnt = base;
}

extern "C" void kernel_launch(void* const* d_in, const int* in_sizes, int n_in,
                              void* d_out, int out_size, void* d_ws, size_t ws_size,
                              hipStream_t stream) {
    const int* x = (const int*)d_in[0];
    const float* emb = (const float*)d_in[1];
    const float* head = (const float*)d_in[2];
    const float* Wv = (const float*)d_in[3];
    const float* Wo = (const float*)d_in[4];
    const float* W1 = (const float*)d_in[5];
    const float* W2 = (const float*)d_in[6];
    const float* ln1s = (const float*)d_in[7];
    const float* ln1b = (const float*)d_in[8];
    const float* ln2s = (const float*)d_in[9];
    const float* ln2b = (const float*)d_in[10];
    float* out = (float*)d_out;
    float* ws = (float*)d_ws;

    float* h  = ws;                      // TT*DIM fp32
    float* hn = ws + 2097152;            // TT*DIM
    float* tA = ws + 4194304;            // TT*DIM (scratch: WvFlat hi/lo during setup)
    float* tF = ws + 6291456;            // TT*FFN
    short* hnHi = (short*)hn;
    short* hnLo = hnHi + TT * DIM;
    short* tAHi = (short*)tA;
    short* tALo = tAHi + TT * DIM;
    short* tFHi = (short*)tF;
    short* tFLo = tFHi + TT * FFN;
    // conf partials alias tF (free at head time; blocks 1-2 write tF only after conf_reduce)
    float2* pp = (float2*)tF;            // TT*NGRP float2 = 16 MB < 33 MB region
    int* flags = (int*)(ws + 14680064);  // TT
    int* idxl  = flags + TT;             // TT
    int* cntp  = flags + 2 * TT;         // 1
    short* hHi    = (short*)(ws + 14700000);
    short* hLo    = (short*)(ws + 15748576);
    short* headHi = (short*)(ws + 16797152);
    short* headLo = (short*)(ws + 24989152);
    short* wT     = (short*)(ws + 33181152);  // 2 layers x 5242880 shorts
    const size_t LSTRIDE = 5242880;
    const size_t NEED_T2 = (size_t)33181152 * 4;
    const size_t NEED_T1 = (size_t)38424032 * 4;
    const int tier = ws_size >= NEED_T1 ? 1 : (ws_size >= NEED_T2 ? 2 : 3);

    gather_kernel<<<TT, 128, 0, stream>>>(x, emb, h, flags);

    const float THR[3] = {3.5e-05f, 4.0e-05f, 1.0f};
    const dim3 gDD(DIM / 64, TT / 64), gDF(FFN / 64, TT / 64), gHead(NVOCAB / 64, TT / 64);

    // ---------- block 0: dense ----------
    if (tier == 1) {
        // weight prep: transpose-splits; W_voT = WoT @ WvFlat (3-product MFMA)
        for (int l = 0; l < 2; ++l) {
            short* wb = wT + (size_t)l * LSTRIDE;
            cvt_hilo<<<(DIM * DIM / 4 + 255) / 256, 256, 0, stream>>>(Wv + (size_t)l * DIM * DIM, tAHi, tALo, DIM * DIM / 4);
            cvt_w_t<<<dim3(DIM / 32, DIM / 32), 256, 0, stream>>>(Wo + (size_t)l * DIM * DIM, wb + 524288, wb + 786432, DIM, DIM);
            gemm_l64<0><<<dim3(DIM / 64, DIM / 128), 256, 0, stream>>>(
                wb + 524288, wb + 786432, tAHi, tALo, nullptr, wb, wb + 262144, DIM, DIM);
            cvt_w_t_hi<<<dim3(FFN / 32, DIM / 32), 256, 0, stream>>>(W1 + (size_t)l * DIM * FFN, wb + 1048576, DIM, FFN);
            cvt_w_t_hi<<<dim3(DIM / 32, FFN / 32), 256, 0, stream>>>(W2 + (size_t)l * FFN * DIM, wb + 3145728, FFN, DIM);
        }
        for (int l = 0; l < 2; ++l) {
            short* wb = wT + (size_t)l * LSTRIDE;
            ln_hilo<<<TT / 4, 256, 0, stream>>>(h, ln1s + l * DIM, ln1b + l * DIM, hnHi, hnLo);
            gemm_l64b<2><<<dim3(TT / 64, DIM / 128), 256, 0, stream>>>(hnHi, hnLo, wb, h, nullptr, nullptr, DIM, DIM);
            ln_hilo<<<TT / 4, 256, 0, stream>>>(h, ln2s + l * DIM, ln2b + l * DIM, hnHi, hnLo);
            gemm_l2<1><<<dim3(TT / 128, FFN / 128), 256, 0, stream>>>(hnHi, hnLo, wb + 1048576, nullptr, tFHi, tFLo, FFN, DIM);
            if (l == 1) {
                gemm_l64b<4><<<dim3(TT / 64, DIM / 128), 256, 0, stream>>>(tFHi, tFLo, wb + 3145728, h, hHi, hLo, DIM, FFN);
            } else {
                gemm_l64b<2><<<dim3(TT / 64, DIM / 128), 256, 0, stream>>>(tFHi, tFLo, wb + 3145728, h, nullptr, nullptr, DIM, FFN);
            }
        }
        cvt_bf16<<<(NVOCAB * DIM / 4 + 255) / 256, 256, 0, stream>>>(head, headHi, NVOCAB * DIM / 4);
        gemm_head_bf16<<<dim3(TT / 128, NVOCAB / 128), 256, 0, stream>>>(hHi, headHi, out, pp, NVOCAB, DIM);
        conf_reduce<<<TT / 4, 256, 0, stream>>>(pp, flags, THR[0]);
    } else {
        for (int l = 0; l < 2; ++l) {
            ln_kernel<false><<<TT / 4, 256, 0, stream>>>(h, ln1s + l * DIM, ln1b + l * DIM, hn, nullptr, nullptr);
            gemm_nn<false, false><<<gDD, 256, 0, stream>>>(hn, Wv + (size_t)l * DIM * DIM, tA, TT, DIM, DIM);
            gemm_nn<true, false><<<gDD, 256, 0, stream>>>(tA, Wo + (size_t)l * DIM * DIM, h, TT, DIM, DIM);
            ln_kernel<false><<<TT / 4, 256, 0, stream>>>(h, ln2s + l * DIM, ln2b + l * DIM, hn, nullptr, nullptr);
            gemm_nn<false, true><<<gDF, 256, 0, stream>>>(hn, W1 + (size_t)l * DIM * FFN, tF, TT, FFN, DIM);
            gemm_nn<true, false><<<gDD, 256, 0, stream>>>(tF, W2 + (size_t)l * FFN * DIM, h, TT, DIM, FFN);
        }
        if (tier == 2) {
            cvt_hilo<<<(TT * DIM / 4 + 255) / 256, 256, 0, stream>>>(h, hHi, hLo, TT * DIM / 4);
            cvt_hilo<<<(NVOCAB * DIM / 4 + 255) / 256, 256, 0, stream>>>(head, headHi, headLo, NVOCAB * DIM / 4);
            gemm_l_mfma<3><<<dim3(TT / 128, NVOCAB / 128), 256, 0, stream>>>(hHi, hLo, headHi, headLo, out, nullptr, nullptr, NVOCAB, DIM);
        } else {
            compact_kernel<<<1, 256, 0, stream>>>(flags, idxl, cntp);
            gemm_nt_head_gs<<<512, 256, 0, stream>>>(h, head, out, idxl, cntp);
        }
        conf_exit<false><<<TT, 256, 0, stream>>>(out, flags, nullptr, nullptr, THR[0]);
    }
    compact_kernel<<<1, 256, 0, stream>>>(flags, idxl, cntp);

    // ---------- blocks 1,2: compacted active rows (grid-stride fp32 path; ~empty) ----------
    for (int b = 1; b < 3; ++b) {
        for (int li = 0; li < 2; ++li) {
            int l = b * 2 + li;
            ln_kernel<true><<<TT / 4, 256, 0, stream>>>(h, ln1s + l * DIM, ln1b + l * DIM, hn, idxl, cntp);
            gemm_nn_gs<false, false, false><<<256, 256, 0, stream>>>(hn, Wv + (size_t)l * DIM * DIM, tA, DIM, DIM, idxl, cntp);
            gemm_nn_gs<true, false, true><<<256, 256, 0, stream>>>(tA, Wo + (size_t)l * DIM * DIM, h, DIM, DIM, idxl, cntp);
            ln_kernel<true><<<TT / 4, 256, 0, stream>>>(h, ln2s + l * DIM, ln2b + l * DIM, hn, idxl, cntp);
            gemm_nn_gs<false, true, false><<<256, 256, 0, stream>>>(hn, W1 + (size_t)l * DIM * FFN, tF, FFN, DIM, idxl, cntp);
            gemm_nn_gs<true, false, true><<<256, 256, 0, stream>>>(tF, W2 + (size_t)l * FFN * DIM, h, DIM, FFN, idxl, cntp);
        }
        gemm_nt_head_gs<<<512, 256, 0, stream>>>(h, head, out, idxl, cntp);
        if (b == 1) {
            conf_exit<true><<<TT, 256, 0, stream>>>(out, flags, idxl, cntp, THR[1]);
            compact_kernel<<<1, 256, 0, stream>>>(flags, idxl, cntp);
        }
    }
}

// Round 14
// 659.421 us; speedup vs baseline: 1.6261x; 1.0413x over previous
//
#include <hip/hip_runtime.h>
#include <hip/hip_bf16.h>
#include <math.h>

#define TT 4096
#define DIM 512
#define FFN 2048
#define NVOCAB 32000
#define NGRP 500   // conf partial groups per token (250 n-tiles x 2 wave strips)

typedef __attribute__((ext_vector_type(8))) short short8_t;
typedef __attribute__((ext_vector_type(4))) float f32x4;

__device__ __forceinline__ float gelu_f(float x) {
    float x3 = x * x * x;
    float u = 0.7978845608028654f * (x + 0.044715f * x3);
    return 0.5f * x * (1.0f + tanhf(u));
}

__device__ __forceinline__ unsigned short f2bf_rn(float f) {
    unsigned u = __float_as_uint(f);
    u += 0x7FFFu + ((u >> 16) & 1u);
    return (unsigned short)(u >> 16);
}

// -------------------- embedding gather + flag init --------------------
__global__ __launch_bounds__(128) void gather_kernel(const int* __restrict__ x,
                                                     const float* __restrict__ emb,
                                                     float* __restrict__ h,
                                                     int* __restrict__ flags) {
    int t = blockIdx.x;
    int idx = x[t];
    const float4 v = *(const float4*)&emb[(size_t)idx * DIM + threadIdx.x * 4];
    *(float4*)&h[(size_t)t * DIM + threadIdx.x * 4] = v;
    if (threadIdx.x == 0) flags[t] = 1;
}

// -------------------- fp32 -> bf16 hi/lo split (flat) --------------------
__global__ __launch_bounds__(256) void cvt_hilo(const float* __restrict__ src,
                                                short* __restrict__ hi,
                                                short* __restrict__ lo, int n4) {
    int i = blockIdx.x * 256 + threadIdx.x;
    if (i >= n4) return;
    float4 v = *(const float4*)&src[(size_t)i * 4];
    float f[4] = {v.x, v.y, v.z, v.w};
    short4 hv, lv;
    short* hp = &hv.x;
    short* lp = &lv.x;
#pragma unroll
    for (int j = 0; j < 4; ++j) {
        unsigned short hb = f2bf_rn(f[j]);
        float hf = __uint_as_float((unsigned)hb << 16);
        unsigned short lb = f2bf_rn(f[j] - hf);
        hp[j] = (short)hb;
        lp[j] = (short)lb;
    }
    *(short4*)&hi[(size_t)i * 4] = hv;
    *(short4*)&lo[(size_t)i * 4] = lv;
}

// -------------------- fp32 -> bf16 (hi only, flat) --------------------
__global__ __launch_bounds__(256) void cvt_bf16(const float* __restrict__ src,
                                                short* __restrict__ hi, int n4) {
    int i = blockIdx.x * 256 + threadIdx.x;
    if (i >= n4) return;
    float4 v = *(const float4*)&src[(size_t)i * 4];
    float f[4] = {v.x, v.y, v.z, v.w};
    short4 hv;
    short* hp = &hv.x;
#pragma unroll
    for (int j = 0; j < 4; ++j) hp[j] = (short)f2bf_rn(f[j]);
    *(short4*)&hi[(size_t)i * 4] = hv;
}

// -------------------- fp32 W (K,N) -> bf16 hi/lo transposed (N,K) --------------------
__global__ __launch_bounds__(256) void cvt_w_t(const float* __restrict__ W,
                                               short* __restrict__ hiT,
                                               short* __restrict__ loT,
                                               int K, int N) {
    __shared__ short hs[32][36];
    __shared__ short ls[32][36];
    const int n0 = blockIdx.x * 32, k0 = blockIdx.y * 32;
    const int r = threadIdx.x >> 3, c4 = (threadIdx.x & 7) << 2;
    float4 v = *(const float4*)&W[(size_t)(k0 + r) * N + n0 + c4];
    float f[4] = {v.x, v.y, v.z, v.w};
#pragma unroll
    for (int j = 0; j < 4; ++j) {
        unsigned short hb = f2bf_rn(f[j]);
        float hf = __uint_as_float((unsigned)hb << 16);
        unsigned short lb = f2bf_rn(f[j] - hf);
        hs[r][c4 + j] = (short)hb;
        ls[r][c4 + j] = (short)lb;
    }
    __syncthreads();
    const int nr = threadIdx.x >> 3, kc4 = (threadIdx.x & 7) << 2;
    short4 hv, lv;
    short* hp = &hv.x;
    short* lp = &lv.x;
#pragma unroll
    for (int j = 0; j < 4; ++j) {
        hp[j] = hs[kc4 + j][nr];
        lp[j] = ls[kc4 + j][nr];
    }
    *(short4*)&hiT[(size_t)(n0 + nr) * K + k0 + kc4] = hv;
    *(short4*)&loT[(size_t)(n0 + nr) * K + k0 + kc4] = lv;
}

// -------------------- fp32 W (K,N) -> bf16 hi transposed only --------------------
__global__ __launch_bounds__(256) void cvt_w_t_hi(const float* __restrict__ W,
                                                  short* __restrict__ hiT,
                                                  int K, int N) {
    __shared__ short hs[32][36];
    const int n0 = blockIdx.x * 32, k0 = blockIdx.y * 32;
    const int r = threadIdx.x >> 3, c4 = (threadIdx.x & 7) << 2;
    float4 v = *(const float4*)&W[(size_t)(k0 + r) * N + n0 + c4];
    float f[4] = {v.x, v.y, v.z, v.w};
#pragma unroll
    for (int j = 0; j < 4; ++j) hs[r][c4 + j] = (short)f2bf_rn(f[j]);
    __syncthreads();
    const int nr = threadIdx.x >> 3, kc4 = (threadIdx.x & 7) << 2;
    short4 hv;
    short* hp = &hv.x;
#pragma unroll
    for (int j = 0; j < 4; ++j) hp[j] = hs[kc4 + j][nr];
    *(short4*)&hiT[(size_t)(n0 + nr) * K + k0 + kc4] = hv;
}

// -------------------- LayerNorm (fp32 out; optional index gather) --------------------
template<bool IDX>
__global__ __launch_bounds__(256) void ln_kernel(const float* __restrict__ x,
                                                 const float* __restrict__ gam,
                                                 const float* __restrict__ bet,
                                                 float* __restrict__ out,
                                                 const int* __restrict__ idx,
                                                 const int* __restrict__ cnt) {
    int wv = threadIdx.x >> 6, lane = threadIdx.x & 63;
    int p = (blockIdx.x << 2) | wv;
    if (IDX && p >= *cnt) return;
    int t = IDX ? idx[p] : p;
    const float* row = x + (size_t)t * DIM;
    int base = lane * 8;
    float4 v0 = *(const float4*)&row[base];
    float4 v1 = *(const float4*)&row[base + 4];
    float s = v0.x + v0.y + v0.z + v0.w + v1.x + v1.y + v1.z + v1.w;
#pragma unroll
    for (int o = 32; o; o >>= 1) s += __shfl_xor(s, o, 64);
    float mean = s * (1.0f / (float)DIM);
    float d0 = v0.x - mean, d1 = v0.y - mean, d2 = v0.z - mean, d3 = v0.w - mean;
    float d4 = v1.x - mean, d5 = v1.y - mean, d6 = v1.z - mean, d7 = v1.w - mean;
    float q = d0*d0 + d1*d1 + d2*d2 + d3*d3 + d4*d4 + d5*d5 + d6*d6 + d7*d7;
#pragma unroll
    for (int o = 32; o; o >>= 1) q += __shfl_xor(q, o, 64);
    float var = q * (1.0f / (float)DIM);
    float rs = 1.0f / sqrtf(var + 1e-5f);
    float4 g0 = *(const float4*)&gam[base];
    float4 g1 = *(const float4*)&gam[base + 4];
    float4 b0 = *(const float4*)&bet[base];
    float4 b1 = *(const float4*)&bet[base + 4];
    float4 o0, o1;
    o0.x = d0 * rs * g0.x + b0.x;  o0.y = d1 * rs * g0.y + b0.y;
    o0.z = d2 * rs * g0.z + b0.z;  o0.w = d3 * rs * g0.w + b0.w;
    o1.x = d4 * rs * g1.x + b1.x;  o1.y = d5 * rs * g1.y + b1.y;
    o1.z = d6 * rs * g1.z + b1.z;  o1.w = d7 * rs * g1.w + b1.w;
    float* orow = out + (size_t)p * DIM;
    *(float4*)&orow[base] = o0;
    *(float4*)&orow[base + 4] = o1;
}

// -------------------- LayerNorm -> bf16 hi/lo (dense, block 0) --------------------
__global__ __launch_bounds__(256) void ln_hilo(const float* __restrict__ x,
                                               const float* __restrict__ gam,
                                               const float* __restrict__ bet,
                                               short* __restrict__ ohi,
                                               short* __restrict__ olo) {
    int wv = threadIdx.x >> 6, lane = threadIdx.x & 63;
    int t = (blockIdx.x << 2) | wv;
    const float* row = x + (size_t)t * DIM;
    int base = lane * 8;
    float4 v0 = *(const float4*)&row[base];
    float4 v1 = *(const float4*)&row[base + 4];
    float s = v0.x + v0.y + v0.z + v0.w + v1.x + v1.y + v1.z + v1.w;
#pragma unroll
    for (int o = 32; o; o >>= 1) s += __shfl_xor(s, o, 64);
    float mean = s * (1.0f / (float)DIM);
    float d[8] = {v0.x - mean, v0.y - mean, v0.z - mean, v0.w - mean,
                  v1.x - mean, v1.y - mean, v1.z - mean, v1.w - mean};
    float q = 0.0f;
#pragma unroll
    for (int j = 0; j < 8; ++j) q += d[j] * d[j];
#pragma unroll
    for (int o = 32; o; o >>= 1) q += __shfl_xor(q, o, 64);
    float var = q * (1.0f / (float)DIM);
    float rs = 1.0f / sqrtf(var + 1e-5f);
    float g[8], bb[8];
    *(float4*)&g[0] = *(const float4*)&gam[base];
    *(float4*)&g[4] = *(const float4*)&gam[base + 4];
    *(float4*)&bb[0] = *(const float4*)&bet[base];
    *(float4*)&bb[4] = *(const float4*)&bet[base + 4];
    short8_t hv, lv;
#pragma unroll
    for (int j = 0; j < 8; ++j) {
        float val = d[j] * rs * g[j] + bb[j];
        unsigned short hb = f2bf_rn(val);
        float hf = __uint_as_float((unsigned)hb << 16);
        hv[j] = (short)hb;
        lv[j] = (short)f2bf_rn(val - hf);
    }
    *(short8_t*)&ohi[(size_t)t * DIM + base] = hv;
    *(short8_t*)&olo[(size_t)t * DIM + base] = lv;
}

// ==================== EPILOGUE helper ====================
__device__ __forceinline__ void epi_store(int EPI, float val, size_t off,
                                          float* Cf, short* oHi, short* oLo) {
    if (EPI == 3) {
        Cf[off] = val;
    } else if (EPI == 2) {
        Cf[off] += val;
    } else if (EPI == 4) {
        float nv = Cf[off] + val;
        Cf[off] = nv;
        unsigned short hb = f2bf_rn(nv);
        float hf = __uint_as_float((unsigned)hb << 16);
        oHi[off] = (short)hb;
        oLo[off] = (short)f2bf_rn(nv - hf);
    } else {
        if (EPI == 1) val = gelu_f(val);
        unsigned short hb = f2bf_rn(val);
        float hf = __uint_as_float((unsigned)hb << 16);
        oHi[off] = (short)hb;
        oLo[off] = (short)f2bf_rn(val - hf);
    }
}

// -------------------- 3-product split-bf16 MFMA GEMM (128x128) --------------------
template<int EPI>
__global__ __launch_bounds__(256) void gemm_l_mfma(const short* __restrict__ Ah,
                                                   const short* __restrict__ Al,
                                                   const short* __restrict__ Bh,
                                                   const short* __restrict__ Bl,
                                                   float* __restrict__ Cf,
                                                   short* __restrict__ oHi,
                                                   short* __restrict__ oLo,
                                                   int N, int K) {
    __shared__ __align__(16) short sm[16384];
    short* sAh = sm;
    short* sAl = sm + 4096;
    short* sBh = sm + 8192;
    short* sBl = sm + 12288;
    const int tid = threadIdx.x;
    const int wv = tid >> 6, lane = tid & 63;
    const int m0 = blockIdx.x * 128;
    const int n0 = blockIdx.y * 128;
    const int wm = (wv & 1) * 64, wn = (wv >> 1) * 64;
    const int r16 = lane >> 2;
    const int gsw = ((lane & 3) ^ (r16 & 3)) << 3;
    const int fr = lane & 15;
    const int q = lane >> 4;

    f32x4 acc[4][4];
#pragma unroll
    for (int i = 0; i < 4; ++i)
#pragma unroll
        for (int j = 0; j < 4; ++j)
            acc[i][j] = (f32x4){0.0f, 0.0f, 0.0f, 0.0f};

    const int NKT = K >> 5;
    for (int kt = 0; kt < NKT; ++kt) {
        const int k0 = kt << 5;
        __syncthreads();
#pragma unroll
        for (int j = 0; j < 2; ++j) {
            const int rr = (wv << 5) + (j << 4);
            const int gr = rr + r16;
            const short* ga_h = Ah + (size_t)(m0 + gr) * K + k0 + gsw;
            const short* ga_l = Al + (size_t)(m0 + gr) * K + k0 + gsw;
            const short* gb_h = Bh + (size_t)(n0 + gr) * K + k0 + gsw;
            const short* gb_l = Bl + (size_t)(n0 + gr) * K + k0 + gsw;
            __builtin_amdgcn_global_load_lds((const __attribute__((address_space(1))) void*)ga_h,
                                             (__attribute__((address_space(3))) void*)(sAh + rr * 32), 16, 0, 0);
            __builtin_amdgcn_global_load_lds((const __attribute__((address_space(1))) void*)ga_l,
                                             (__attribute__((address_space(3))) void*)(sAl + rr * 32), 16, 0, 0);
            __builtin_amdgcn_global_load_lds((const __attribute__((address_space(1))) void*)gb_h,
                                             (__attribute__((address_space(3))) void*)(sBh + rr * 32), 16, 0, 0);
            __builtin_amdgcn_global_load_lds((const __attribute__((address_space(1))) void*)gb_l,
                                             (__attribute__((address_space(3))) void*)(sBl + rr * 32), 16, 0, 0);
        }
        __syncthreads();
        short8_t ah[4], al[4], bh[4], bl[4];
#pragma unroll
        for (int i = 0; i < 4; ++i) {
            const int ra = wm + i * 16 + fr;
            const int rb = wn + i * 16 + fr;
            const int swa = (q ^ (fr & 3)) << 3;
            ah[i] = *(const short8_t*)&sAh[ra * 32 + swa];
            al[i] = *(const short8_t*)&sAl[ra * 32 + swa];
            bh[i] = *(const short8_t*)&sBh[rb * 32 + swa];
            bl[i] = *(const short8_t*)&sBl[rb * 32 + swa];
        }
#pragma unroll
        for (int i = 0; i < 4; ++i)
#pragma unroll
            for (int j = 0; j < 4; ++j) {
                acc[i][j] = __builtin_amdgcn_mfma_f32_16x16x32_bf16(ah[i], bh[j], acc[i][j], 0, 0, 0);
                acc[i][j] = __builtin_amdgcn_mfma_f32_16x16x32_bf16(ah[i], bl[j], acc[i][j], 0, 0, 0);
                acc[i][j] = __builtin_amdgcn_mfma_f32_16x16x32_bf16(al[i], bh[j], acc[i][j], 0, 0, 0);
            }
    }
    const int row_base = (lane >> 4) << 2;
#pragma unroll
    for (int i = 0; i < 4; ++i)
#pragma unroll
        for (int j = 0; j < 4; ++j) {
            const int row = m0 + wm + i * 16 + row_base;
            const int col = n0 + wn + j * 16 + fr;
#pragma unroll
            for (int r = 0; r < 4; ++r)
                epi_store(EPI, acc[i][j][r], (size_t)(row + r) * N + col, Cf, oHi, oLo);
        }
}

// -------------------- 2-product GEMM (128x128): A hi/lo, B hi only --------------------
template<int EPI>
__global__ __launch_bounds__(256) void gemm_l2(const short* __restrict__ Ah,
                                               const short* __restrict__ Al,
                                               const short* __restrict__ Bh,
                                               float* __restrict__ Cf,
                                               short* __restrict__ oHi,
                                               short* __restrict__ oLo,
                                               int N, int K) {
    __shared__ __align__(16) short sm[12288];
    short* sAh = sm;
    short* sAl = sm + 4096;
    short* sBh = sm + 8192;
    const int tid = threadIdx.x;
    const int wv = tid >> 6, lane = tid & 63;
    const int m0 = blockIdx.x * 128;
    const int n0 = blockIdx.y * 128;
    const int wm = (wv & 1) * 64, wn = (wv >> 1) * 64;
    const int r16 = lane >> 2;
    const int gsw = ((lane & 3) ^ (r16 & 3)) << 3;
    const int fr = lane & 15;
    const int q = lane >> 4;

    f32x4 acc[4][4];
#pragma unroll
    for (int i = 0; i < 4; ++i)
#pragma unroll
        for (int j = 0; j < 4; ++j)
            acc[i][j] = (f32x4){0.0f, 0.0f, 0.0f, 0.0f};

    const int NKT = K >> 5;
    for (int kt = 0; kt < NKT; ++kt) {
        const int k0 = kt << 5;
        __syncthreads();
#pragma unroll
        for (int j = 0; j < 2; ++j) {
            const int rr = (wv << 5) + (j << 4);
            const int gr = rr + r16;
            const short* ga_h = Ah + (size_t)(m0 + gr) * K + k0 + gsw;
            const short* ga_l = Al + (size_t)(m0 + gr) * K + k0 + gsw;
            const short* gb_h = Bh + (size_t)(n0 + gr) * K + k0 + gsw;
            __builtin_amdgcn_global_load_lds((const __attribute__((address_space(1))) void*)ga_h,
                                             (__attribute__((address_space(3))) void*)(sAh + rr * 32), 16, 0, 0);
            __builtin_amdgcn_global_load_lds((const __attribute__((address_space(1))) void*)ga_l,
                                             (__attribute__((address_space(3))) void*)(sAl + rr * 32), 16, 0, 0);
            __builtin_amdgcn_global_load_lds((const __attribute__((address_space(1))) void*)gb_h,
                                             (__attribute__((address_space(3))) void*)(sBh + rr * 32), 16, 0, 0);
        }
        __syncthreads();
        short8_t ah[4], al[4], bh[4];
#pragma unroll
        for (int i = 0; i < 4; ++i) {
            const int ra = wm + i * 16 + fr;
            const int rb = wn + i * 16 + fr;
            const int swa = (q ^ (fr & 3)) << 3;
            ah[i] = *(const short8_t*)&sAh[ra * 32 + swa];
            al[i] = *(const short8_t*)&sAl[ra * 32 + swa];
            bh[i] = *(const short8_t*)&sBh[rb * 32 + swa];
        }
#pragma unroll
        for (int i = 0; i < 4; ++i)
#pragma unroll
            for (int j = 0; j < 4; ++j) {
                acc[i][j] = __builtin_amdgcn_mfma_f32_16x16x32_bf16(ah[i], bh[j], acc[i][j], 0, 0, 0);
                acc[i][j] = __builtin_amdgcn_mfma_f32_16x16x32_bf16(al[i], bh[j], acc[i][j], 0, 0, 0);
            }
    }
    const int row_base = (lane >> 4) << 2;
#pragma unroll
    for (int i = 0; i < 4; ++i)
#pragma unroll
        for (int j = 0; j < 4; ++j) {
            const int row = m0 + wm + i * 16 + row_base;
            const int col = n0 + wn + j * 16 + fr;
#pragma unroll
            for (int r = 0; r < 4; ++r)
                epi_store(EPI, acc[i][j][r], (size_t)(row + r) * N + col, Cf, oHi, oLo);
        }
}

// -------------------- 2-product GEMM (64x128): A hi/lo, B hi only --------------------
template<int EPI>
__global__ __launch_bounds__(256) void gemm_l64b(const short* __restrict__ Ah,
                                                 const short* __restrict__ Al,
                                                 const short* __restrict__ Bh,
                                                 float* __restrict__ Cf,
                                                 short* __restrict__ oHi,
                                                 short* __restrict__ oLo,
                                                 int N, int K) {
    __shared__ __align__(16) short sm[8192];
    short* sAh = sm;
    short* sAl = sm + 2048;
    short* sBh = sm + 4096;
    const int tid = threadIdx.x;
    const int wv = tid >> 6, lane = tid & 63;
    const int m0 = blockIdx.x * 64;
    const int n0 = blockIdx.y * 128;
    const int wm = (wv & 1) * 32, wn = (wv >> 1) * 64;
    const int r16 = lane >> 2;
    const int gsw = ((lane & 3) ^ (r16 & 3)) << 3;
    const int fr = lane & 15;
    const int q = lane >> 4;

    f32x4 acc[2][4];
#pragma unroll
    for (int i = 0; i < 2; ++i)
#pragma unroll
        for (int j = 0; j < 4; ++j)
            acc[i][j] = (f32x4){0.0f, 0.0f, 0.0f, 0.0f};

    const int NKT = K >> 5;
    for (int kt = 0; kt < NKT; ++kt) {
        const int k0 = kt << 5;
        __syncthreads();
        {
            const int rr = wv << 4;
            const int gr = rr + r16;
            const short* ga_h = Ah + (size_t)(m0 + gr) * K + k0 + gsw;
            const short* ga_l = Al + (size_t)(m0 + gr) * K + k0 + gsw;
            __builtin_amdgcn_global_load_lds((const __attribute__((address_space(1))) void*)ga_h,
                                             (__attribute__((address_space(3))) void*)(sAh + rr * 32), 16, 0, 0);
            __builtin_amdgcn_global_load_lds((const __attribute__((address_space(1))) void*)ga_l,
                                             (__attribute__((address_space(3))) void*)(sAl + rr * 32), 16, 0, 0);
        }
#pragma unroll
        for (int j = 0; j < 2; ++j) {
            const int rr = (wv << 5) + (j << 4);
            const int gr = rr + r16;
            const short* gb_h = Bh + (size_t)(n0 + gr) * K + k0 + gsw;
            __builtin_amdgcn_global_load_lds((const __attribute__((address_space(1))) void*)gb_h,
                                             (__attribute__((address_space(3))) void*)(sBh + rr * 32), 16, 0, 0);
        }
        __syncthreads();
        short8_t ah[2], al[2], bh[4];
        const int swa = (q ^ (fr & 3)) << 3;
#pragma unroll
        for (int i = 0; i < 2; ++i) {
            const int ra = wm + i * 16 + fr;
            ah[i] = *(const short8_t*)&sAh[ra * 32 + swa];
            al[i] = *(const short8_t*)&sAl[ra * 32 + swa];
        }
#pragma unroll
        for (int j = 0; j < 4; ++j) {
            const int rb = wn + j * 16 + fr;
            bh[j] = *(const short8_t*)&sBh[rb * 32 + swa];
        }
#pragma unroll
        for (int i = 0; i < 2; ++i)
#pragma unroll
            for (int j = 0; j < 4; ++j) {
                acc[i][j] = __builtin_amdgcn_mfma_f32_16x16x32_bf16(ah[i], bh[j], acc[i][j], 0, 0, 0);
                acc[i][j] = __builtin_amdgcn_mfma_f32_16x16x32_bf16(al[i], bh[j], acc[i][j], 0, 0, 0);
            }
    }
    const int row_base = (lane >> 4) << 2;
#pragma unroll
    for (int i = 0; i < 2; ++i)
#pragma unroll
        for (int j = 0; j < 4; ++j) {
            const int row = m0 + wm + i * 16 + row_base;
            const int col = n0 + wn + j * 16 + fr;
#pragma unroll
            for (int r = 0; r < 4; ++r)
                epi_store(EPI, acc[i][j][r], (size_t)(row + r) * N + col, Cf, oHi, oLo);
        }
}

// -------------------- 3-product GEMM (64x128) — W_vo prep only --------------------
template<int EPI>
__global__ __launch_bounds__(256) void gemm_l64(const short* __restrict__ Ah,
                                                const short* __restrict__ Al,
                                                const short* __restrict__ Bh,
                                                const short* __restrict__ Bl,
                                                float* __restrict__ Cf,
                                                short* __restrict__ oHi,
                                                short* __restrict__ oLo,
                                                int N, int K) {
    __shared__ __align__(16) short sm[12288];
    short* sAh = sm;
    short* sAl = sm + 2048;
    short* sBh = sm + 4096;
    short* sBl = sm + 8192;
    const int tid = threadIdx.x;
    const int wv = tid >> 6, lane = tid & 63;
    const int m0 = blockIdx.x * 64;
    const int n0 = blockIdx.y * 128;
    const int wm = (wv & 1) * 32, wn = (wv >> 1) * 64;
    const int r16 = lane >> 2;
    const int gsw = ((lane & 3) ^ (r16 & 3)) << 3;
    const int fr = lane & 15;
    const int q = lane >> 4;

    f32x4 acc[2][4];
#pragma unroll
    for (int i = 0; i < 2; ++i)
#pragma unroll
        for (int j = 0; j < 4; ++j)
            acc[i][j] = (f32x4){0.0f, 0.0f, 0.0f, 0.0f};

    const int NKT = K >> 5;
    for (int kt = 0; kt < NKT; ++kt) {
        const int k0 = kt << 5;
        __syncthreads();
        {
            const int rr = wv << 4;
            const int gr = rr + r16;
            const short* ga_h = Ah + (size_t)(m0 + gr) * K + k0 + gsw;
            const short* ga_l = Al + (size_t)(m0 + gr) * K + k0 + gsw;
            __builtin_amdgcn_global_load_lds((const __attribute__((address_space(1))) void*)ga_h,
                                             (__attribute__((address_space(3))) void*)(sAh + rr * 32), 16, 0, 0);
            __builtin_amdgcn_global_load_lds((const __attribute__((address_space(1))) void*)ga_l,
                                             (__attribute__((address_space(3))) void*)(sAl + rr * 32), 16, 0, 0);
        }
#pragma unroll
        for (int j = 0; j < 2; ++j) {
            const int rr = (wv << 5) + (j << 4);
            const int gr = rr + r16;
            const short* gb_h = Bh + (size_t)(n0 + gr) * K + k0 + gsw;
            const short* gb_l = Bl + (size_t)(n0 + gr) * K + k0 + gsw;
            __builtin_amdgcn_global_load_lds((const __attribute__((address_space(1))) void*)gb_h,
                                             (__attribute__((address_space(3))) void*)(sBh + rr * 32), 16, 0, 0);
            __builtin_amdgcn_global_load_lds((const __attribute__((address_space(1))) void*)gb_l,
                                             (__attribute__((address_space(3))) void*)(sBl + rr * 32), 16, 0, 0);
        }
        __syncthreads();
        short8_t ah[2], al[2], bh[4], bl[4];
        const int swa = (q ^ (fr & 3)) << 3;
#pragma unroll
        for (int i = 0; i < 2; ++i) {
            const int ra = wm + i * 16 + fr;
            ah[i] = *(const short8_t*)&sAh[ra * 32 + swa];
            al[i] = *(const short8_t*)&sAl[ra * 32 + swa];
        }
#pragma unroll
        for (int j = 0; j < 4; ++j) {
            const int rb = wn + j * 16 + fr;
            bh[j] = *(const short8_t*)&sBh[rb * 32 + swa];
            bl[j] = *(const short8_t*)&sBl[rb * 32 + swa];
        }
#pragma unroll
        for (int i = 0; i < 2; ++i)
#pragma unroll
            for (int j = 0; j < 4; ++j) {
                acc[i][j] = __builtin_amdgcn_mfma_f32_16x16x32_bf16(ah[i], bh[j], acc[i][j], 0, 0, 0);
                acc[i][j] = __builtin_amdgcn_mfma_f32_16x16x32_bf16(ah[i], bl[j], acc[i][j], 0, 0, 0);
                acc[i][j] = __builtin_amdgcn_mfma_f32_16x16x32_bf16(al[i], bh[j], acc[i][j], 0, 0, 0);
            }
    }
    const int row_base = (lane >> 4) << 2;
#pragma unroll
    for (int i = 0; i < 2; ++i)
#pragma unroll
        for (int j = 0; j < 4; ++j) {
            const int row = m0 + wm + i * 16 + row_base;
            const int col = n0 + wn + j * 16 + fr;
#pragma unroll
            for (int r = 0; r < 4; ++r)
                epi_store(EPI, acc[i][j][r], (size_t)(row + r) * N + col, Cf, oHi, oLo);
        }
}

// -------------------- PLAIN bf16 head GEMM: double-buffered counted-vmcnt pipeline ----
// R5-verified schedule on the 2-array bf16 kernel: stage t,t+1 up front; per iter
// wait vmcnt(4) -> raw barrier -> ds_read+MFMA -> lgkmcnt(0)+sched_barrier -> barrier
// -> stage t+2. Conf partials from acc (no LDS/barrier), C stores last.
__global__ __launch_bounds__(256) void gemm_head_bf16(const short* __restrict__ Ah,
                                                      const short* __restrict__ Bh,
                                                      float* __restrict__ C,
                                                      float2* __restrict__ pp,
                                                      int N, int K) {
    __shared__ __align__(16) short sm[16384];  // 2 buf x (A 4096 + B 4096)
    const int tid = threadIdx.x;
    const int wv = tid >> 6, lane = tid & 63;
    const int m0 = blockIdx.x * 128;
    const int n0 = blockIdx.y * 128;
    const int nt = blockIdx.y;
    const int wm = (wv & 1) * 64, wn = (wv >> 1) * 64;
    const int r16 = lane >> 2;
    const int gsw = ((lane & 3) ^ (r16 & 3)) << 3;
    const int fr = lane & 15;
    const int q = lane >> 4;

#define STG_HEAD(bufi, kt)                                                                \
    {                                                                                     \
        const int k0s = (kt) << 5;                                                        \
        _Pragma("unroll")                                                                 \
        for (int j = 0; j < 2; ++j) {                                                     \
            const int rr = (wv << 5) + (j << 4);                                          \
            const int gr = rr + r16;                                                      \
            const short* ga = Ah + (size_t)(m0 + gr) * K + k0s + gsw;                     \
            const short* gb = Bh + (size_t)(n0 + gr) * K + k0s + gsw;                     \
            __builtin_amdgcn_global_load_lds(                                             \
                (const __attribute__((address_space(1))) void*)ga,                        \
                (__attribute__((address_space(3))) void*)(sm + (bufi) * 8192 + rr * 32),  \
                16, 0, 0);                                                                \
            __builtin_amdgcn_global_load_lds(                                             \
                (const __attribute__((address_space(1))) void*)gb,                        \
                (__attribute__((address_space(3))) void*)(sm + (bufi) * 8192 + 4096 + rr * 32), \
                16, 0, 0);                                                                \
        }                                                                                 \
    }

    f32x4 acc[4][4];
#pragma unroll
    for (int i = 0; i < 4; ++i)
#pragma unroll
        for (int j = 0; j < 4; ++j)
            acc[i][j] = (f32x4){0.0f, 0.0f, 0.0f, 0.0f};

    const int NKT = K >> 5;  // 16
    STG_HEAD(0, 0)
    STG_HEAD(1, 1)

    for (int t = 0; t < NKT; ++t) {
        if (t < NKT - 1) {
            asm volatile("s_waitcnt vmcnt(4)" ::: "memory");
        } else {
            asm volatile("s_waitcnt vmcnt(0)" ::: "memory");
        }
        __builtin_amdgcn_sched_barrier(0);
        __builtin_amdgcn_s_barrier();
        const int buf = t & 1;
        const short* pA = sm + buf * 8192;
        const short* pB = pA + 4096;
        __builtin_amdgcn_s_setprio(1);
        short8_t ah[4], bh[4];
        const int swa = (q ^ (fr & 3)) << 3;
#pragma unroll
        for (int i = 0; i < 4; ++i) {
            ah[i] = *(const short8_t*)&pA[(wm + i * 16 + fr) * 32 + swa];
            bh[i] = *(const short8_t*)&pB[(wn + i * 16 + fr) * 32 + swa];
        }
#pragma unroll
        for (int i = 0; i < 4; ++i)
#pragma unroll
            for (int j = 0; j < 4; ++j)
                acc[i][j] = __builtin_amdgcn_mfma_f32_16x16x32_bf16(ah[i], bh[j], acc[i][j], 0, 0, 0);
        __builtin_amdgcn_s_setprio(0);
        asm volatile("s_waitcnt lgkmcnt(0)" ::: "memory");
        __builtin_amdgcn_sched_barrier(0);
        __builtin_amdgcn_s_barrier();
        if (t + 2 < NKT) {
            STG_HEAD(buf, t + 2)
        }
    }
#undef STG_HEAD

    const int hi = lane >> 4;
    const int row_base = hi << 2;
    // conf partials (no barrier, no LDS): per (i,r) row, reduce over 16 lanes x 4 j
#pragma unroll
    for (int i = 0; i < 4; ++i)
#pragma unroll
        for (int r = 0; r < 4; ++r) {
            float v0 = acc[i][0][r], v1 = acc[i][1][r];
            float v2 = acc[i][2][r], v3 = acc[i][3][r];
            float mg = fmaxf(fmaxf(v0, v1), fmaxf(v2, v3));
#pragma unroll
            for (int o = 1; o < 16; o <<= 1) mg = fmaxf(mg, __shfl_xor(mg, o, 64));
            float sg = __expf(v0 - mg) + __expf(v1 - mg) + __expf(v2 - mg) + __expf(v3 - mg);
#pragma unroll
            for (int o = 1; o < 16; o <<= 1) sg += __shfl_xor(sg, o, 64);
            if (fr == 0)
                pp[(size_t)(m0 + wm + i * 16 + hi * 4 + r) * NGRP + nt * 2 + (wn >> 6)] =
                    make_float2(mg, sg);
        }
    // C stores last: fire and retire
#pragma unroll
    for (int i = 0; i < 4; ++i)
#pragma unroll
        for (int j = 0; j < 4; ++j) {
            const int row = m0 + wm + i * 16 + row_base;
            const int col = n0 + wn + j * 16 + fr;
#pragma unroll
            for (int r = 0; r < 4; ++r)
                C[(size_t)(row + r) * N + col] = acc[i][j][r];
        }
}

// -------------------- conf reduce over head partials (one wave per token) ---------
__global__ __launch_bounds__(256) void conf_reduce(const float2* __restrict__ pp,
                                                   int* __restrict__ flags, float thr) {
    int wv = threadIdx.x >> 6, lane = threadIdx.x & 63;
    int t = blockIdx.x * 4 + wv;
    float m = -INFINITY, s = 0.0f;
    for (int k = lane; k < NGRP; k += 64) {
        float2 v = pp[(size_t)t * NGRP + k];
        float mm = fmaxf(m, v.x);
        s = s * __expf(m - mm) + v.y * __expf(v.x - mm);
        m = mm;
    }
#pragma unroll
    for (int o = 1; o < 64; o <<= 1) {
        float mo = __shfl_xor(m, o, 64);
        float so = __shfl_xor(s, o, 64);
        float mm = fmaxf(m, mo);
        s = s * __expf(m - mm) + so * __expf(mo - mm);
        m = mm;
    }
    if (lane == 0) {
        float conf = 1.0f / s;
        if (conf > thr) flags[t] = 0;
    }
}

// -------------------- fp32 tiled GEMM (tier 2/3 dense block-0 path) --------------------
template<bool ADD, bool GELU>
__global__ __launch_bounds__(256) void gemm_nn(const float* __restrict__ A,
                                               const float* __restrict__ B,
                                               float* __restrict__ C,
                                               int M, int N, int K) {
    const int m0 = blockIdx.y * 64, n0 = blockIdx.x * 64;
    __shared__ float As[16][68];
    __shared__ float Bs[16][68];
    const int tid = threadIdx.x;
    const int am = tid >> 2, ak = (tid & 3) << 2;
    const int bk = tid >> 4, bn = (tid & 15) << 2;
    const int tn = tid & 15, tm = tid >> 4;
    float acc[4][4] = {};
    for (int k0 = 0; k0 < K; k0 += 16) {
        float4 a4 = *(const float4*)&A[(size_t)(m0 + am) * K + k0 + ak];
        float4 b4 = *(const float4*)&B[(size_t)(k0 + bk) * N + n0 + bn];
        __syncthreads();
        As[ak + 0][am] = a4.x;
        As[ak + 1][am] = a4.y;
        As[ak + 2][am] = a4.z;
        As[ak + 3][am] = a4.w;
        *(float4*)&Bs[bk][bn] = b4;
        __syncthreads();
#pragma unroll
        for (int kk = 0; kk < 16; ++kk) {
            float4 av = *(const float4*)&As[kk][tm << 2];
            float4 bv = *(const float4*)&Bs[kk][tn << 2];
            float a[4] = {av.x, av.y, av.z, av.w};
            float b[4] = {bv.x, bv.y, bv.z, bv.w};
#pragma unroll
            for (int i = 0; i < 4; ++i)
#pragma unroll
                for (int j = 0; j < 4; ++j)
                    acc[i][j] = fmaf(a[i], b[j], acc[i][j]);
        }
    }
#pragma unroll
    for (int i = 0; i < 4; ++i) {
        size_t row = (size_t)(m0 + (tm << 2) + i);
        float* cp = &C[row * (size_t)N + n0 + (tn << 2)];
        float rr[4] = {acc[i][0], acc[i][1], acc[i][2], acc[i][3]};
        if (GELU) {
#pragma unroll
            for (int j = 0; j < 4; ++j) rr[j] = gelu_f(rr[j]);
        }
        if (ADD) {
            float4 cc = *(const float4*)cp;
            rr[0] += cc.x; rr[1] += cc.y; rr[2] += cc.z; rr[3] += cc.w;
        }
        float4 rv = {rr[0], rr[1], rr[2], rr[3]};
        *(float4*)cp = rv;
    }
}

// -------------------- grid-stride fp32 GEMM over compacted rows (blocks 1-2) ----------
template<bool ADD, bool GELU, bool SCAT>
__global__ __launch_bounds__(256) void gemm_nn_gs(const float* __restrict__ A,
                                                  const float* __restrict__ B,
                                                  float* __restrict__ C,
                                                  int N, int K,
                                                  const int* __restrict__ idx,
                                                  const int* __restrict__ cnt) {
    const int c = *cnt;
    const int ntm = (c + 63) >> 6;
    const int ntn = N >> 6;
    const int total = ntm * ntn;
    __shared__ float As[16][68];
    __shared__ float Bs[16][68];
    const int tid = threadIdx.x;
    const int am = tid >> 2, ak = (tid & 3) << 2;
    const int bk = tid >> 4, bn = (tid & 15) << 2;
    const int tn = tid & 15, tm = tid >> 4;
    for (int tile = blockIdx.x; tile < total; tile += gridDim.x) {
        const int m0 = (tile % ntm) << 6, n0 = (tile / ntm) << 6;
        int ar = m0 + am;
        ar = ar < c ? ar : c - 1;
        float acc[4][4] = {};
        for (int k0 = 0; k0 < K; k0 += 16) {
            float4 a4 = *(const float4*)&A[(size_t)ar * K + k0 + ak];
            float4 b4 = *(const float4*)&B[(size_t)(k0 + bk) * N + n0 + bn];
            __syncthreads();
            As[ak + 0][am] = a4.x;
            As[ak + 1][am] = a4.y;
            As[ak + 2][am] = a4.z;
            As[ak + 3][am] = a4.w;
            *(float4*)&Bs[bk][bn] = b4;
            __syncthreads();
#pragma unroll
            for (int kk = 0; kk < 16; ++kk) {
                float4 av = *(const float4*)&As[kk][tm << 2];
                float4 bv = *(const float4*)&Bs[kk][tn << 2];
                float a[4] = {av.x, av.y, av.z, av.w};
                float b[4] = {bv.x, bv.y, bv.z, bv.w};
#pragma unroll
                for (int i = 0; i < 4; ++i)
#pragma unroll
                    for (int j = 0; j < 4; ++j)
                        acc[i][j] = fmaf(a[i], b[j], acc[i][j]);
            }
        }
#pragma unroll
        for (int i = 0; i < 4; ++i) {
            int p = m0 + (tm << 2) + i;
            if (p >= c) continue;
            int r = SCAT ? idx[p] : p;
            float* cp = &C[(size_t)r * N + n0 + (tn << 2)];
            float rr[4] = {acc[i][0], acc[i][1], acc[i][2], acc[i][3]};
            if (GELU) {
#pragma unroll
                for (int j = 0; j < 4; ++j) rr[j] = gelu_f(rr[j]);
            }
            if (ADD) {
                float4 cc = *(const float4*)cp;
                rr[0] += cc.x; rr[1] += cc.y; rr[2] += cc.z; rr[3] += cc.w;
            }
            float4 rv = {rr[0], rr[1], rr[2], rr[3]};
            *(float4*)cp = rv;
        }
        __syncthreads();
    }
}

// -------------------- grid-stride fp32 head GEMM over compacted rows (blocks 1-2) -----
__global__ __launch_bounds__(256) void gemm_nt_head_gs(const float* __restrict__ A,
                                                       const float* __restrict__ Bt,
                                                       float* __restrict__ C,
                                                       const int* __restrict__ idx,
                                                       const int* __restrict__ cnt) {
    const int c = *cnt;
    const int ntm = (c + 63) >> 6;
    const int ntn = NVOCAB >> 6;
    const int total = ntm * ntn;
    __shared__ float As[16][68];
    __shared__ float Bs[16][68];
    const int tid = threadIdx.x;
    const int am = tid >> 2, ak = (tid & 3) << 2;
    const int tn = tid & 15, tm = tid >> 4;
    for (int tile = blockIdx.x; tile < total; tile += gridDim.x) {
        const int m0 = (tile % ntm) << 6, n0 = (tile / ntm) << 6;
        int ap = m0 + am;
        int ar = idx[ap < c ? ap : c - 1];
        float acc[4][4] = {};
        for (int k0 = 0; k0 < DIM; k0 += 16) {
            float4 a4 = *(const float4*)&A[(size_t)ar * DIM + k0 + ak];
            float4 b4 = *(const float4*)&Bt[(size_t)(n0 + am) * DIM + k0 + ak];
            __syncthreads();
            As[ak + 0][am] = a4.x;
            As[ak + 1][am] = a4.y;
            As[ak + 2][am] = a4.z;
            As[ak + 3][am] = a4.w;
            Bs[ak + 0][am] = b4.x;
            Bs[ak + 1][am] = b4.y;
            Bs[ak + 2][am] = b4.z;
            Bs[ak + 3][am] = b4.w;
            __syncthreads();
#pragma unroll
            for (int kk = 0; kk < 16; ++kk) {
                float4 av = *(const float4*)&As[kk][tm << 2];
                float4 bv = *(const float4*)&Bs[kk][tn << 2];
                float a[4] = {av.x, av.y, av.z, av.w};
                float b[4] = {bv.x, bv.y, bv.z, bv.w};
#pragma unroll
                for (int i = 0; i < 4; ++i)
#pragma unroll
                    for (int j = 0; j < 4; ++j)
                        acc[i][j] = fmaf(a[i], b[j], acc[i][j]);
            }
        }
#pragma unroll
        for (int i = 0; i < 4; ++i) {
            int p = m0 + (tm << 2) + i;
            if (p >= c) continue;
            int r = idx[p];
            float4 rv = {acc[i][0], acc[i][1], acc[i][2], acc[i][3]};
            *(float4*)&C[(size_t)r * NVOCAB + n0 + (tn << 2)] = rv;
        }
        __syncthreads();
    }
}

// -------------------- confidence + exit (vectorized full-row read) --------------------
template<bool IDX>
__global__ __launch_bounds__(256) void conf_exit(const float* __restrict__ out,
                                                 int* __restrict__ flags,
                                                 const int* __restrict__ idx,
                                                 const int* __restrict__ cnt,
                                                 float thr) {
    int t;
    if (IDX) {
        if (blockIdx.x >= *cnt) return;
        t = idx[blockIdx.x];
    } else {
        t = blockIdx.x;
        if (flags[t] == 0) return;
    }
    const float4* row = (const float4*)(out + (size_t)t * NVOCAB);
    float m = -INFINITY, s = 0.0f;
    for (int i = threadIdx.x; i < NVOCAB / 4; i += 256) {
        float4 v = row[i];
        float m4 = fmaxf(fmaxf(v.x, v.y), fmaxf(v.z, v.w));
        float s4 = __expf(v.x - m4) + __expf(v.y - m4) + __expf(v.z - m4) + __expf(v.w - m4);
        if (m4 > m) {
            s = s * __expf(m - m4) + s4;
            m = m4;
        } else {
            s += s4 * __expf(m4 - m);
        }
    }
    __shared__ float ms[256], ss[256];
    ms[threadIdx.x] = m;
    ss[threadIdx.x] = s;
    __syncthreads();
    for (int st = 128; st; st >>= 1) {
        if (threadIdx.x < st) {
            float m1 = ms[threadIdx.x], s1 = ss[threadIdx.x];
            float m2 = ms[threadIdx.x + st], s2 = ss[threadIdx.x + st];
            float mm = fmaxf(m1, m2);
            ss[threadIdx.x] = s1 * __expf(m1 - mm) + s2 * __expf(m2 - mm);
            ms[threadIdx.x] = mm;
        }
        __syncthreads();
    }
    if (threadIdx.x == 0) {
        float conf = 1.0f / ss[0];
        if (conf > thr) flags[t] = 0;
    }
}

// -------------------- ordered compaction of active tokens (single block) --------------------
__global__ __launch_bounds__(256) void compact_kernel(const int* __restrict__ flags,
                                                      int* __restrict__ idx,
                                                      int* __restrict__ cnt) {
    __shared__ int wsum[4];
    __shared__ int base;
    if (threadIdx.x == 0) base = 0;
    int lane = threadIdx.x & 63, wv = threadIdx.x >> 6;
    for (int chunk = 0; chunk < TT; chunk += 256) {
        __syncthreads();
        int t = chunk + threadIdx.x;
        int f = flags[t];
        unsigned long long b = __ballot(f != 0);
        if (lane == 0) wsum[wv] = __popcll(b);
        __syncthreads();
        int off = base;
        for (int w = 0; w < wv; ++w) off += wsum[w];
        off += __popcll(b & ((1ull << lane) - 1));
        if (f) idx[off] = t;
        __syncthreads();
        if (threadIdx.x == 0) base += wsum[0] + wsum[1] + wsum[2] + wsum[3];
    }
    __syncthreads();
    if (threadIdx.x == 0) *cnt = base;
}

extern "C" void kernel_launch(void* const* d_in, const int* in_sizes, int n_in,
                              void* d_out, int out_size, void* d_ws, size_t ws_size,
                              hipStream_t stream) {
    const int* x = (const int*)d_in[0];
    const float* emb = (const float*)d_in[1];
    const float* head = (const float*)d_in[2];
    const float* Wv = (const float*)d_in[3];
    const float* Wo = (const float*)d_in[4];
    const float* W1 = (const float*)d_in[5];
    const float* W2 = (const float*)d_in[6];
    const float* ln1s = (const float*)d_in[7];
    const float* ln1b = (const float*)d_in[8];
    const float* ln2s = (const float*)d_in[9];
    const float* ln2b = (const float*)d_in[10];
    float* out = (float*)d_out;
    float* ws = (float*)d_ws;

    float* h  = ws;                      // TT*DIM fp32
    float* hn = ws + 2097152;            // TT*DIM
    float* tA = ws + 4194304;            // TT*DIM (scratch: WvFlat hi/lo during setup)
    float* tF = ws + 6291456;            // TT*FFN
    short* hnHi = (short*)hn;
    short* hnLo = hnHi + TT * DIM;
    short* tAHi = (short*)tA;
    short* tALo = tAHi + TT * DIM;
    short* tFHi = (short*)tF;
    short* tFLo = tFHi + TT * FFN;
    float2* pp = (float2*)tF;            // conf partials alias tF region
    int* flags = (int*)(ws + 14680064);  // TT
    int* idxl  = flags + TT;             // TT
    int* cntp  = flags + 2 * TT;         // 1
    short* hHi    = (short*)(ws + 14700000);
    short* hLo    = (short*)(ws + 15748576);
    short* headHi = (short*)(ws + 16797152);
    short* headLo = (short*)(ws + 24989152);
    short* wT     = (short*)(ws + 33181152);  // 2 layers x 5242880 shorts
    const size_t LSTRIDE = 5242880;
    const size_t NEED_T2 = (size_t)33181152 * 4;
    const size_t NEED_T1 = (size_t)38424032 * 4;
    const int tier = ws_size >= NEED_T1 ? 1 : (ws_size >= NEED_T2 ? 2 : 3);

    gather_kernel<<<TT, 128, 0, stream>>>(x, emb, h, flags);

    const float THR[3] = {3.5e-05f, 4.0e-05f, 1.0f};
    const dim3 gDD(DIM / 64, TT / 64), gDF(FFN / 64, TT / 64), gHead(NVOCAB / 64, TT / 64);

    // ---------- block 0: dense ----------
    if (tier == 1) {
        // weight prep: transpose-splits; W_voT = WoT @ WvFlat (3-product MFMA)
        for (int l = 0; l < 2; ++l) {
            short* wb = wT + (size_t)l * LSTRIDE;
            cvt_hilo<<<(DIM * DIM / 4 + 255) / 256, 256, 0, stream>>>(Wv + (size_t)l * DIM * DIM, tAHi, tALo, DIM * DIM / 4);
            cvt_w_t<<<dim3(DIM / 32, DIM / 32), 256, 0, stream>>>(Wo + (size_t)l * DIM * DIM, wb + 524288, wb + 786432, DIM, DIM);
            gemm_l64<0><<<dim3(DIM / 64, DIM / 128), 256, 0, stream>>>(
                wb + 524288, wb + 786432, tAHi, tALo, nullptr, wb, wb + 262144, DIM, DIM);
            cvt_w_t_hi<<<dim3(FFN / 32, DIM / 32), 256, 0, stream>>>(W1 + (size_t)l * DIM * FFN, wb + 1048576, DIM, FFN);
            cvt_w_t_hi<<<dim3(DIM / 32, FFN / 32), 256, 0, stream>>>(W2 + (size_t)l * FFN * DIM, wb + 3145728, FFN, DIM);
        }
        for (int l = 0; l < 2; ++l) {
            short* wb = wT + (size_t)l * LSTRIDE;
            ln_hilo<<<TT / 4, 256, 0, stream>>>(h, ln1s + l * DIM, ln1b + l * DIM, hnHi, hnLo);
            gemm_l64b<2><<<dim3(TT / 64, DIM / 128), 256, 0, stream>>>(hnHi, hnLo, wb, h, nullptr, nullptr, DIM, DIM);
            ln_hilo<<<TT / 4, 256, 0, stream>>>(h, ln2s + l * DIM, ln2b + l * DIM, hnHi, hnLo);
            gemm_l2<1><<<dim3(TT / 128, FFN / 128), 256, 0, stream>>>(hnHi, hnLo, wb + 1048576, nullptr, tFHi, tFLo, FFN, DIM);
            if (l == 1) {
                gemm_l64b<4><<<dim3(TT / 64, DIM / 128), 256, 0, stream>>>(tFHi, tFLo, wb + 3145728, h, hHi, hLo, DIM, FFN);
            } else {
                gemm_l64b<2><<<dim3(TT / 64, DIM / 128), 256, 0, stream>>>(tFHi, tFLo, wb + 3145728, h, nullptr, nullptr, DIM, FFN);
            }
        }
        cvt_bf16<<<(NVOCAB * DIM / 4 + 255) / 256, 256, 0, stream>>>(head, headHi, NVOCAB * DIM / 4);
        gemm_head_bf16<<<dim3(TT / 128, NVOCAB / 128), 256, 0, stream>>>(hHi, headHi, out, pp, NVOCAB, DIM);
        conf_reduce<<<TT / 4, 256, 0, stream>>>(pp, flags, THR[0]);
    } else {
        for (int l = 0; l < 2; ++l) {
            ln_kernel<false><<<TT / 4, 256, 0, stream>>>(h, ln1s + l * DIM, ln1b + l * DIM, hn, nullptr, nullptr);
            gemm_nn<false, false><<<gDD, 256, 0, stream>>>(hn, Wv + (size_t)l * DIM * DIM, tA, TT, DIM, DIM);
            gemm_nn<true, false><<<gDD, 256, 0, stream>>>(tA, Wo + (size_t)l * DIM * DIM, h, TT, DIM, DIM);
            ln_kernel<false><<<TT / 4, 256, 0, stream>>>(h, ln2s + l * DIM, ln2b + l * DIM, hn, nullptr, nullptr);
            gemm_nn<false, true><<<gDF, 256, 0, stream>>>(hn, W1 + (size_t)l * DIM * FFN, tF, TT, FFN, DIM);
            gemm_nn<true, false><<<gDD, 256, 0, stream>>>(tF, W2 + (size_t)l * FFN * DIM, h, TT, DIM, FFN);
        }
        if (tier == 2) {
            cvt_hilo<<<(TT * DIM / 4 + 255) / 256, 256, 0, stream>>>(h, hHi, hLo, TT * DIM / 4);
            cvt_hilo<<<(NVOCAB * DIM / 4 + 255) / 256, 256, 0, stream>>>(head, headHi, headLo, NVOCAB * DIM / 4);
            gemm_l_mfma<3><<<dim3(TT / 128, NVOCAB / 128), 256, 0, stream>>>(hHi, hLo, headHi, headLo, out, nullptr, nullptr, NVOCAB, DIM);
        } else {
            compact_kernel<<<1, 256, 0, stream>>>(flags, idxl, cntp);
            gemm_nt_head_gs<<<512, 256, 0, stream>>>(h, head, out, idxl, cntp);
        }
        conf_exit<false><<<TT, 256, 0, stream>>>(out, flags, nullptr, nullptr, THR[0]);
    }
    compact_kernel<<<1, 256, 0, stream>>>(flags, idxl, cntp);

    // ---------- blocks 1,2: compacted active rows (grid-stride fp32 path; ~empty) ----------
    for (int b = 1; b < 3; ++b) {
        for (int li = 0; li < 2; ++li) {
            int l = b * 2 + li;
            ln_kernel<true><<<TT / 4, 256, 0, stream>>>(h, ln1s + l * DIM, ln1b + l * DIM, hn, idxl, cntp);
            gemm_nn_gs<false, false, false><<<256, 256, 0, stream>>>(hn, Wv + (size_t)l * DIM * DIM, tA, DIM, DIM, idxl, cntp);
            gemm_nn_gs<true, false, true><<<256, 256, 0, stream>>>(tA, Wo + (size_t)l * DIM * DIM, h, DIM, DIM, idxl, cntp);
            ln_kernel<true><<<TT / 4, 256, 0, stream>>>(h, ln2s + l * DIM, ln2b + l * DIM, hn, idxl, cntp);
            gemm_nn_gs<false, true, false><<<256, 256, 0, stream>>>(hn, W1 + (size_t)l * DIM * FFN, tF, FFN, DIM, idxl, cntp);
            gemm_nn_gs<true, false, true><<<256, 256, 0, stream>>>(tF, W2 + (size_t)l * FFN * DIM, h, DIM, FFN, idxl, cntp);
        }
        gemm_nt_head_gs<<<512, 256, 0, stream>>>(h, head, out, idxl, cntp);
        if (b == 1) {
            conf_exit<true><<<TT, 256, 0, stream>>>(out, flags, idxl, cntp, THR[1]);
            compact_kernel<<<1, 256, 0, stream>>>(flags, idxl, cntp);
        }
    }
}

// Round 15
// 653.643 us; speedup vs baseline: 1.6404x; 1.0088x over previous
//
#include <hip/hip_runtime.h>
#include <hip/hip_bf16.h>
#include <math.h>

#define TT 4096
#define DIM 512
#define FFN 2048
#define NVOCAB 32000
#define NGRP 500   // conf partial groups per token (250 n-tiles x 2 wave strips)

typedef __attribute__((ext_vector_type(8))) short short8_t;
typedef __attribute__((ext_vector_type(4))) float f32x4;

__device__ __forceinline__ float gelu_f(float x) {
    float x3 = x * x * x;
    float u = 0.7978845608028654f * (x + 0.044715f * x3);
    return 0.5f * x * (1.0f + tanhf(u));
}

__device__ __forceinline__ unsigned short f2bf_rn(float f) {
    unsigned u = __float_as_uint(f);
    u += 0x7FFFu + ((u >> 16) & 1u);
    return (unsigned short)(u >> 16);
}

// -------------------- embedding gather + flag init --------------------
__global__ __launch_bounds__(128) void gather_kernel(const int* __restrict__ x,
                                                     const float* __restrict__ emb,
                                                     float* __restrict__ h,
                                                     int* __restrict__ flags) {
    int t = blockIdx.x;
    int idx = x[t];
    const float4 v = *(const float4*)&emb[(size_t)idx * DIM + threadIdx.x * 4];
    *(float4*)&h[(size_t)t * DIM + threadIdx.x * 4] = v;
    if (threadIdx.x == 0) flags[t] = 1;
}

// -------------------- fp32 -> bf16 hi/lo split (flat) --------------------
__global__ __launch_bounds__(256) void cvt_hilo(const float* __restrict__ src,
                                                short* __restrict__ hi,
                                                short* __restrict__ lo, int n4) {
    int i = blockIdx.x * 256 + threadIdx.x;
    if (i >= n4) return;
    float4 v = *(const float4*)&src[(size_t)i * 4];
    float f[4] = {v.x, v.y, v.z, v.w};
    short4 hv, lv;
    short* hp = &hv.x;
    short* lp = &lv.x;
#pragma unroll
    for (int j = 0; j < 4; ++j) {
        unsigned short hb = f2bf_rn(f[j]);
        float hf = __uint_as_float((unsigned)hb << 16);
        unsigned short lb = f2bf_rn(f[j] - hf);
        hp[j] = (short)hb;
        lp[j] = (short)lb;
    }
    *(short4*)&hi[(size_t)i * 4] = hv;
    *(short4*)&lo[(size_t)i * 4] = lv;
}

// -------------------- fp32 -> bf16 (hi only, flat) --------------------
__global__ __launch_bounds__(256) void cvt_bf16(const float* __restrict__ src,
                                                short* __restrict__ hi, int n4) {
    int i = blockIdx.x * 256 + threadIdx.x;
    if (i >= n4) return;
    float4 v = *(const float4*)&src[(size_t)i * 4];
    float f[4] = {v.x, v.y, v.z, v.w};
    short4 hv;
    short* hp = &hv.x;
#pragma unroll
    for (int j = 0; j < 4; ++j) hp[j] = (short)f2bf_rn(f[j]);
    *(short4*)&hi[(size_t)i * 4] = hv;
}

// -------------------- fp32 W (K,N) -> bf16 hi/lo transposed (N,K) --------------------
__global__ __launch_bounds__(256) void cvt_w_t(const float* __restrict__ W,
                                               short* __restrict__ hiT,
                                               short* __restrict__ loT,
                                               int K, int N) {
    __shared__ short hs[32][36];
    __shared__ short ls[32][36];
    const int n0 = blockIdx.x * 32, k0 = blockIdx.y * 32;
    const int r = threadIdx.x >> 3, c4 = (threadIdx.x & 7) << 2;
    float4 v = *(const float4*)&W[(size_t)(k0 + r) * N + n0 + c4];
    float f[4] = {v.x, v.y, v.z, v.w};
#pragma unroll
    for (int j = 0; j < 4; ++j) {
        unsigned short hb = f2bf_rn(f[j]);
        float hf = __uint_as_float((unsigned)hb << 16);
        unsigned short lb = f2bf_rn(f[j] - hf);
        hs[r][c4 + j] = (short)hb;
        ls[r][c4 + j] = (short)lb;
    }
    __syncthreads();
    const int nr = threadIdx.x >> 3, kc4 = (threadIdx.x & 7) << 2;
    short4 hv, lv;
    short* hp = &hv.x;
    short* lp = &lv.x;
#pragma unroll
    for (int j = 0; j < 4; ++j) {
        hp[j] = hs[kc4 + j][nr];
        lp[j] = ls[kc4 + j][nr];
    }
    *(short4*)&hiT[(size_t)(n0 + nr) * K + k0 + kc4] = hv;
    *(short4*)&loT[(size_t)(n0 + nr) * K + k0 + kc4] = lv;
}

// -------------------- fp32 W (K,N) -> bf16 hi transposed only --------------------
__global__ __launch_bounds__(256) void cvt_w_t_hi(const float* __restrict__ W,
                                                  short* __restrict__ hiT,
                                                  int K, int N) {
    __shared__ short hs[32][36];
    const int n0 = blockIdx.x * 32, k0 = blockIdx.y * 32;
    const int r = threadIdx.x >> 3, c4 = (threadIdx.x & 7) << 2;
    float4 v = *(const float4*)&W[(size_t)(k0 + r) * N + n0 + c4];
    float f[4] = {v.x, v.y, v.z, v.w};
#pragma unroll
    for (int j = 0; j < 4; ++j) hs[r][c4 + j] = (short)f2bf_rn(f[j]);
    __syncthreads();
    const int nr = threadIdx.x >> 3, kc4 = (threadIdx.x & 7) << 2;
    short4 hv;
    short* hp = &hv.x;
#pragma unroll
    for (int j = 0; j < 4; ++j) hp[j] = hs[kc4 + j][nr];
    *(short4*)&hiT[(size_t)(n0 + nr) * K + k0 + kc4] = hv;
}

// -------------------- LayerNorm (fp32 out; optional index gather) --------------------
template<bool IDX>
__global__ __launch_bounds__(256) void ln_kernel(const float* __restrict__ x,
                                                 const float* __restrict__ gam,
                                                 const float* __restrict__ bet,
                                                 float* __restrict__ out,
                                                 const int* __restrict__ idx,
                                                 const int* __restrict__ cnt) {
    int wv = threadIdx.x >> 6, lane = threadIdx.x & 63;
    int p = (blockIdx.x << 2) | wv;
    if (IDX && p >= *cnt) return;
    int t = IDX ? idx[p] : p;
    const float* row = x + (size_t)t * DIM;
    int base = lane * 8;
    float4 v0 = *(const float4*)&row[base];
    float4 v1 = *(const float4*)&row[base + 4];
    float s = v0.x + v0.y + v0.z + v0.w + v1.x + v1.y + v1.z + v1.w;
#pragma unroll
    for (int o = 32; o; o >>= 1) s += __shfl_xor(s, o, 64);
    float mean = s * (1.0f / (float)DIM);
    float d0 = v0.x - mean, d1 = v0.y - mean, d2 = v0.z - mean, d3 = v0.w - mean;
    float d4 = v1.x - mean, d5 = v1.y - mean, d6 = v1.z - mean, d7 = v1.w - mean;
    float q = d0*d0 + d1*d1 + d2*d2 + d3*d3 + d4*d4 + d5*d5 + d6*d6 + d7*d7;
#pragma unroll
    for (int o = 32; o; o >>= 1) q += __shfl_xor(q, o, 64);
    float var = q * (1.0f / (float)DIM);
    float rs = 1.0f / sqrtf(var + 1e-5f);
    float4 g0 = *(const float4*)&gam[base];
    float4 g1 = *(const float4*)&gam[base + 4];
    float4 b0 = *(const float4*)&bet[base];
    float4 b1 = *(const float4*)&bet[base + 4];
    float4 o0, o1;
    o0.x = d0 * rs * g0.x + b0.x;  o0.y = d1 * rs * g0.y + b0.y;
    o0.z = d2 * rs * g0.z + b0.z;  o0.w = d3 * rs * g0.w + b0.w;
    o1.x = d4 * rs * g1.x + b1.x;  o1.y = d5 * rs * g1.y + b1.y;
    o1.z = d6 * rs * g1.z + b1.z;  o1.w = d7 * rs * g1.w + b1.w;
    float* orow = out + (size_t)p * DIM;
    *(float4*)&orow[base] = o0;
    *(float4*)&orow[base + 4] = o1;
}

// -------------------- LayerNorm -> bf16 hi/lo (dense, block 0) --------------------
__global__ __launch_bounds__(256) void ln_hilo(const float* __restrict__ x,
                                               const float* __restrict__ gam,
                                               const float* __restrict__ bet,
                                               short* __restrict__ ohi,
                                               short* __restrict__ olo) {
    int wv = threadIdx.x >> 6, lane = threadIdx.x & 63;
    int t = (blockIdx.x << 2) | wv;
    const float* row = x + (size_t)t * DIM;
    int base = lane * 8;
    float4 v0 = *(const float4*)&row[base];
    float4 v1 = *(const float4*)&row[base + 4];
    float s = v0.x + v0.y + v0.z + v0.w + v1.x + v1.y + v1.z + v1.w;
#pragma unroll
    for (int o = 32; o; o >>= 1) s += __shfl_xor(s, o, 64);
    float mean = s * (1.0f / (float)DIM);
    float d[8] = {v0.x - mean, v0.y - mean, v0.z - mean, v0.w - mean,
                  v1.x - mean, v1.y - mean, v1.z - mean, v1.w - mean};
    float q = 0.0f;
#pragma unroll
    for (int j = 0; j < 8; ++j) q += d[j] * d[j];
#pragma unroll
    for (int o = 32; o; o >>= 1) q += __shfl_xor(q, o, 64);
    float var = q * (1.0f / (float)DIM);
    float rs = 1.0f / sqrtf(var + 1e-5f);
    float g[8], bb[8];
    *(float4*)&g[0] = *(const float4*)&gam[base];
    *(float4*)&g[4] = *(const float4*)&gam[base + 4];
    *(float4*)&bb[0] = *(const float4*)&bet[base];
    *(float4*)&bb[4] = *(const float4*)&bet[base + 4];
    short8_t hv, lv;
#pragma unroll
    for (int j = 0; j < 8; ++j) {
        float val = d[j] * rs * g[j] + bb[j];
        unsigned short hb = f2bf_rn(val);
        float hf = __uint_as_float((unsigned)hb << 16);
        hv[j] = (short)hb;
        lv[j] = (short)f2bf_rn(val - hf);
    }
    *(short8_t*)&ohi[(size_t)t * DIM + base] = hv;
    *(short8_t*)&olo[(size_t)t * DIM + base] = lv;
}

// ==================== EPILOGUE helper ====================
__device__ __forceinline__ void epi_store(int EPI, float val, size_t off,
                                          float* Cf, short* oHi, short* oLo) {
    if (EPI == 3) {
        Cf[off] = val;
    } else if (EPI == 2) {
        Cf[off] += val;
    } else if (EPI == 4) {
        float nv = Cf[off] + val;
        Cf[off] = nv;
        unsigned short hb = f2bf_rn(nv);
        float hf = __uint_as_float((unsigned)hb << 16);
        oHi[off] = (short)hb;
        oLo[off] = (short)f2bf_rn(nv - hf);
    } else {
        if (EPI == 1) val = gelu_f(val);
        unsigned short hb = f2bf_rn(val);
        float hf = __uint_as_float((unsigned)hb << 16);
        oHi[off] = (short)hb;
        oLo[off] = (short)f2bf_rn(val - hf);
    }
}

// -------------------- 3-product split-bf16 MFMA GEMM (128x128) --------------------
template<int EPI>
__global__ __launch_bounds__(256) void gemm_l_mfma(const short* __restrict__ Ah,
                                                   const short* __restrict__ Al,
                                                   const short* __restrict__ Bh,
                                                   const short* __restrict__ Bl,
                                                   float* __restrict__ Cf,
                                                   short* __restrict__ oHi,
                                                   short* __restrict__ oLo,
                                                   int N, int K) {
    __shared__ __align__(16) short sm[16384];
    short* sAh = sm;
    short* sAl = sm + 4096;
    short* sBh = sm + 8192;
    short* sBl = sm + 12288;
    const int tid = threadIdx.x;
    const int wv = tid >> 6, lane = tid & 63;
    const int m0 = blockIdx.x * 128;
    const int n0 = blockIdx.y * 128;
    const int wm = (wv & 1) * 64, wn = (wv >> 1) * 64;
    const int r16 = lane >> 2;
    const int gsw = ((lane & 3) ^ (r16 & 3)) << 3;
    const int fr = lane & 15;
    const int q = lane >> 4;

    f32x4 acc[4][4];
#pragma unroll
    for (int i = 0; i < 4; ++i)
#pragma unroll
        for (int j = 0; j < 4; ++j)
            acc[i][j] = (f32x4){0.0f, 0.0f, 0.0f, 0.0f};

    const int NKT = K >> 5;
    for (int kt = 0; kt < NKT; ++kt) {
        const int k0 = kt << 5;
        __syncthreads();
#pragma unroll
        for (int j = 0; j < 2; ++j) {
            const int rr = (wv << 5) + (j << 4);
            const int gr = rr + r16;
            const short* ga_h = Ah + (size_t)(m0 + gr) * K + k0 + gsw;
            const short* ga_l = Al + (size_t)(m0 + gr) * K + k0 + gsw;
            const short* gb_h = Bh + (size_t)(n0 + gr) * K + k0 + gsw;
            const short* gb_l = Bl + (size_t)(n0 + gr) * K + k0 + gsw;
            __builtin_amdgcn_global_load_lds((const __attribute__((address_space(1))) void*)ga_h,
                                             (__attribute__((address_space(3))) void*)(sAh + rr * 32), 16, 0, 0);
            __builtin_amdgcn_global_load_lds((const __attribute__((address_space(1))) void*)ga_l,
                                             (__attribute__((address_space(3))) void*)(sAl + rr * 32), 16, 0, 0);
            __builtin_amdgcn_global_load_lds((const __attribute__((address_space(1))) void*)gb_h,
                                             (__attribute__((address_space(3))) void*)(sBh + rr * 32), 16, 0, 0);
            __builtin_amdgcn_global_load_lds((const __attribute__((address_space(1))) void*)gb_l,
                                             (__attribute__((address_space(3))) void*)(sBl + rr * 32), 16, 0, 0);
        }
        __syncthreads();
        short8_t ah[4], al[4], bh[4], bl[4];
#pragma unroll
        for (int i = 0; i < 4; ++i) {
            const int ra = wm + i * 16 + fr;
            const int rb = wn + i * 16 + fr;
            const int swa = (q ^ (fr & 3)) << 3;
            ah[i] = *(const short8_t*)&sAh[ra * 32 + swa];
            al[i] = *(const short8_t*)&sAl[ra * 32 + swa];
            bh[i] = *(const short8_t*)&sBh[rb * 32 + swa];
            bl[i] = *(const short8_t*)&sBl[rb * 32 + swa];
        }
#pragma unroll
        for (int i = 0; i < 4; ++i)
#pragma unroll
            for (int j = 0; j < 4; ++j) {
                acc[i][j] = __builtin_amdgcn_mfma_f32_16x16x32_bf16(ah[i], bh[j], acc[i][j], 0, 0, 0);
                acc[i][j] = __builtin_amdgcn_mfma_f32_16x16x32_bf16(ah[i], bl[j], acc[i][j], 0, 0, 0);
                acc[i][j] = __builtin_amdgcn_mfma_f32_16x16x32_bf16(al[i], bh[j], acc[i][j], 0, 0, 0);
            }
    }
    const int row_base = (lane >> 4) << 2;
#pragma unroll
    for (int i = 0; i < 4; ++i)
#pragma unroll
        for (int j = 0; j < 4; ++j) {
            const int row = m0 + wm + i * 16 + row_base;
            const int col = n0 + wn + j * 16 + fr;
#pragma unroll
            for (int r = 0; r < 4; ++r)
                epi_store(EPI, acc[i][j][r], (size_t)(row + r) * N + col, Cf, oHi, oLo);
        }
}

// -------------------- 2-product GEMM (128x128): A hi/lo, B hi only --------------------
template<int EPI>
__global__ __launch_bounds__(256) void gemm_l2(const short* __restrict__ Ah,
                                               const short* __restrict__ Al,
                                               const short* __restrict__ Bh,
                                               float* __restrict__ Cf,
                                               short* __restrict__ oHi,
                                               short* __restrict__ oLo,
                                               int N, int K) {
    __shared__ __align__(16) short sm[12288];
    short* sAh = sm;
    short* sAl = sm + 4096;
    short* sBh = sm + 8192;
    const int tid = threadIdx.x;
    const int wv = tid >> 6, lane = tid & 63;
    const int m0 = blockIdx.x * 128;
    const int n0 = blockIdx.y * 128;
    const int wm = (wv & 1) * 64, wn = (wv >> 1) * 64;
    const int r16 = lane >> 2;
    const int gsw = ((lane & 3) ^ (r16 & 3)) << 3;
    const int fr = lane & 15;
    const int q = lane >> 4;

    f32x4 acc[4][4];
#pragma unroll
    for (int i = 0; i < 4; ++i)
#pragma unroll
        for (int j = 0; j < 4; ++j)
            acc[i][j] = (f32x4){0.0f, 0.0f, 0.0f, 0.0f};

    const int NKT = K >> 5;
    for (int kt = 0; kt < NKT; ++kt) {
        const int k0 = kt << 5;
        __syncthreads();
#pragma unroll
        for (int j = 0; j < 2; ++j) {
            const int rr = (wv << 5) + (j << 4);
            const int gr = rr + r16;
            const short* ga_h = Ah + (size_t)(m0 + gr) * K + k0 + gsw;
            const short* ga_l = Al + (size_t)(m0 + gr) * K + k0 + gsw;
            const short* gb_h = Bh + (size_t)(n0 + gr) * K + k0 + gsw;
            __builtin_amdgcn_global_load_lds((const __attribute__((address_space(1))) void*)ga_h,
                                             (__attribute__((address_space(3))) void*)(sAh + rr * 32), 16, 0, 0);
            __builtin_amdgcn_global_load_lds((const __attribute__((address_space(1))) void*)ga_l,
                                             (__attribute__((address_space(3))) void*)(sAl + rr * 32), 16, 0, 0);
            __builtin_amdgcn_global_load_lds((const __attribute__((address_space(1))) void*)gb_h,
                                             (__attribute__((address_space(3))) void*)(sBh + rr * 32), 16, 0, 0);
        }
        __syncthreads();
        short8_t ah[4], al[4], bh[4];
#pragma unroll
        for (int i = 0; i < 4; ++i) {
            const int ra = wm + i * 16 + fr;
            const int rb = wn + i * 16 + fr;
            const int swa = (q ^ (fr & 3)) << 3;
            ah[i] = *(const short8_t*)&sAh[ra * 32 + swa];
            al[i] = *(const short8_t*)&sAl[ra * 32 + swa];
            bh[i] = *(const short8_t*)&sBh[rb * 32 + swa];
        }
#pragma unroll
        for (int i = 0; i < 4; ++i)
#pragma unroll
            for (int j = 0; j < 4; ++j) {
                acc[i][j] = __builtin_amdgcn_mfma_f32_16x16x32_bf16(ah[i], bh[j], acc[i][j], 0, 0, 0);
                acc[i][j] = __builtin_amdgcn_mfma_f32_16x16x32_bf16(al[i], bh[j], acc[i][j], 0, 0, 0);
            }
    }
    const int row_base = (lane >> 4) << 2;
#pragma unroll
    for (int i = 0; i < 4; ++i)
#pragma unroll
        for (int j = 0; j < 4; ++j) {
            const int row = m0 + wm + i * 16 + row_base;
            const int col = n0 + wn + j * 16 + fr;
#pragma unroll
            for (int r = 0; r < 4; ++r)
                epi_store(EPI, acc[i][j][r], (size_t)(row + r) * N + col, Cf, oHi, oLo);
        }
}

// -------------------- 2-product GEMM (64x128): A hi/lo, B hi only --------------------
template<int EPI>
__global__ __launch_bounds__(256) void gemm_l64b(const short* __restrict__ Ah,
                                                 const short* __restrict__ Al,
                                                 const short* __restrict__ Bh,
                                                 float* __restrict__ Cf,
                                                 short* __restrict__ oHi,
                                                 short* __restrict__ oLo,
                                                 int N, int K) {
    __shared__ __align__(16) short sm[8192];
    short* sAh = sm;
    short* sAl = sm + 2048;
    short* sBh = sm + 4096;
    const int tid = threadIdx.x;
    const int wv = tid >> 6, lane = tid & 63;
    const int m0 = blockIdx.x * 64;
    const int n0 = blockIdx.y * 128;
    const int wm = (wv & 1) * 32, wn = (wv >> 1) * 64;
    const int r16 = lane >> 2;
    const int gsw = ((lane & 3) ^ (r16 & 3)) << 3;
    const int fr = lane & 15;
    const int q = lane >> 4;

    f32x4 acc[2][4];
#pragma unroll
    for (int i = 0; i < 2; ++i)
#pragma unroll
        for (int j = 0; j < 4; ++j)
            acc[i][j] = (f32x4){0.0f, 0.0f, 0.0f, 0.0f};

    const int NKT = K >> 5;
    for (int kt = 0; kt < NKT; ++kt) {
        const int k0 = kt << 5;
        __syncthreads();
        {
            const int rr = wv << 4;
            const int gr = rr + r16;
            const short* ga_h = Ah + (size_t)(m0 + gr) * K + k0 + gsw;
            const short* ga_l = Al + (size_t)(m0 + gr) * K + k0 + gsw;
            __builtin_amdgcn_global_load_lds((const __attribute__((address_space(1))) void*)ga_h,
                                             (__attribute__((address_space(3))) void*)(sAh + rr * 32), 16, 0, 0);
            __builtin_amdgcn_global_load_lds((const __attribute__((address_space(1))) void*)ga_l,
                                             (__attribute__((address_space(3))) void*)(sAl + rr * 32), 16, 0, 0);
        }
#pragma unroll
        for (int j = 0; j < 2; ++j) {
            const int rr = (wv << 5) + (j << 4);
            const int gr = rr + r16;
            const short* gb_h = Bh + (size_t)(n0 + gr) * K + k0 + gsw;
            __builtin_amdgcn_global_load_lds((const __attribute__((address_space(1))) void*)gb_h,
                                             (__attribute__((address_space(3))) void*)(sBh + rr * 32), 16, 0, 0);
        }
        __syncthreads();
        short8_t ah[2], al[2], bh[4];
        const int swa = (q ^ (fr & 3)) << 3;
#pragma unroll
        for (int i = 0; i < 2; ++i) {
            const int ra = wm + i * 16 + fr;
            ah[i] = *(const short8_t*)&sAh[ra * 32 + swa];
            al[i] = *(const short8_t*)&sAl[ra * 32 + swa];
        }
#pragma unroll
        for (int j = 0; j < 4; ++j) {
            const int rb = wn + j * 16 + fr;
            bh[j] = *(const short8_t*)&sBh[rb * 32 + swa];
        }
#pragma unroll
        for (int i = 0; i < 2; ++i)
#pragma unroll
            for (int j = 0; j < 4; ++j) {
                acc[i][j] = __builtin_amdgcn_mfma_f32_16x16x32_bf16(ah[i], bh[j], acc[i][j], 0, 0, 0);
                acc[i][j] = __builtin_amdgcn_mfma_f32_16x16x32_bf16(al[i], bh[j], acc[i][j], 0, 0, 0);
            }
    }
    const int row_base = (lane >> 4) << 2;
#pragma unroll
    for (int i = 0; i < 2; ++i)
#pragma unroll
        for (int j = 0; j < 4; ++j) {
            const int row = m0 + wm + i * 16 + row_base;
            const int col = n0 + wn + j * 16 + fr;
#pragma unroll
            for (int r = 0; r < 4; ++r)
                epi_store(EPI, acc[i][j][r], (size_t)(row + r) * N + col, Cf, oHi, oLo);
        }
}

// -------------------- 3-product GEMM (64x128) — W_vo prep only --------------------
template<int EPI>
__global__ __launch_bounds__(256) void gemm_l64(const short* __restrict__ Ah,
                                                const short* __restrict__ Al,
                                                const short* __restrict__ Bh,
                                                const short* __restrict__ Bl,
                                                float* __restrict__ Cf,
                                                short* __restrict__ oHi,
                                                short* __restrict__ oLo,
                                                int N, int K) {
    __shared__ __align__(16) short sm[12288];
    short* sAh = sm;
    short* sAl = sm + 2048;
    short* sBh = sm + 4096;
    short* sBl = sm + 8192;
    const int tid = threadIdx.x;
    const int wv = tid >> 6, lane = tid & 63;
    const int m0 = blockIdx.x * 64;
    const int n0 = blockIdx.y * 128;
    const int wm = (wv & 1) * 32, wn = (wv >> 1) * 64;
    const int r16 = lane >> 2;
    const int gsw = ((lane & 3) ^ (r16 & 3)) << 3;
    const int fr = lane & 15;
    const int q = lane >> 4;

    f32x4 acc[2][4];
#pragma unroll
    for (int i = 0; i < 2; ++i)
#pragma unroll
        for (int j = 0; j < 4; ++j)
            acc[i][j] = (f32x4){0.0f, 0.0f, 0.0f, 0.0f};

    const int NKT = K >> 5;
    for (int kt = 0; kt < NKT; ++kt) {
        const int k0 = kt << 5;
        __syncthreads();
        {
            const int rr = wv << 4;
            const int gr = rr + r16;
            const short* ga_h = Ah + (size_t)(m0 + gr) * K + k0 + gsw;
            const short* ga_l = Al + (size_t)(m0 + gr) * K + k0 + gsw;
            __builtin_amdgcn_global_load_lds((const __attribute__((address_space(1))) void*)ga_h,
                                             (__attribute__((address_space(3))) void*)(sAh + rr * 32), 16, 0, 0);
            __builtin_amdgcn_global_load_lds((const __attribute__((address_space(1))) void*)ga_l,
                                             (__attribute__((address_space(3))) void*)(sAl + rr * 32), 16, 0, 0);
        }
#pragma unroll
        for (int j = 0; j < 2; ++j) {
            const int rr = (wv << 5) + (j << 4);
            const int gr = rr + r16;
            const short* gb_h = Bh + (size_t)(n0 + gr) * K + k0 + gsw;
            const short* gb_l = Bl + (size_t)(n0 + gr) * K + k0 + gsw;
            __builtin_amdgcn_global_load_lds((const __attribute__((address_space(1))) void*)gb_h,
                                             (__attribute__((address_space(3))) void*)(sBh + rr * 32), 16, 0, 0);
            __builtin_amdgcn_global_load_lds((const __attribute__((address_space(1))) void*)gb_l,
                                             (__attribute__((address_space(3))) void*)(sBl + rr * 32), 16, 0, 0);
        }
        __syncthreads();
        short8_t ah[2], al[2], bh[4], bl[4];
        const int swa = (q ^ (fr & 3)) << 3;
#pragma unroll
        for (int i = 0; i < 2; ++i) {
            const int ra = wm + i * 16 + fr;
            ah[i] = *(const short8_t*)&sAh[ra * 32 + swa];
            al[i] = *(const short8_t*)&sAl[ra * 32 + swa];
        }
#pragma unroll
        for (int j = 0; j < 4; ++j) {
            const int rb = wn + j * 16 + fr;
            bh[j] = *(const short8_t*)&sBh[rb * 32 + swa];
            bl[j] = *(const short8_t*)&sBl[rb * 32 + swa];
        }
#pragma unroll
        for (int i = 0; i < 2; ++i)
#pragma unroll
            for (int j = 0; j < 4; ++j) {
                acc[i][j] = __builtin_amdgcn_mfma_f32_16x16x32_bf16(ah[i], bh[j], acc[i][j], 0, 0, 0);
                acc[i][j] = __builtin_amdgcn_mfma_f32_16x16x32_bf16(ah[i], bl[j], acc[i][j], 0, 0, 0);
                acc[i][j] = __builtin_amdgcn_mfma_f32_16x16x32_bf16(al[i], bh[j], acc[i][j], 0, 0, 0);
            }
    }
    const int row_base = (lane >> 4) << 2;
#pragma unroll
    for (int i = 0; i < 2; ++i)
#pragma unroll
        for (int j = 0; j < 4; ++j) {
            const int row = m0 + wm + i * 16 + row_base;
            const int col = n0 + wn + j * 16 + fr;
#pragma unroll
            for (int r = 0; r < 4; ++r)
                epi_store(EPI, acc[i][j][r], (size_t)(row + r) * N + col, Cf, oHi, oLo);
        }
}

// -------------------- PLAIN bf16 head GEMM: 3-deep ring counted-vmcnt pipeline --------
// Stage t,t+1,t+2 up front; per iter wait vmcnt(8) (oldest stage done; loads get ~2
// iterations to land) -> raw barrier -> ds_read+MFMA -> lgkmcnt(0)+sched_barrier ->
// barrier -> stage t+3 into just-freed buffer. Epilogue waits taper 8->4->0.
// Conf partials from acc (no LDS/barrier), C stores last.
__global__ __launch_bounds__(256) void gemm_head_bf16(const short* __restrict__ Ah,
                                                      const short* __restrict__ Bh,
                                                      float* __restrict__ C,
                                                      float2* __restrict__ pp,
                                                      int N, int K) {
    __shared__ __align__(16) short sm[24576];  // 3 buf x (A 4096 + B 4096)
    const int tid = threadIdx.x;
    const int wv = tid >> 6, lane = tid & 63;
    const int m0 = blockIdx.x * 128;
    const int n0 = blockIdx.y * 128;
    const int nt = blockIdx.y;
    const int wm = (wv & 1) * 64, wn = (wv >> 1) * 64;
    const int r16 = lane >> 2;
    const int gsw = ((lane & 3) ^ (r16 & 3)) << 3;
    const int fr = lane & 15;
    const int q = lane >> 4;

#define STG_HEAD(bufi, kt)                                                                \
    {                                                                                     \
        const int k0s = (kt) << 5;                                                        \
        _Pragma("unroll")                                                                 \
        for (int j = 0; j < 2; ++j) {                                                     \
            const int rr = (wv << 5) + (j << 4);                                          \
            const int gr = rr + r16;                                                      \
            const short* ga = Ah + (size_t)(m0 + gr) * K + k0s + gsw;                     \
            const short* gb = Bh + (size_t)(n0 + gr) * K + k0s + gsw;                     \
            __builtin_amdgcn_global_load_lds(                                             \
                (const __attribute__((address_space(1))) void*)ga,                        \
                (__attribute__((address_space(3))) void*)(sm + (bufi) * 8192 + rr * 32),  \
                16, 0, 0);                                                                \
            __builtin_amdgcn_global_load_lds(                                             \
                (const __attribute__((address_space(1))) void*)gb,                        \
                (__attribute__((address_space(3))) void*)(sm + (bufi) * 8192 + 4096 + rr * 32), \
                16, 0, 0);                                                                \
        }                                                                                 \
    }

    f32x4 acc[4][4];
#pragma unroll
    for (int i = 0; i < 4; ++i)
#pragma unroll
        for (int j = 0; j < 4; ++j)
            acc[i][j] = (f32x4){0.0f, 0.0f, 0.0f, 0.0f};

    const int NKT = K >> 5;  // 16
    STG_HEAD(0, 0)
    STG_HEAD(1, 1)
    STG_HEAD(2, 2)

    int buf = 0;
    for (int t = 0; t < NKT; ++t) {
        if (t < NKT - 2) {
            asm volatile("s_waitcnt vmcnt(8)" ::: "memory");
        } else if (t == NKT - 2) {
            asm volatile("s_waitcnt vmcnt(4)" ::: "memory");
        } else {
            asm volatile("s_waitcnt vmcnt(0)" ::: "memory");
        }
        __builtin_amdgcn_sched_barrier(0);
        __builtin_amdgcn_s_barrier();
        const short* pA = sm + buf * 8192;
        const short* pB = pA + 4096;
        __builtin_amdgcn_s_setprio(1);
        short8_t ah[4], bh[4];
        const int swa = (q ^ (fr & 3)) << 3;
#pragma unroll
        for (int i = 0; i < 4; ++i) {
            ah[i] = *(const short8_t*)&pA[(wm + i * 16 + fr) * 32 + swa];
            bh[i] = *(const short8_t*)&pB[(wn + i * 16 + fr) * 32 + swa];
        }
#pragma unroll
        for (int i = 0; i < 4; ++i)
#pragma unroll
            for (int j = 0; j < 4; ++j)
                acc[i][j] = __builtin_amdgcn_mfma_f32_16x16x32_bf16(ah[i], bh[j], acc[i][j], 0, 0, 0);
        __builtin_amdgcn_s_setprio(0);
        asm volatile("s_waitcnt lgkmcnt(0)" ::: "memory");
        __builtin_amdgcn_sched_barrier(0);
        __builtin_amdgcn_s_barrier();
        if (t + 3 < NKT) {
            STG_HEAD(buf, t + 3)
        }
        buf = buf == 2 ? 0 : buf + 1;
    }
#undef STG_HEAD

    const int hi = lane >> 4;
    const int row_base = hi << 2;
    // conf partials (no barrier, no LDS): per (i,r) row, reduce over 16 lanes x 4 j
#pragma unroll
    for (int i = 0; i < 4; ++i)
#pragma unroll
        for (int r = 0; r < 4; ++r) {
            float v0 = acc[i][0][r], v1 = acc[i][1][r];
            float v2 = acc[i][2][r], v3 = acc[i][3][r];
            float mg = fmaxf(fmaxf(v0, v1), fmaxf(v2, v3));
#pragma unroll
            for (int o = 1; o < 16; o <<= 1) mg = fmaxf(mg, __shfl_xor(mg, o, 64));
            float sg = __expf(v0 - mg) + __expf(v1 - mg) + __expf(v2 - mg) + __expf(v3 - mg);
#pragma unroll
            for (int o = 1; o < 16; o <<= 1) sg += __shfl_xor(sg, o, 64);
            if (fr == 0)
                pp[(size_t)(m0 + wm + i * 16 + hi * 4 + r) * NGRP + nt * 2 + (wn >> 6)] =
                    make_float2(mg, sg);
        }
    // C stores last: fire and retire
#pragma unroll
    for (int i = 0; i < 4; ++i)
#pragma unroll
        for (int j = 0; j < 4; ++j) {
            const int row = m0 + wm + i * 16 + row_base;
            const int col = n0 + wn + j * 16 + fr;
#pragma unroll
            for (int r = 0; r < 4; ++r)
                C[(size_t)(row + r) * N + col] = acc[i][j][r];
        }
}

// -------------------- conf reduce over head partials (one wave per token) ---------
__global__ __launch_bounds__(256) void conf_reduce(const float2* __restrict__ pp,
                                                   int* __restrict__ flags, float thr) {
    int wv = threadIdx.x >> 6, lane = threadIdx.x & 63;
    int t = blockIdx.x * 4 + wv;
    float m = -INFINITY, s = 0.0f;
    for (int k = lane; k < NGRP; k += 64) {
        float2 v = pp[(size_t)t * NGRP + k];
        float mm = fmaxf(m, v.x);
        s = s * __expf(m - mm) + v.y * __expf(v.x - mm);
        m = mm;
    }
#pragma unroll
    for (int o = 1; o < 64; o <<= 1) {
        float mo = __shfl_xor(m, o, 64);
        float so = __shfl_xor(s, o, 64);
        float mm = fmaxf(m, mo);
        s = s * __expf(m - mm) + so * __expf(mo - mm);
        m = mm;
    }
    if (lane == 0) {
        float conf = 1.0f / s;
        if (conf > thr) flags[t] = 0;
    }
}

// -------------------- fp32 tiled GEMM (tier 2/3 dense block-0 path) --------------------
template<bool ADD, bool GELU>
__global__ __launch_bounds__(256) void gemm_nn(const float* __restrict__ A,
                                               const float* __restrict__ B,
                                               float* __restrict__ C,
                                               int M, int N, int K) {
    const int m0 = blockIdx.y * 64, n0 = blockIdx.x * 64;
    __shared__ float As[16][68];
    __shared__ float Bs[16][68];
    const int tid = threadIdx.x;
    const int am = tid >> 2, ak = (tid & 3) << 2;
    const int bk = tid >> 4, bn = (tid & 15) << 2;
    const int tn = tid & 15, tm = tid >> 4;
    float acc[4][4] = {};
    for (int k0 = 0; k0 < K; k0 += 16) {
        float4 a4 = *(const float4*)&A[(size_t)(m0 + am) * K + k0 + ak];
        float4 b4 = *(const float4*)&B[(size_t)(k0 + bk) * N + n0 + bn];
        __syncthreads();
        As[ak + 0][am] = a4.x;
        As[ak + 1][am] = a4.y;
        As[ak + 2][am] = a4.z;
        As[ak + 3][am] = a4.w;
        *(float4*)&Bs[bk][bn] = b4;
        __syncthreads();
#pragma unroll
        for (int kk = 0; kk < 16; ++kk) {
            float4 av = *(const float4*)&As[kk][tm << 2];
            float4 bv = *(const float4*)&Bs[kk][tn << 2];
            float a[4] = {av.x, av.y, av.z, av.w};
            float b[4] = {bv.x, bv.y, bv.z, bv.w};
#pragma unroll
            for (int i = 0; i < 4; ++i)
#pragma unroll
                for (int j = 0; j < 4; ++j)
                    acc[i][j] = fmaf(a[i], b[j], acc[i][j]);
        }
    }
#pragma unroll
    for (int i = 0; i < 4; ++i) {
        size_t row = (size_t)(m0 + (tm << 2) + i);
        float* cp = &C[row * (size_t)N + n0 + (tn << 2)];
        float rr[4] = {acc[i][0], acc[i][1], acc[i][2], acc[i][3]};
        if (GELU) {
#pragma unroll
            for (int j = 0; j < 4; ++j) rr[j] = gelu_f(rr[j]);
        }
        if (ADD) {
            float4 cc = *(const float4*)cp;
            rr[0] += cc.x; rr[1] += cc.y; rr[2] += cc.z; rr[3] += cc.w;
        }
        float4 rv = {rr[0], rr[1], rr[2], rr[3]};
        *(float4*)cp = rv;
    }
}

// -------------------- grid-stride fp32 GEMM over compacted rows (blocks 1-2) ----------
template<bool ADD, bool GELU, bool SCAT>
__global__ __launch_bounds__(256) void gemm_nn_gs(const float* __restrict__ A,
                                                  const float* __restrict__ B,
                                                  float* __restrict__ C,
                                                  int N, int K,
                                                  const int* __restrict__ idx,
                                                  const int* __restrict__ cnt) {
    const int c = *cnt;
    const int ntm = (c + 63) >> 6;
    const int ntn = N >> 6;
    const int total = ntm * ntn;
    __shared__ float As[16][68];
    __shared__ float Bs[16][68];
    const int tid = threadIdx.x;
    const int am = tid >> 2, ak = (tid & 3) << 2;
    const int bk = tid >> 4, bn = (tid & 15) << 2;
    const int tn = tid & 15, tm = tid >> 4;
    for (int tile = blockIdx.x; tile < total; tile += gridDim.x) {
        const int m0 = (tile % ntm) << 6, n0 = (tile / ntm) << 6;
        int ar = m0 + am;
        ar = ar < c ? ar : c - 1;
        float acc[4][4] = {};
        for (int k0 = 0; k0 < K; k0 += 16) {
            float4 a4 = *(const float4*)&A[(size_t)ar * K + k0 + ak];
            float4 b4 = *(const float4*)&B[(size_t)(k0 + bk) * N + n0 + bn];
            __syncthreads();
            As[ak + 0][am] = a4.x;
            As[ak + 1][am] = a4.y;
            As[ak + 2][am] = a4.z;
            As[ak + 3][am] = a4.w;
            *(float4*)&Bs[bk][bn] = b4;
            __syncthreads();
#pragma unroll
            for (int kk = 0; kk < 16; ++kk) {
                float4 av = *(const float4*)&As[kk][tm << 2];
                float4 bv = *(const float4*)&Bs[kk][tn << 2];
                float a[4] = {av.x, av.y, av.z, av.w};
                float b[4] = {bv.x, bv.y, bv.z, bv.w};
#pragma unroll
                for (int i = 0; i < 4; ++i)
#pragma unroll
                    for (int j = 0; j < 4; ++j)
                        acc[i][j] = fmaf(a[i], b[j], acc[i][j]);
            }
        }
#pragma unroll
        for (int i = 0; i < 4; ++i) {
            int p = m0 + (tm << 2) + i;
            if (p >= c) continue;
            int r = SCAT ? idx[p] : p;
            float* cp = &C[(size_t)r * N + n0 + (tn << 2)];
            float rr[4] = {acc[i][0], acc[i][1], acc[i][2], acc[i][3]};
            if (GELU) {
#pragma unroll
                for (int j = 0; j < 4; ++j) rr[j] = gelu_f(rr[j]);
            }
            if (ADD) {
                float4 cc = *(const float4*)cp;
                rr[0] += cc.x; rr[1] += cc.y; rr[2] += cc.z; rr[3] += cc.w;
            }
            float4 rv = {rr[0], rr[1], rr[2], rr[3]};
            *(float4*)cp = rv;
        }
        __syncthreads();
    }
}

// -------------------- grid-stride fp32 head GEMM over compacted rows (blocks 1-2) -----
__global__ __launch_bounds__(256) void gemm_nt_head_gs(const float* __restrict__ A,
                                                       const float* __restrict__ Bt,
                                                       float* __restrict__ C,
                                                       const int* __restrict__ idx,
                                                       const int* __restrict__ cnt) {
    const int c = *cnt;
    const int ntm = (c + 63) >> 6;
    const int ntn = NVOCAB >> 6;
    const int total = ntm * ntn;
    __shared__ float As[16][68];
    __shared__ float Bs[16][68];
    const int tid = threadIdx.x;
    const int am = tid >> 2, ak = (tid & 3) << 2;
    const int tn = tid & 15, tm = tid >> 4;
    for (int tile = blockIdx.x; tile < total; tile += gridDim.x) {
        const int m0 = (tile % ntm) << 6, n0 = (tile / ntm) << 6;
        int ap = m0 + am;
        int ar = idx[ap < c ? ap : c - 1];
        float acc[4][4] = {};
        for (int k0 = 0; k0 < DIM; k0 += 16) {
            float4 a4 = *(const float4*)&A[(size_t)ar * DIM + k0 + ak];
            float4 b4 = *(const float4*)&Bt[(size_t)(n0 + am) * DIM + k0 + ak];
            __syncthreads();
            As[ak + 0][am] = a4.x;
            As[ak + 1][am] = a4.y;
            As[ak + 2][am] = a4.z;
            As[ak + 3][am] = a4.w;
            Bs[ak + 0][am] = b4.x;
            Bs[ak + 1][am] = b4.y;
            Bs[ak + 2][am] = b4.z;
            Bs[ak + 3][am] = b4.w;
            __syncthreads();
#pragma unroll
            for (int kk = 0; kk < 16; ++kk) {
                float4 av = *(const float4*)&As[kk][tm << 2];
                float4 bv = *(const float4*)&Bs[kk][tn << 2];
                float a[4] = {av.x, av.y, av.z, av.w};
                float b[4] = {bv.x, bv.y, bv.z, bv.w};
#pragma unroll
                for (int i = 0; i < 4; ++i)
#pragma unroll
                    for (int j = 0; j < 4; ++j)
                        acc[i][j] = fmaf(a[i], b[j], acc[i][j]);
            }
        }
#pragma unroll
        for (int i = 0; i < 4; ++i) {
            int p = m0 + (tm << 2) + i;
            if (p >= c) continue;
            int r = idx[p];
            float4 rv = {acc[i][0], acc[i][1], acc[i][2], acc[i][3]};
            *(float4*)&C[(size_t)r * NVOCAB + n0 + (tn << 2)] = rv;
        }
        __syncthreads();
    }
}

// -------------------- confidence + exit (vectorized full-row read) --------------------
template<bool IDX>
__global__ __launch_bounds__(256) void conf_exit(const float* __restrict__ out,
                                                 int* __restrict__ flags,
                                                 const int* __restrict__ idx,
                                                 const int* __restrict__ cnt,
                                                 float thr) {
    int t;
    if (IDX) {
        if (blockIdx.x >= *cnt) return;
        t = idx[blockIdx.x];
    } else {
        t = blockIdx.x;
        if (flags[t] == 0) return;
    }
    const float4* row = (const float4*)(out + (size_t)t * NVOCAB);
    float m = -INFINITY, s = 0.0f;
    for (int i = threadIdx.x; i < NVOCAB / 4; i += 256) {
        float4 v = row[i];
        float m4 = fmaxf(fmaxf(v.x, v.y), fmaxf(v.z, v.w));
        float s4 = __expf(v.x - m4) + __expf(v.y - m4) + __expf(v.z - m4) + __expf(v.w - m4);
        if (m4 > m) {
            s = s * __expf(m - m4) + s4;
            m = m4;
        } else {
            s += s4 * __expf(m4 - m);
        }
    }
    __shared__ float ms[256], ss[256];
    ms[threadIdx.x] = m;
    ss[threadIdx.x] = s;
    __syncthreads();
    for (int st = 128; st; st >>= 1) {
        if (threadIdx.x < st) {
            float m1 = ms[threadIdx.x], s1 = ss[threadIdx.x];
            float m2 = ms[threadIdx.x + st], s2 = ss[threadIdx.x + st];
            float mm = fmaxf(m1, m2);
            ss[threadIdx.x] = s1 * __expf(m1 - mm) + s2 * __expf(m2 - mm);
            ms[threadIdx.x] = mm;
        }
        __syncthreads();
    }
    if (threadIdx.x == 0) {
        float conf = 1.0f / ss[0];
        if (conf > thr) flags[t] = 0;
    }
}

// -------------------- ordered compaction of active tokens (single block) --------------------
__global__ __launch_bounds__(256) void compact_kernel(const int* __restrict__ flags,
                                                      int* __restrict__ idx,
                                                      int* __restrict__ cnt) {
    __shared__ int wsum[4];
    __shared__ int base;
    if (threadIdx.x == 0) base = 0;
    int lane = threadIdx.x & 63, wv = threadIdx.x >> 6;
    for (int chunk = 0; chunk < TT; chunk += 256) {
        __syncthreads();
        int t = chunk + threadIdx.x;
        int f = flags[t];
        unsigned long long b = __ballot(f != 0);
        if (lane == 0) wsum[wv] = __popcll(b);
        __syncthreads();
        int off = base;
        for (int w = 0; w < wv; ++w) off += wsum[w];
        off += __popcll(b & ((1ull << lane) - 1));
        if (f) idx[off] = t;
        __syncthreads();
        if (threadIdx.x == 0) base += wsum[0] + wsum[1] + wsum[2] + wsum[3];
    }
    __syncthreads();
    if (threadIdx.x == 0) *cnt = base;
}

extern "C" void kernel_launch(void* const* d_in, const int* in_sizes, int n_in,
                              void* d_out, int out_size, void* d_ws, size_t ws_size,
                              hipStream_t stream) {
    const int* x = (const int*)d_in[0];
    const float* emb = (const float*)d_in[1];
    const float* head = (const float*)d_in[2];
    const float* Wv = (const float*)d_in[3];
    const float* Wo = (const float*)d_in[4];
    const float* W1 = (const float*)d_in[5];
    const float* W2 = (const float*)d_in[6];
    const float* ln1s = (const float*)d_in[7];
    const float* ln1b = (const float*)d_in[8];
    const float* ln2s = (const float*)d_in[9];
    const float* ln2b = (const float*)d_in[10];
    float* out = (float*)d_out;
    float* ws = (float*)d_ws;

    float* h  = ws;                      // TT*DIM fp32
    float* hn = ws + 2097152;            // TT*DIM
    float* tA = ws + 4194304;            // TT*DIM (scratch: WvFlat hi/lo during setup)
    float* tF = ws + 6291456;            // TT*FFN
    short* hnHi = (short*)hn;
    short* hnLo = hnHi + TT * DIM;
    short* tAHi = (short*)tA;
    short* tALo = tAHi + TT * DIM;
    short* tFHi = (short*)tF;
    short* tFLo = tFHi + TT * FFN;
    float2* pp = (float2*)tF;            // conf partials alias tF region
    int* flags = (int*)(ws + 14680064);  // TT
    int* idxl  = flags + TT;             // TT
    int* cntp  = flags + 2 * TT;         // 1
    short* hHi    = (short*)(ws + 14700000);
    short* hLo    = (short*)(ws + 15748576);
    short* headHi = (short*)(ws + 16797152);
    short* headLo = (short*)(ws + 24989152);
    short* wT     = (short*)(ws + 33181152);  // 2 layers x 5242880 shorts
    const size_t LSTRIDE = 5242880;
    const size_t NEED_T2 = (size_t)33181152 * 4;
    const size_t NEED_T1 = (size_t)38424032 * 4;
    const int tier = ws_size >= NEED_T1 ? 1 : (ws_size >= NEED_T2 ? 2 : 3);

    gather_kernel<<<TT, 128, 0, stream>>>(x, emb, h, flags);

    const float THR[3] = {3.5e-05f, 4.0e-05f, 1.0f};
    const dim3 gDD(DIM / 64, TT / 64), gDF(FFN / 64, TT / 64), gHead(NVOCAB / 64, TT / 64);

    // ---------- block 0: dense ----------
    if (tier == 1) {
        // weight prep: transpose-splits; W_voT = WoT @ WvFlat (3-product MFMA)
        for (int l = 0; l < 2; ++l) {
            short* wb = wT + (size_t)l * LSTRIDE;
            cvt_hilo<<<(DIM * DIM / 4 + 255) / 256, 256, 0, stream>>>(Wv + (size_t)l * DIM * DIM, tAHi, tALo, DIM * DIM / 4);
            cvt_w_t<<<dim3(DIM / 32, DIM / 32), 256, 0, stream>>>(Wo + (size_t)l * DIM * DIM, wb + 524288, wb + 786432, DIM, DIM);
            gemm_l64<0><<<dim3(DIM / 64, DIM / 128), 256, 0, stream>>>(
                wb + 524288, wb + 786432, tAHi, tALo, nullptr, wb, wb + 262144, DIM, DIM);
            cvt_w_t_hi<<<dim3(FFN / 32, DIM / 32), 256, 0, stream>>>(W1 + (size_t)l * DIM * FFN, wb + 1048576, DIM, FFN);
            cvt_w_t_hi<<<dim3(DIM / 32, FFN / 32), 256, 0, stream>>>(W2 + (size_t)l * FFN * DIM, wb + 3145728, FFN, DIM);
        }
        for (int l = 0; l < 2; ++l) {
            short* wb = wT + (size_t)l * LSTRIDE;
            ln_hilo<<<TT / 4, 256, 0, stream>>>(h, ln1s + l * DIM, ln1b + l * DIM, hnHi, hnLo);
            gemm_l64b<2><<<dim3(TT / 64, DIM / 128), 256, 0, stream>>>(hnHi, hnLo, wb, h, nullptr, nullptr, DIM, DIM);
            ln_hilo<<<TT / 4, 256, 0, stream>>>(h, ln2s + l * DIM, ln2b + l * DIM, hnHi, hnLo);
            gemm_l2<1><<<dim3(TT / 128, FFN / 128), 256, 0, stream>>>(hnHi, hnLo, wb + 1048576, nullptr, tFHi, tFLo, FFN, DIM);
            if (l == 1) {
                gemm_l64b<4><<<dim3(TT / 64, DIM / 128), 256, 0, stream>>>(tFHi, tFLo, wb + 3145728, h, hHi, hLo, DIM, FFN);
            } else {
                gemm_l64b<2><<<dim3(TT / 64, DIM / 128), 256, 0, stream>>>(tFHi, tFLo, wb + 3145728, h, nullptr, nullptr, DIM, FFN);
            }
        }
        cvt_bf16<<<(NVOCAB * DIM / 4 + 255) / 256, 256, 0, stream>>>(head, headHi, NVOCAB * DIM / 4);
        gemm_head_bf16<<<dim3(TT / 128, NVOCAB / 128), 256, 0, stream>>>(hHi, headHi, out, pp, NVOCAB, DIM);
        conf_reduce<<<TT / 4, 256, 0, stream>>>(pp, flags, THR[0]);
    } else {
        for (int l = 0; l < 2; ++l) {
            ln_kernel<false><<<TT / 4, 256, 0, stream>>>(h, ln1s + l * DIM, ln1b + l * DIM, hn, nullptr, nullptr);
            gemm_nn<false, false><<<gDD, 256, 0, stream>>>(hn, Wv + (size_t)l * DIM * DIM, tA, TT, DIM, DIM);
            gemm_nn<true, false><<<gDD, 256, 0, stream>>>(tA, Wo + (size_t)l * DIM * DIM, h, TT, DIM, DIM);
            ln_kernel<false><<<TT / 4, 256, 0, stream>>>(h, ln2s + l * DIM, ln2b + l * DIM, hn, nullptr, nullptr);
            gemm_nn<false, true><<<gDF, 256, 0, stream>>>(hn, W1 + (size_t)l * DIM * FFN, tF, TT, FFN, DIM);
            gemm_nn<true, false><<<gDD, 256, 0, stream>>>(tF, W2 + (size_t)l * FFN * DIM, h, TT, DIM, FFN);
        }
        if (tier == 2) {
            cvt_hilo<<<(TT * DIM / 4 + 255) / 256, 256, 0, stream>>>(h, hHi, hLo, TT * DIM / 4);
            cvt_hilo<<<(NVOCAB * DIM / 4 + 255) / 256, 256, 0, stream>>>(head, headHi, headLo, NVOCAB * DIM / 4);
            gemm_l_mfma<3><<<dim3(TT / 128, NVOCAB / 128), 256, 0, stream>>>(hHi, hLo, headHi, headLo, out, nullptr, nullptr, NVOCAB, DIM);
        } else {
            compact_kernel<<<1, 256, 0, stream>>>(flags, idxl, cntp);
            gemm_nt_head_gs<<<512, 256, 0, stream>>>(h, head, out, idxl, cntp);
        }
        conf_exit<false><<<TT, 256, 0, stream>>>(out, flags, nullptr, nullptr, THR[0]);
    }
    compact_kernel<<<1, 256, 0, stream>>>(flags, idxl, cntp);

    // ---------- blocks 1,2: compacted active rows (grid-stride fp32 path; ~empty) ----------
    for (int b = 1; b < 3; ++b) {
        for (int li = 0; li < 2; ++li) {
            int l = b * 2 + li;
            ln_kernel<true><<<TT / 4, 256, 0, stream>>>(h, ln1s + l * DIM, ln1b + l * DIM, hn, idxl, cntp);
            gemm_nn_gs<false, false, false><<<256, 256, 0, stream>>>(hn, Wv + (size_t)l * DIM * DIM, tA, DIM, DIM, idxl, cntp);
            gemm_nn_gs<true, false, true><<<256, 256, 0, stream>>>(tA, Wo + (size_t)l * DIM * DIM, h, DIM, DIM, idxl, cntp);
            ln_kernel<true><<<TT / 4, 256, 0, stream>>>(h, ln2s + l * DIM, ln2b + l * DIM, hn, idxl, cntp);
            gemm_nn_gs<false, true, false><<<256, 256, 0, stream>>>(hn, W1 + (size_t)l * DIM * FFN, tF, FFN, DIM, idxl, cntp);
            gemm_nn_gs<true, false, true><<<256, 256, 0, stream>>>(tF, W2 + (size_t)l * FFN * DIM, h, DIM, FFN, idxl, cntp);
        }
        gemm_nt_head_gs<<<512, 256, 0, stream>>>(h, head, out, idxl, cntp);
        if (b == 1) {
            conf_exit<true><<<TT, 256, 0, stream>>>(out, flags, idxl, cntp, THR[1]);
            compact_kernel<<<1, 256, 0, stream>>>(flags, idxl, cntp);
        }
    }
}